// Round 6
// baseline (307.307 us; speedup 1.0000x reference)
//
#include <hip/hip_runtime.h>
#include <math.h>

// RouterLite v10 = v9 with k2_mfma software-pipelined (same disease kA had:
// VGPR=60 -> no prefetch, vmcnt(0) every K-step, MfmaUtil 6.3%, 48.4us for
// 8.6 GFLOP). v10 k2: two register fragment sets (24 frags = 96 VGPR each),
// body = 4 K-steps, fully unrolled; issue next body's 24 loads before current
// body's 32 MFMAs. No LDS, no barriers -> no barrier-drain; compiler emits
// counted vmcnt. launch_bounds(256,2) opens ~256 VGPR (grid caps 2 waves/SIMD
// anyway). Everything else unchanged from v9.
//
// ws map (float offsets), total ~61.9 MB:
//   Xbf  @0         [8192][2048] bf16 (8388608 fl) — dead after k2_mfma,
//                   ALIASED by OP @0 [16][4096][128] fp32 (exact fit)
//   HP   @8388608   [2][8192][256] fp32 partials (k2->k3, dead after),
//                   ALIASED by LW @8388608 [16][4096][2] fp32 (kA->kC)
//   Wbf  @12582912  [512][2048] bf16 (W1q rows 0..255, W1r 256..511)
//   Z    @13107200  [8192][128] fp32
//   Zbf  @14155776  [8192][128] bf16
//   ZbfT @14680064  [128][4096] bf16 (Z_r transposed)
//   RB   @14942208  [4096][128]
//   COS  @15466496  [4096]
//   ILW  @15470592  [4096][2]
// d_out: fp32, [0..4095]=raw_logit, [4096..8191]=delta_theta.

#define HD   2048
#define D2   256
#define DD   128
#define NQ   4096
#define NT   8192
#define NSPLIT 16
#define KPS  (NQ / NSPLIT)   // 256 K-rows per split
#define NIT  (KPS / 64)      // 4 iterations of 64 K-rows

typedef __attribute__((ext_vector_type(8))) short s16x8;
typedef __attribute__((ext_vector_type(4))) float f32x4;

static __device__ __forceinline__ float gelu_exact(float x){
    return 0.5f * x * (1.0f + erff(x * 0.7071067811865475f));
}
static __device__ __forceinline__ unsigned short f2bf(float f){
    unsigned int u = __float_as_uint(f);
    return (unsigned short)((u + 0x7FFFu + ((u >> 16) & 1u)) >> 16);
}
static __device__ __forceinline__ unsigned int pack2bf(float a, float b){
    return (unsigned int)f2bf(a) | ((unsigned int)f2bf(b) << 16);
}

// ---------------- KLN: LN(x) -> bf16 Xbf (blocks 0..8191); W1 -> bf16 Wbf (8192..8703)
__global__ __launch_bounds__(256)
void kLN_cast(const float* __restrict__ q, const float* __restrict__ R,
              const float* __restrict__ gq, const float* __restrict__ bq,
              const float* __restrict__ gr, const float* __restrict__ br,
              const float* __restrict__ W1q, const float* __restrict__ W1r,
              unsigned short* __restrict__ Xbf, unsigned short* __restrict__ Wbf){
    const int r = blockIdx.x;
    const int tid = threadIdx.x;
    if (r >= NT){
        const int rw = r - NT;
        const float* src = (rw >= 256) ? (W1r + (size_t)(rw - 256) * HD)
                                       : (W1q + (size_t)rw * HD);
        float4 a = *(const float4*)&src[tid * 8];
        float4 c = *(const float4*)&src[tid * 8 + 4];
        uint4 p = {pack2bf(a.x, a.y), pack2bf(a.z, a.w),
                   pack2bf(c.x, c.y), pack2bf(c.z, c.w)};
        *(uint4*)&Wbf[(size_t)rw * HD + tid * 8] = p;
        return;
    }
    const float* src = (r < NQ) ? (q + (size_t)r * HD) : (R + (size_t)(r - NQ) * HD);
    const float* g  = (r < NQ) ? gq : gr;
    const float* bb = (r < NQ) ? bq : br;
    float4 x0 = *(const float4*)&src[tid * 8];
    float4 x1 = *(const float4*)&src[tid * 8 + 4];
    float v[8] = {x0.x, x0.y, x0.z, x0.w, x1.x, x1.y, x1.z, x1.w};
    float s = 0.f, sq = 0.f;
#pragma unroll
    for (int i = 0; i < 8; ++i){ s += v[i]; sq += v[i] * v[i]; }
    __shared__ float red[256];
    __shared__ float mS, rS;
    red[tid] = s; __syncthreads();
    for (int off = 128; off > 0; off >>= 1){
        if (tid < off) red[tid] += red[tid + off];
        __syncthreads();
    }
    float sum = red[0]; __syncthreads();
    red[tid] = sq; __syncthreads();
    for (int off = 128; off > 0; off >>= 1){
        if (tid < off) red[tid] += red[tid + off];
        __syncthreads();
    }
    if (tid == 0){
        float mean = sum * (1.0f / HD);
        float var  = red[0] * (1.0f / HD) - mean * mean;
        mS = mean;
        rS = rsqrtf(fmaxf(var, 0.0f) + 1e-5f);
    }
    __syncthreads();
    float mean = mS, rstd = rS;
    float4 g0 = *(const float4*)&g[tid * 8];
    float4 g1 = *(const float4*)&g[tid * 8 + 4];
    float4 b0 = *(const float4*)&bb[tid * 8];
    float4 b1 = *(const float4*)&bb[tid * 8 + 4];
    float gg[8] = {g0.x, g0.y, g0.z, g0.w, g1.x, g1.y, g1.z, g1.w};
    float bv[8] = {b0.x, b0.y, b0.z, b0.w, b1.x, b1.y, b1.z, b1.w};
    float h[8];
#pragma unroll
    for (int i = 0; i < 8; ++i) h[i] = (v[i] - mean) * rstd * gg[i] + bv[i];
    uint4 p = {pack2bf(h[0], h[1]), pack2bf(h[2], h[3]),
               pack2bf(h[4], h[5]), pack2bf(h[6], h[7])};
    *(uint4*)&Xbf[(size_t)r * HD + tid * 8] = p;
}

// ---------------- K2 v10: HP[ks] = Xbf @ Wbf^T (K-half ks), bf16 MFMA,
// software-pipelined: 2 register fragment sets, body = 4 K-steps (24 frags),
// next body's loads issued before current body's 32 MFMAs. Fully unrolled.
__global__ __launch_bounds__(256, 2)
void k2_mfma(const unsigned short* __restrict__ Xbf,
             const unsigned short* __restrict__ Wbf,
             float* __restrict__ HP){
    const int tid  = threadIdx.x;
    const int wave = tid >> 6, lane = tid & 63;
    const int quad = lane >> 4, col = lane & 15;
    const int mblk = blockIdx.x;
    const int nblk = blockIdx.y;
    const int ks   = blockIdx.z;
    const int inp  = mblk >> 6;
    const int mbase = mblk * 64 + (wave & 1) * 32;
    const int nbase = nblk * 128 + (wave >> 1) * 64;

    const unsigned short* A0 = Xbf + (size_t)(mbase + col) * HD + ks * 1024 + quad * 8;
    const unsigned short* A1 = A0 + (size_t)16 * HD;
    const unsigned short* B0 = Wbf + (size_t)(inp * 256 + nbase + col) * HD + ks * 1024 + quad * 8;
    const unsigned short* B1 = B0 + (size_t)16 * HD;
    const unsigned short* B2 = B0 + (size_t)32 * HD;
    const unsigned short* B3 = B0 + (size_t)48 * HD;

    f32x4 acc[2][4];
#pragma unroll
    for (int mi = 0; mi < 2; ++mi)
#pragma unroll
        for (int ni = 0; ni < 4; ++ni) acc[mi][ni] = (f32x4){0.f, 0.f, 0.f, 0.f};

    // Two fragment sets, 4 K-steps each (K-step = 32 elems). All indices
    // compile-time (full unroll) so everything stays in registers.
    s16x8 Xa0[4], Xa1[4], Xb0[4], Xb1[4], Xb2[4], Xb3[4];
    s16x8 Ya0[4], Ya1[4], Yb0[4], Yb1[4], Yb2[4], Yb3[4];

#define K2_LOADSET(Sa0, Sa1, Sb0, Sb1, Sb2, Sb3, KO)                          \
    {                                                                         \
        _Pragma("unroll")                                                     \
        for (int st = 0; st < 4; ++st){                                       \
            const int ko = (KO) + st * 32;                                    \
            Sa0[st] = *(const s16x8*)(A0 + ko);                               \
            Sa1[st] = *(const s16x8*)(A1 + ko);                               \
            Sb0[st] = *(const s16x8*)(B0 + ko);                               \
            Sb1[st] = *(const s16x8*)(B1 + ko);                               \
            Sb2[st] = *(const s16x8*)(B2 + ko);                               \
            Sb3[st] = *(const s16x8*)(B3 + ko);                               \
        }                                                                     \
    }

#define K2_MFMASET(Sa0, Sa1, Sb0, Sb1, Sb2, Sb3)                              \
    {                                                                         \
        _Pragma("unroll")                                                     \
        for (int st = 0; st < 4; ++st){                                       \
            acc[0][0] = __builtin_amdgcn_mfma_f32_16x16x32_bf16(Sa0[st], Sb0[st], acc[0][0], 0, 0, 0); \
            acc[0][1] = __builtin_amdgcn_mfma_f32_16x16x32_bf16(Sa0[st], Sb1[st], acc[0][1], 0, 0, 0); \
            acc[0][2] = __builtin_amdgcn_mfma_f32_16x16x32_bf16(Sa0[st], Sb2[st], acc[0][2], 0, 0, 0); \
            acc[0][3] = __builtin_amdgcn_mfma_f32_16x16x32_bf16(Sa0[st], Sb3[st], acc[0][3], 0, 0, 0); \
            acc[1][0] = __builtin_amdgcn_mfma_f32_16x16x32_bf16(Sa1[st], Sb0[st], acc[1][0], 0, 0, 0); \
            acc[1][1] = __builtin_amdgcn_mfma_f32_16x16x32_bf16(Sa1[st], Sb1[st], acc[1][1], 0, 0, 0); \
            acc[1][2] = __builtin_amdgcn_mfma_f32_16x16x32_bf16(Sa1[st], Sb2[st], acc[1][2], 0, 0, 0); \
            acc[1][3] = __builtin_amdgcn_mfma_f32_16x16x32_bf16(Sa1[st], Sb3[st], acc[1][3], 0, 0, 0); \
        }                                                                     \
    }

    // 8 bodies x 4 K-steps x 32 elems = 1024 K (one ks half).
    K2_LOADSET(Xa0, Xa1, Xb0, Xb1, Xb2, Xb3, 0);
#pragma unroll
    for (int body = 0; body < 8; body += 2){
        if (body + 1 < 8) K2_LOADSET(Ya0, Ya1, Yb0, Yb1, Yb2, Yb3, (body + 1) * 128);
        K2_MFMASET(Xa0, Xa1, Xb0, Xb1, Xb2, Xb3);
        if (body + 2 < 8) K2_LOADSET(Xa0, Xa1, Xb0, Xb1, Xb2, Xb3, (body + 2) * 128);
        K2_MFMASET(Ya0, Ya1, Yb0, Yb1, Yb2, Yb3);
    }
#undef K2_LOADSET
#undef K2_MFMASET

    float* dst = HP + (size_t)ks * NT * D2;
#pragma unroll
    for (int mi = 0; mi < 2; ++mi){
#pragma unroll
        for (int ni = 0; ni < 4; ++ni){
#pragma unroll
            for (int reg = 0; reg < 4; ++reg){
                int m = mbase + mi * 16 + quad * 4 + reg;
                int n = nbase + ni * 16 + col;
                dst[(size_t)m * D2 + n] = acc[mi][ni][reg];
            }
        }
    }
}

// ---------------- K3: combine HP + bias + GELU, GEMM2, l2norm -> Z (fp32), Zbf (bf16)
__global__ __launch_bounds__(256)
void k3_gemm2(const float* __restrict__ HP,
              const float* __restrict__ b1q, const float* __restrict__ b1r,
              const float* __restrict__ W2q, const float* __restrict__ b2q,
              const float* __restrict__ W2r, const float* __restrict__ b2r,
              float* __restrict__ Z, unsigned short* __restrict__ Zbf){
    const int gstart = blockIdx.x * 32;
    const int inp = (gstart >= NQ) ? 1 : 0;
    const float* b1 = inp ? b1r : b1q;
    const float* W2 = inp ? W2r : W2q;
    const float* b2 = inp ? b2r : b2q;

    __shared__ __align__(16) float Hs[32][68];
    __shared__ __align__(16) float Wk[64][132];
    __shared__ float red[32][17];
    __shared__ float normS[32];

    const int tid = threadIdx.x;
    const int ty = tid >> 4;
    const int tx = tid & 15;

    float acc[2][8];
#pragma unroll
    for (int jj = 0; jj < 8; ++jj){ acc[0][jj] = 0.f; acc[1][jj] = 0.f; }

    for (int kc = 0; kc < 4; ++kc){
#pragma unroll
        for (int i = 0; i < 8; ++i){
            int e = tid + i * 256;
            int rr = e >> 6, kk = e & 63;
            size_t idx = (size_t)(gstart + rr) * D2 + kc * 64 + kk;
            float hv = HP[idx] + HP[(size_t)NT * D2 + idx] + b1[kc * 64 + kk];
            Hs[rr][kk] = gelu_exact(hv);
        }
#pragma unroll
        for (int i = 0; i < 32; ++i){
            int e = tid + i * 256;
            int nn = e >> 6, kk = e & 63;
            Wk[kk][nn] = W2[(size_t)nn * D2 + kc * 64 + kk];
        }
        __syncthreads();
#pragma unroll
        for (int k4 = 0; k4 < 16; ++k4){
            float a0[4], a1[4];
            float4 t0 = *(const float4*)&Hs[ty * 2][k4 * 4];
            a0[0] = t0.x; a0[1] = t0.y; a0[2] = t0.z; a0[3] = t0.w;
            float4 t1 = *(const float4*)&Hs[ty * 2 + 1][k4 * 4];
            a1[0] = t1.x; a1[1] = t1.y; a1[2] = t1.z; a1[3] = t1.w;
#pragma unroll
            for (int kq = 0; kq < 4; ++kq){
                float4 w0 = *(const float4*)&Wk[k4 * 4 + kq][tx * 8];
                float4 w1 = *(const float4*)&Wk[k4 * 4 + kq][tx * 8 + 4];
                float wv[8] = {w0.x, w0.y, w0.z, w0.w, w1.x, w1.y, w1.z, w1.w};
#pragma unroll
                for (int jj = 0; jj < 8; ++jj){
                    acc[0][jj] += a0[kq] * wv[jj];
                    acc[1][jj] += a1[kq] * wv[jj];
                }
            }
        }
        __syncthreads();
    }
    float v0[8], v1[8];
    float sq0 = 0.f, sq1 = 0.f;
#pragma unroll
    for (int jj = 0; jj < 8; ++jj){
        int c = tx * 8 + jj;
        v0[jj] = acc[0][jj] + b2[c];
        v1[jj] = acc[1][jj] + b2[c];
        sq0 += v0[jj] * v0[jj];
        sq1 += v1[jj] * v1[jj];
    }
    red[ty * 2][tx]     = sq0;
    red[ty * 2 + 1][tx] = sq1;
    __syncthreads();
    if (tid < 32){
        float s = 0.f;
#pragma unroll
        for (int t = 0; t < 16; ++t) s += red[tid][t];
        normS[tid] = 1.0f / fmaxf(sqrtf(s), 1e-12f);
    }
    __syncthreads();
    float s0 = normS[ty * 2], s1 = normS[ty * 2 + 1];
    int row0 = gstart + ty * 2, row1 = row0 + 1;
    size_t o0 = (size_t)row0 * DD + tx * 8;
    size_t o1 = (size_t)row1 * DD + tx * 8;
    float z0[8], z1[8];
#pragma unroll
    for (int jj = 0; jj < 8; ++jj){ z0[jj] = v0[jj] * s0; z1[jj] = v1[jj] * s1; }
    float4 a = {z0[0], z0[1], z0[2], z0[3]}, b = {z0[4], z0[5], z0[6], z0[7]};
    float4 c = {z1[0], z1[1], z1[2], z1[3]}, d = {z1[4], z1[5], z1[6], z1[7]};
    *(float4*)&Z[o0]     = a;  *(float4*)&Z[o0 + 4] = b;
    *(float4*)&Z[o1]     = c;  *(float4*)&Z[o1 + 4] = d;
    uint4 p0 = {pack2bf(z0[0], z0[1]), pack2bf(z0[2], z0[3]),
                pack2bf(z0[4], z0[5]), pack2bf(z0[6], z0[7])};
    uint4 p1 = {pack2bf(z1[0], z1[1]), pack2bf(z1[2], z1[3]),
                pack2bf(z1[4], z1[5]), pack2bf(z1[6], z1[7])};
    *(uint4*)&Zbf[o0] = p0;
    *(uint4*)&Zbf[o1] = p1;
}

// ---------------- KT: ZbfT[d][r] = Zbf[NQ + r][d]  (r part only), tile 64x128.
__global__ __launch_bounds__(256)
void kT_transpose(const unsigned short* __restrict__ Zbf,
                  unsigned short* __restrict__ ZbfT){
    __shared__ unsigned short Ts[64][129];
    const int r0 = blockIdx.x * 64;
    const int tid = threadIdx.x;
#pragma unroll
    for (int i = 0; i < 32; ++i){
        int e = tid + i * 256;
        int rr = e >> 7, dd = e & 127;
        Ts[rr][dd] = Zbf[(size_t)(NQ + r0 + rr) * DD + dd];
    }
    __syncthreads();
#pragma unroll
    for (int i = 0; i < 32; ++i){
        int e = tid + i * 256;
        int dd = e >> 6, rr = e & 63;
        ZbfT[(size_t)dd * NQ + r0 + rr] = Ts[rr][dd];
    }
}

// ---------------- KA v9: flash attention, 32 q-rows/wave, V-prefetch.
__global__ __launch_bounds__(256, 2)
void kA_attn(const unsigned short* __restrict__ Zbf,
             const unsigned short* __restrict__ ZbfT,
             float* __restrict__ OP, float* __restrict__ LW){
    const int tid  = threadIdx.x;
    const int wave = tid >> 6, lane = tid & 63;
    const int quad = lane >> 4, col = lane & 15;
    const int m0   = blockIdx.x * 128 + wave * 32;
    const int split = blockIdx.y;
    const float scl = 0.08838834764831845f;   // 1/sqrt(128)

    __shared__ __align__(16) unsigned short Pt[4][2][16][72];  // per-wave, 2 m-subtiles

    s16x8 aq[2][4];
#pragma unroll
    for (int m = 0; m < 2; ++m)
#pragma unroll
        for (int kb = 0; kb < 4; ++kb)
            aq[m][kb] = *(const s16x8*)&Zbf[(size_t)(m0 + m * 16 + col) * DD + kb * 32 + quad * 8];

    f32x4 o[2][8];
#pragma unroll
    for (int m = 0; m < 2; ++m)
#pragma unroll
        for (int dt = 0; dt < 8; ++dt) o[m][dt] = (f32x4){0.f, 0.f, 0.f, 0.f};
    float lp[2][4] = {{0.f,0.f,0.f,0.f},{0.f,0.f,0.f,0.f}};
    float wp[2][4] = {{0.f,0.f,0.f,0.f},{0.f,0.f,0.f,0.f}};

    for (int it = 0; it < NIT; ++it){
        const int r0 = split * KPS + it * 64;

        // ---- V prefetch (16 frags, 64 VGPR) — issued before QK so the
        // global latency overlaps QK MFMAs + exp chain.
        s16x8 bv[8][2];
#pragma unroll
        for (int dt = 0; dt < 8; ++dt)
#pragma unroll
            for (int kb2 = 0; kb2 < 2; ++kb2)
                bv[dt][kb2] = *(const s16x8*)&ZbfT[(size_t)(dt * 16 + col) * NQ + r0 + kb2 * 32 + quad * 8];

        // ---- QK^T + exp for both m-subtiles.
#pragma unroll
        for (int nt = 0; nt < 4; ++nt){
            s16x8 b[4];
#pragma unroll
            for (int kb = 0; kb < 4; ++kb)
                b[kb] = *(const s16x8*)&Zbf[(size_t)(NQ + r0 + nt * 16 + col) * DD + kb * 32 + quad * 8];
#pragma unroll
            for (int m = 0; m < 2; ++m){
                f32x4 s = (f32x4){0.f, 0.f, 0.f, 0.f};
#pragma unroll
                for (int kb = 0; kb < 4; ++kb)
                    s = __builtin_amdgcn_mfma_f32_16x16x32_bf16(aq[m][kb], b[kb], s, 0, 0, 0);
#pragma unroll
                for (int reg = 0; reg < 4; ++reg){
                    float sv = s[reg] * scl;
                    float e  = __expf(sv);
                    lp[m][reg] += e;
                    wp[m][reg] += e * sv;
                    Pt[wave][m][quad * 4 + reg][nt * 16 + col] = f2bf(e);
                }
            }
        }

        // ---- PV using prefetched V.
#pragma unroll
        for (int m = 0; m < 2; ++m){
            s16x8 ap[2];
#pragma unroll
            for (int kb2 = 0; kb2 < 2; ++kb2)
                ap[kb2] = *(const s16x8*)&Pt[wave][m][col][kb2 * 32 + quad * 8];
#pragma unroll
            for (int dt = 0; dt < 8; ++dt)
#pragma unroll
                for (int kb2 = 0; kb2 < 2; ++kb2)
                    o[m][dt] = __builtin_amdgcn_mfma_f32_16x16x32_bf16(ap[kb2], bv[dt][kb2], o[m][dt], 0, 0, 0);
        }
    }

#pragma unroll
    for (int m = 0; m < 2; ++m)
#pragma unroll
    for (int reg = 0; reg < 4; ++reg){
        float l = lp[m][reg], w = wp[m][reg];
        l += __shfl_xor(l, 8);  w += __shfl_xor(w, 8);
        l += __shfl_xor(l, 4);  w += __shfl_xor(w, 4);
        l += __shfl_xor(l, 2);  w += __shfl_xor(w, 2);
        l += __shfl_xor(l, 1);  w += __shfl_xor(w, 1);
        if (col == 0){
            int row = m0 + m * 16 + quad * 4 + reg;
            LW[((size_t)split * NQ + row) * 2]     = l;
            LW[((size_t)split * NQ + row) * 2 + 1] = w;
        }
    }
#pragma unroll
    for (int m = 0; m < 2; ++m)
#pragma unroll
    for (int dt = 0; dt < 8; ++dt){
#pragma unroll
        for (int reg = 0; reg < 4; ++reg){
            int row = m0 + m * 16 + quad * 4 + reg;
            OP[((size_t)split * NQ + row) * DD + dt * 16 + col] = o[m][dt][reg];
        }
    }
}

// ---------------- KC: combine NSPLIT splits -> r_bar, cos, u_n.
__global__ __launch_bounds__(128)
void kC_combine(const float* __restrict__ OP, const float* __restrict__ LW,
                const float* __restrict__ Z,
                float* __restrict__ RB, float* __restrict__ COS,
                float* __restrict__ ILW){
    const int r = blockIdx.x;
    const int c = threadIdx.x;
    float v = 0.f;
#pragma unroll
    for (int s = 0; s < NSPLIT; ++s) v += OP[((size_t)s * NQ + r) * DD + c];
    __shared__ float red[128];
    red[c] = v * v; __syncthreads();
    for (int off = 64; off > 0; off >>= 1){
        if (c < off) red[c] += red[c + off];
        __syncthreads();
    }
    float scale = 1.0f / fmaxf(sqrtf(red[0]), 1e-12f);
    __syncthreads();
    float rb = v * scale;
    RB[(size_t)r * DD + c] = rb;
    float zq = Z[(size_t)r * DD + c];
    red[c] = zq * rb; __syncthreads();
    for (int off = 64; off > 0; off >>= 1){
        if (c < off) red[c] += red[c + off];
        __syncthreads();
    }
    if (c == 0){
        COS[r] = red[0];
        float l = 0.f, w = 0.f;
#pragma unroll
        for (int s = 0; s < NSPLIT; ++s){
            l += LW[((size_t)s * NQ + r) * 2];
            w += LW[((size_t)s * NQ + r) * 2 + 1];
        }
        float ent = logf(l) - w / l;
        ILW[2 * r]     = 1.0f / l;
        ILW[2 * r + 1] = ent * (1.0f / 8.317766166719343f);  // / ln(4096)
    }
}

// ---------------- K8: decoder MLP (occupancy rewrite, unchanged from v7).
__global__ __launch_bounds__(256)
void k8_decoder(const float* __restrict__ Z, const float* __restrict__ RB,
                const float* __restrict__ ILW, const float* __restrict__ COS,
                const float* __restrict__ gd, const float* __restrict__ bd,
                const float* __restrict__ W1d, const float* __restrict__ b1d,
                const float* __restrict__ W2d, const float* __restrict__ b2d,
                const float* __restrict__ beta, const float* __restrict__ W_len,
                const float* __restrict__ b_len,
                float* __restrict__ out){
    const int r0 = blockIdx.x * 4;
    const int tid = threadIdx.x;
    const int wave = tid >> 6, lane = tid & 63;

    __shared__ __align__(16) float Xs[4][256];
    __shared__ float pr[4][2];

    {
        const int row = r0 + wave;
        const int c0 = lane * 4;
        float4 v;
        if (c0 < DD) v = *(const float4*)&Z[(size_t)row * DD + c0];
        else         v = *(const float4*)&RB[(size_t)row * DD + (c0 - DD)];
        float s  = v.x + v.y + v.z + v.w;
        float sq = v.x * v.x + v.y * v.y + v.z * v.z + v.w * v.w;
#pragma unroll
        for (int off = 32; off > 0; off >>= 1){
            s  += __shfl_xor(s, off);
            sq += __shfl_xor(sq, off);
        }
        float mean = s * (1.0f / D2);
        float var  = sq * (1.0f / D2) - mean * mean;
        float rstd = rsqrtf(fmaxf(var, 0.0f) + 1e-5f);
        float4 g = *(const float4*)&gd[c0];
        float4 b = *(const float4*)&bd[c0];
        float4 xn;
        xn.x = (v.x - mean) * rstd * g.x + b.x;
        xn.y = (v.y - mean) * rstd * g.y + b.y;
        xn.z = (v.z - mean) * rstd * g.z + b.z;
        xn.w = (v.w - mean) * rstd * g.w + b.w;
        *(float4*)&Xs[wave][c0] = xn;
    }
    __syncthreads();

    const int j  = tid & 127;
    const int rp = tid >> 7;
    const float* wrow = W1d + (size_t)j * D2;
    const float* xa = &Xs[rp * 2][0];
    const float* xb = &Xs[rp * 2 + 1][0];
    float h0 = 0.f, h1 = 0.f;
#pragma unroll 8
    for (int k = 0; k < D2; k += 4){
        float4 w  = *(const float4*)&wrow[k];
        float4 a4 = *(const float4*)&xa[k];
        float4 b4 = *(const float4*)&xb[k];
        h0 += w.x * a4.x + w.y * a4.y + w.z * a4.z + w.w * a4.w;
        h1 += w.x * b4.x + w.y * b4.y + w.z * b4.z + w.w * b4.w;
    }
    float bj = b1d[j];
    h0 = gelu_exact(h0 + bj);
    h1 = gelu_exact(h1 + bj);
    float w2 = W2d[j];
    float p0 = h0 * w2, p1 = h1 * w2;
#pragma unroll
    for (int off = 32; off > 0; off >>= 1){
        p0 += __shfl_xor(p0, off);
        p1 += __shfl_xor(p1, off);
    }
    if (lane == 0){ pr[wave][0] = p0; pr[wave][1] = p1; }
    __syncthreads();

    if (tid < 4){
        const int row   = tid;
        const int rpair = row >> 1, rlo = row & 1;
        float lg = b2d[0] + pr[rpair * 2][rlo] + pr[rpair * 2 + 1][rlo];
        const int gr = r0 + row;
        float u  = ILW[2 * gr + 1];
        float cv = COS[gr];
        float dln = cv * W_len[0] + u * W_len[1] + b_len[0];
        float dt = beta[0] * u + beta[1] * tanhf(dln);
        dt = fminf(0.5f, fmaxf(-0.5f, dt));
        out[gr]      = lg;
        out[NQ + gr] = dt;
    }
}

extern "C" void kernel_launch(void* const* d_in, const int* in_sizes, int n_in,
                              void* d_out, int out_size, void* d_ws, size_t ws_size,
                              hipStream_t stream){
    const float* q      = (const float*)d_in[0];
    const float* R      = (const float*)d_in[1];
    const float* ln_q_g = (const float*)d_in[2];
    const float* ln_q_b = (const float*)d_in[3];
    const float* W1q    = (const float*)d_in[4];
    const float* b1q    = (const float*)d_in[5];
    const float* W2q    = (const float*)d_in[6];
    const float* b2q    = (const float*)d_in[7];
    const float* ln_r_g = (const float*)d_in[8];
    const float* ln_r_b = (const float*)d_in[9];
    const float* W1r    = (const float*)d_in[10];
    const float* b1r    = (const float*)d_in[11];
    const float* W2r    = (const float*)d_in[12];
    const float* b2r    = (const float*)d_in[13];
    const float* ln_d_g = (const float*)d_in[14];
    const float* ln_d_b = (const float*)d_in[15];
    const float* W1d    = (const float*)d_in[16];
    const float* b1d    = (const float*)d_in[17];
    const float* W2d    = (const float*)d_in[18];
    const float* b2d    = (const float*)d_in[19];
    const float* beta   = (const float*)d_in[20];
    const float* W_len  = (const float*)d_in[21];
    const float* b_len  = (const float*)d_in[22];

    float* WS = (float*)d_ws;
    unsigned short* Xbf  = (unsigned short*)(WS);             // 8192*2048 bf16 = 8388608 fl
    float* OP    = WS;                                        // [16][4096][128] aliases Xbf (dead after k2) — exact fit
    float* HP    = WS + 8388608;                              // 2*8192*256
    float* LW    = WS + 8388608;                              // [16][4096][2] aliases HP (dead after k3)
    unsigned short* Wbf  = (unsigned short*)(WS + 12582912);  // 512*2048 bf16
    float* Z     = WS + 13107200;                             // 8192*128
    unsigned short* Zbf  = (unsigned short*)(WS + 14155776);  // 8192*128 bf16
    unsigned short* ZbfT = (unsigned short*)(WS + 14680064);  // 128*4096 bf16
    float* RB    = WS + 14942208;                             // 4096*128
    float* COSV  = WS + 15466496;                             // 4096
    float* ILW   = WS + 15470592;                             // 4096*2
    float* out   = (float*)d_out;

    hipLaunchKernelGGL(kLN_cast, dim3(NT + 512), dim3(256), 0, stream,
                       q, R, ln_q_g, ln_q_b, ln_r_g, ln_r_b, W1q, W1r, Xbf, Wbf);
    hipLaunchKernelGGL(k2_mfma, dim3(128, 2, 2), dim3(256), 0, stream, Xbf, Wbf, HP);
    hipLaunchKernelGGL(k3_gemm2, dim3(256), dim3(256), 0, stream,
                       HP, b1q, b1r, W2q, b2q, W2r, b2r, Z, Zbf);
    hipLaunchKernelGGL(kT_transpose, dim3(64), dim3(256), 0, stream, Zbf, ZbfT);
    hipLaunchKernelGGL(kA_attn, dim3(32, NSPLIT), dim3(256), 0, stream, Zbf, ZbfT, OP, LW);
    hipLaunchKernelGGL(kC_combine, dim3(NQ), dim3(128), 0, stream, OP, LW, Z, RB, COSV, ILW);
    hipLaunchKernelGGL(k8_decoder, dim3(1024), dim3(256), 0, stream,
                       Z, RB, ILW, COSV, ln_d_g, ln_d_b, W1d, b1d, W2d, b2d,
                       beta, W_len, b_len, out);
}

// Round 7
// 273.549 us; speedup vs baseline: 1.1234x; 1.1234x over previous
//
#include <hip/hip_runtime.h>
#include <math.h>

// RouterLite v11 = v10 with k2_mfma rewritten as LDS-staged GEMM.
// v10 post-mortem: compiler defeated reg-level pipelining (VGPR 60->52,
// dur pinned 48us across schedule changes) -> k2 is bound by SCATTERED
// global fragment reads (16 rows x 4KB stride per wave-load), not schedule.
// v11 k2: BM64xBN128xBK64 double-buffered LDS, global_load_lds width=16
// (coalesced, async), XOR-swizzle (byte ^= (row&7)<<4) applied on global
// source + ds_read offsets (linear LDS dest per HW constraint). 2-barrier
// loop; 512 blocks = 2/CU interleave across barrier drains.
//
// ws map (float offsets), total ~61.9 MB:
//   Xbf  @0         [8192][2048] bf16 (8388608 fl) — dead after k2_mfma,
//                   ALIASED by OP @0 [16][4096][128] fp32 (exact fit)
//   HP   @8388608   [2][8192][256] fp32 partials (k2->k3, dead after),
//                   ALIASED by LW @8388608 [16][4096][2] fp32 (kA->kC)
//   Wbf  @12582912  [512][2048] bf16 (W1q rows 0..255, W1r 256..511)
//   Z    @13107200  [8192][128] fp32
//   Zbf  @14155776  [8192][128] bf16
//   ZbfT @14680064  [128][4096] bf16 (Z_r transposed)
//   RB   @14942208  [4096][128]
//   COS  @15466496  [4096]
//   ILW  @15470592  [4096][2]
// d_out: fp32, [0..4095]=raw_logit, [4096..8191]=delta_theta.

#define HD   2048
#define D2   256
#define DD   128
#define NQ   4096
#define NT   8192
#define NSPLIT 16
#define KPS  (NQ / NSPLIT)   // 256 K-rows per split
#define NIT  (KPS / 64)      // 4 iterations of 64 K-rows

typedef __attribute__((ext_vector_type(8))) short s16x8;
typedef __attribute__((ext_vector_type(4))) float f32x4;

static __device__ __forceinline__ float gelu_exact(float x){
    return 0.5f * x * (1.0f + erff(x * 0.7071067811865475f));
}
static __device__ __forceinline__ unsigned short f2bf(float f){
    unsigned int u = __float_as_uint(f);
    return (unsigned short)((u + 0x7FFFu + ((u >> 16) & 1u)) >> 16);
}
static __device__ __forceinline__ unsigned int pack2bf(float a, float b){
    return (unsigned int)f2bf(a) | ((unsigned int)f2bf(b) << 16);
}

static __device__ __forceinline__ void gload_lds16(const void* g, void* l){
    __builtin_amdgcn_global_load_lds(
        (const __attribute__((address_space(1))) unsigned int*)g,
        (__attribute__((address_space(3))) unsigned int*)l, 16, 0, 0);
}

// ---------------- KLN: LN(x) -> bf16 Xbf (blocks 0..8191); W1 -> bf16 Wbf (8192..8703)
__global__ __launch_bounds__(256)
void kLN_cast(const float* __restrict__ q, const float* __restrict__ R,
              const float* __restrict__ gq, const float* __restrict__ bq,
              const float* __restrict__ gr, const float* __restrict__ br,
              const float* __restrict__ W1q, const float* __restrict__ W1r,
              unsigned short* __restrict__ Xbf, unsigned short* __restrict__ Wbf){
    const int r = blockIdx.x;
    const int tid = threadIdx.x;
    if (r >= NT){
        const int rw = r - NT;
        const float* src = (rw >= 256) ? (W1r + (size_t)(rw - 256) * HD)
                                       : (W1q + (size_t)rw * HD);
        float4 a = *(const float4*)&src[tid * 8];
        float4 c = *(const float4*)&src[tid * 8 + 4];
        uint4 p = {pack2bf(a.x, a.y), pack2bf(a.z, a.w),
                   pack2bf(c.x, c.y), pack2bf(c.z, c.w)};
        *(uint4*)&Wbf[(size_t)rw * HD + tid * 8] = p;
        return;
    }
    const float* src = (r < NQ) ? (q + (size_t)r * HD) : (R + (size_t)(r - NQ) * HD);
    const float* g  = (r < NQ) ? gq : gr;
    const float* bb = (r < NQ) ? bq : br;
    float4 x0 = *(const float4*)&src[tid * 8];
    float4 x1 = *(const float4*)&src[tid * 8 + 4];
    float v[8] = {x0.x, x0.y, x0.z, x0.w, x1.x, x1.y, x1.z, x1.w};
    float s = 0.f, sq = 0.f;
#pragma unroll
    for (int i = 0; i < 8; ++i){ s += v[i]; sq += v[i] * v[i]; }
    __shared__ float red[256];
    __shared__ float mS, rS;
    red[tid] = s; __syncthreads();
    for (int off = 128; off > 0; off >>= 1){
        if (tid < off) red[tid] += red[tid + off];
        __syncthreads();
    }
    float sum = red[0]; __syncthreads();
    red[tid] = sq; __syncthreads();
    for (int off = 128; off > 0; off >>= 1){
        if (tid < off) red[tid] += red[tid + off];
        __syncthreads();
    }
    if (tid == 0){
        float mean = sum * (1.0f / HD);
        float var  = red[0] * (1.0f / HD) - mean * mean;
        mS = mean;
        rS = rsqrtf(fmaxf(var, 0.0f) + 1e-5f);
    }
    __syncthreads();
    float mean = mS, rstd = rS;
    float4 g0 = *(const float4*)&g[tid * 8];
    float4 g1 = *(const float4*)&g[tid * 8 + 4];
    float4 b0 = *(const float4*)&bb[tid * 8];
    float4 b1 = *(const float4*)&bb[tid * 8 + 4];
    float gg[8] = {g0.x, g0.y, g0.z, g0.w, g1.x, g1.y, g1.z, g1.w};
    float bv[8] = {b0.x, b0.y, b0.z, b0.w, b1.x, b1.y, b1.z, b1.w};
    float h[8];
#pragma unroll
    for (int i = 0; i < 8; ++i) h[i] = (v[i] - mean) * rstd * gg[i] + bv[i];
    uint4 p = {pack2bf(h[0], h[1]), pack2bf(h[2], h[3]),
               pack2bf(h[4], h[5]), pack2bf(h[6], h[7])};
    *(uint4*)&Xbf[(size_t)r * HD + tid * 8] = p;
}

// ---------------- K2 v11: HP[ks] = Xbf @ Wbf^T (K-half ks), LDS-staged.
// Block: BM=64 x BN=128, 4 waves (wm=wave&1 -> 32 m-rows, wn=wave>>1 -> 64 n).
// BK=64, double-buffered LDS (A 8KB + B 16KB per buf = 48KB total).
// Staging: global_load_lds 16B; LDS dest linear (slot*16); XOR-swizzle via
// global source chunk c = (slot&7)^(row&7); ds_read offset applies same XOR.
__global__ __launch_bounds__(256)
void k2_mfma(const unsigned short* __restrict__ Xbf,
             const unsigned short* __restrict__ Wbf,
             float* __restrict__ HP){
    const int tid  = threadIdx.x;
    const int wave = tid >> 6, lane = tid & 63;
    const int quad = lane >> 4, col = lane & 15;
    const int mblk = blockIdx.x;
    const int nblk = blockIdx.y;
    const int ks   = blockIdx.z;
    const int inp  = mblk >> 6;
    const int mbase = mblk * 64;
    const int nbase = nblk * 128;
    const int wm = wave & 1, wn = wave >> 1;

    __shared__ __align__(16) char smem[49152];   // [2][ A 8192 | B 16384 ]

    // ---- staging source pointers (per thread, 2 A-issues + 4 B-issues).
    // slot s: row = s>>3, physchunk = s&7, logical chunk c = (s&7)^(row&7).
    const unsigned short* gA[2];
    const unsigned short* gB[4];
#pragma unroll
    for (int i = 0; i < 2; ++i){
        int s = i * 256 + wave * 64 + lane;
        int row = s >> 3, c = (s & 7) ^ (row & 7);
        gA[i] = Xbf + (size_t)(mbase + row) * HD + ks * 1024 + c * 8;
    }
#pragma unroll
    for (int j = 0; j < 4; ++j){
        int s = j * 256 + wave * 64 + lane;
        int row = s >> 3, c = (s & 7) ^ (row & 7);
        gB[j] = Wbf + (size_t)(inp * 256 + nbase + row) * HD + ks * 1024 + c * 8;
    }

#define K2_STAGE(d, k0)                                                        \
    {                                                                          \
        _Pragma("unroll")                                                      \
        for (int i = 0; i < 2; ++i)                                            \
            gload_lds16(gA[i] + (k0),                                          \
                        smem + (d) * 24576 + (i * 256 + wave * 64) * 16);      \
        _Pragma("unroll")                                                      \
        for (int j = 0; j < 4; ++j)                                            \
            gload_lds16(gB[j] + (k0),                                          \
                        smem + (d) * 24576 + 8192 + (j * 256 + wave * 64) * 16);\
    }

    // ---- swizzled ds_read byte offsets (compile-time unrolled).
    int aoff[2][2], boff[4][2];
#pragma unroll
    for (int mi = 0; mi < 2; ++mi){
        int ra = wm * 32 + mi * 16 + col;
#pragma unroll
        for (int kst = 0; kst < 2; ++kst){
            int cc = kst * 4 + quad;
            aoff[mi][kst] = ra * 128 + ((cc ^ (ra & 7)) << 4);
        }
    }
#pragma unroll
    for (int ni = 0; ni < 4; ++ni){
        int rb = wn * 64 + ni * 16 + col;
#pragma unroll
        for (int kst = 0; kst < 2; ++kst){
            int cc = kst * 4 + quad;
            boff[ni][kst] = rb * 128 + ((cc ^ (rb & 7)) << 4);
        }
    }

    f32x4 acc[2][4];
#pragma unroll
    for (int mi = 0; mi < 2; ++mi)
#pragma unroll
        for (int ni = 0; ni < 4; ++ni) acc[mi][ni] = (f32x4){0.f, 0.f, 0.f, 0.f};

    int cur = 0;
    K2_STAGE(0, 0);
    __syncthreads();
    for (int t = 0; t < 16; ++t){
        if (t < 15) K2_STAGE(cur ^ 1, (t + 1) * 64);
        const char* Ab = smem + cur * 24576;
        const char* Bb = Ab + 8192;
        s16x8 a[2][2], b[4][2];
#pragma unroll
        for (int mi = 0; mi < 2; ++mi)
#pragma unroll
            for (int kst = 0; kst < 2; ++kst)
                a[mi][kst] = *(const s16x8*)(Ab + aoff[mi][kst]);
#pragma unroll
        for (int ni = 0; ni < 4; ++ni)
#pragma unroll
            for (int kst = 0; kst < 2; ++kst)
                b[ni][kst] = *(const s16x8*)(Bb + boff[ni][kst]);
#pragma unroll
        for (int kst = 0; kst < 2; ++kst)
#pragma unroll
            for (int mi = 0; mi < 2; ++mi)
#pragma unroll
                for (int ni = 0; ni < 4; ++ni)
                    acc[mi][ni] = __builtin_amdgcn_mfma_f32_16x16x32_bf16(
                        a[mi][kst], b[ni][kst], acc[mi][ni], 0, 0, 0);
        __syncthreads();
        cur ^= 1;
    }
#undef K2_STAGE

    float* dst = HP + (size_t)ks * NT * D2;
#pragma unroll
    for (int mi = 0; mi < 2; ++mi){
#pragma unroll
        for (int ni = 0; ni < 4; ++ni){
#pragma unroll
            for (int reg = 0; reg < 4; ++reg){
                int m = mbase + wm * 32 + mi * 16 + quad * 4 + reg;
                int n = nbase + wn * 64 + ni * 16 + col;
                dst[(size_t)m * D2 + n] = acc[mi][ni][reg];
            }
        }
    }
}

// ---------------- K3: combine HP + bias + GELU, GEMM2, l2norm -> Z (fp32), Zbf (bf16)
__global__ __launch_bounds__(256)
void k3_gemm2(const float* __restrict__ HP,
              const float* __restrict__ b1q, const float* __restrict__ b1r,
              const float* __restrict__ W2q, const float* __restrict__ b2q,
              const float* __restrict__ W2r, const float* __restrict__ b2r,
              float* __restrict__ Z, unsigned short* __restrict__ Zbf){
    const int gstart = blockIdx.x * 32;
    const int inp = (gstart >= NQ) ? 1 : 0;
    const float* b1 = inp ? b1r : b1q;
    const float* W2 = inp ? W2r : W2q;
    const float* b2 = inp ? b2r : b2q;

    __shared__ __align__(16) float Hs[32][68];
    __shared__ __align__(16) float Wk[64][132];
    __shared__ float red[32][17];
    __shared__ float normS[32];

    const int tid = threadIdx.x;
    const int ty = tid >> 4;
    const int tx = tid & 15;

    float acc[2][8];
#pragma unroll
    for (int jj = 0; jj < 8; ++jj){ acc[0][jj] = 0.f; acc[1][jj] = 0.f; }

    for (int kc = 0; kc < 4; ++kc){
#pragma unroll
        for (int i = 0; i < 8; ++i){
            int e = tid + i * 256;
            int rr = e >> 6, kk = e & 63;
            size_t idx = (size_t)(gstart + rr) * D2 + kc * 64 + kk;
            float hv = HP[idx] + HP[(size_t)NT * D2 + idx] + b1[kc * 64 + kk];
            Hs[rr][kk] = gelu_exact(hv);
        }
#pragma unroll
        for (int i = 0; i < 32; ++i){
            int e = tid + i * 256;
            int nn = e >> 6, kk = e & 63;
            Wk[kk][nn] = W2[(size_t)nn * D2 + kc * 64 + kk];
        }
        __syncthreads();
#pragma unroll
        for (int k4 = 0; k4 < 16; ++k4){
            float a0[4], a1[4];
            float4 t0 = *(const float4*)&Hs[ty * 2][k4 * 4];
            a0[0] = t0.x; a0[1] = t0.y; a0[2] = t0.z; a0[3] = t0.w;
            float4 t1 = *(const float4*)&Hs[ty * 2 + 1][k4 * 4];
            a1[0] = t1.x; a1[1] = t1.y; a1[2] = t1.z; a1[3] = t1.w;
#pragma unroll
            for (int kq = 0; kq < 4; ++kq){
                float4 w0 = *(const float4*)&Wk[k4 * 4 + kq][tx * 8];
                float4 w1 = *(const float4*)&Wk[k4 * 4 + kq][tx * 8 + 4];
                float wv[8] = {w0.x, w0.y, w0.z, w0.w, w1.x, w1.y, w1.z, w1.w};
#pragma unroll
                for (int jj = 0; jj < 8; ++jj){
                    acc[0][jj] += a0[kq] * wv[jj];
                    acc[1][jj] += a1[kq] * wv[jj];
                }
            }
        }
        __syncthreads();
    }
    float v0[8], v1[8];
    float sq0 = 0.f, sq1 = 0.f;
#pragma unroll
    for (int jj = 0; jj < 8; ++jj){
        int c = tx * 8 + jj;
        v0[jj] = acc[0][jj] + b2[c];
        v1[jj] = acc[1][jj] + b2[c];
        sq0 += v0[jj] * v0[jj];
        sq1 += v1[jj] * v1[jj];
    }
    red[ty * 2][tx]     = sq0;
    red[ty * 2 + 1][tx] = sq1;
    __syncthreads();
    if (tid < 32){
        float s = 0.f;
#pragma unroll
        for (int t = 0; t < 16; ++t) s += red[tid][t];
        normS[tid] = 1.0f / fmaxf(sqrtf(s), 1e-12f);
    }
    __syncthreads();
    float s0 = normS[ty * 2], s1 = normS[ty * 2 + 1];
    int row0 = gstart + ty * 2, row1 = row0 + 1;
    size_t o0 = (size_t)row0 * DD + tx * 8;
    size_t o1 = (size_t)row1 * DD + tx * 8;
    float z0[8], z1[8];
#pragma unroll
    for (int jj = 0; jj < 8; ++jj){ z0[jj] = v0[jj] * s0; z1[jj] = v1[jj] * s1; }
    float4 a = {z0[0], z0[1], z0[2], z0[3]}, b = {z0[4], z0[5], z0[6], z0[7]};
    float4 c = {z1[0], z1[1], z1[2], z1[3]}, d = {z1[4], z1[5], z1[6], z1[7]};
    *(float4*)&Z[o0]     = a;  *(float4*)&Z[o0 + 4] = b;
    *(float4*)&Z[o1]     = c;  *(float4*)&Z[o1 + 4] = d;
    uint4 p0 = {pack2bf(z0[0], z0[1]), pack2bf(z0[2], z0[3]),
                pack2bf(z0[4], z0[5]), pack2bf(z0[6], z0[7])};
    uint4 p1 = {pack2bf(z1[0], z1[1]), pack2bf(z1[2], z1[3]),
                pack2bf(z1[4], z1[5]), pack2bf(z1[6], z1[7])};
    *(uint4*)&Zbf[o0] = p0;
    *(uint4*)&Zbf[o1] = p1;
}

// ---------------- KT: ZbfT[d][r] = Zbf[NQ + r][d]  (r part only), tile 64x128.
__global__ __launch_bounds__(256)
void kT_transpose(const unsigned short* __restrict__ Zbf,
                  unsigned short* __restrict__ ZbfT){
    __shared__ unsigned short Ts[64][129];
    const int r0 = blockIdx.x * 64;
    const int tid = threadIdx.x;
#pragma unroll
    for (int i = 0; i < 32; ++i){
        int e = tid + i * 256;
        int rr = e >> 7, dd = e & 127;
        Ts[rr][dd] = Zbf[(size_t)(NQ + r0 + rr) * DD + dd];
    }
    __syncthreads();
#pragma unroll
    for (int i = 0; i < 32; ++i){
        int e = tid + i * 256;
        int dd = e >> 6, rr = e & 63;
        ZbfT[(size_t)dd * NQ + r0 + rr] = Ts[rr][dd];
    }
}

// ---------------- KA v9: flash attention, 32 q-rows/wave, V-prefetch.
__global__ __launch_bounds__(256, 2)
void kA_attn(const unsigned short* __restrict__ Zbf,
             const unsigned short* __restrict__ ZbfT,
             float* __restrict__ OP, float* __restrict__ LW){
    const int tid  = threadIdx.x;
    const int wave = tid >> 6, lane = tid & 63;
    const int quad = lane >> 4, col = lane & 15;
    const int m0   = blockIdx.x * 128 + wave * 32;
    const int split = blockIdx.y;
    const float scl = 0.08838834764831845f;   // 1/sqrt(128)

    __shared__ __align__(16) unsigned short Pt[4][2][16][72];  // per-wave, 2 m-subtiles

    s16x8 aq[2][4];
#pragma unroll
    for (int m = 0; m < 2; ++m)
#pragma unroll
        for (int kb = 0; kb < 4; ++kb)
            aq[m][kb] = *(const s16x8*)&Zbf[(size_t)(m0 + m * 16 + col) * DD + kb * 32 + quad * 8];

    f32x4 o[2][8];
#pragma unroll
    for (int m = 0; m < 2; ++m)
#pragma unroll
        for (int dt = 0; dt < 8; ++dt) o[m][dt] = (f32x4){0.f, 0.f, 0.f, 0.f};
    float lp[2][4] = {{0.f,0.f,0.f,0.f},{0.f,0.f,0.f,0.f}};
    float wp[2][4] = {{0.f,0.f,0.f,0.f},{0.f,0.f,0.f,0.f}};

    for (int it = 0; it < NIT; ++it){
        const int r0 = split * KPS + it * 64;

        s16x8 bv[8][2];
#pragma unroll
        for (int dt = 0; dt < 8; ++dt)
#pragma unroll
            for (int kb2 = 0; kb2 < 2; ++kb2)
                bv[dt][kb2] = *(const s16x8*)&ZbfT[(size_t)(dt * 16 + col) * NQ + r0 + kb2 * 32 + quad * 8];

#pragma unroll
        for (int nt = 0; nt < 4; ++nt){
            s16x8 b[4];
#pragma unroll
            for (int kb = 0; kb < 4; ++kb)
                b[kb] = *(const s16x8*)&Zbf[(size_t)(NQ + r0 + nt * 16 + col) * DD + kb * 32 + quad * 8];
#pragma unroll
            for (int m = 0; m < 2; ++m){
                f32x4 s = (f32x4){0.f, 0.f, 0.f, 0.f};
#pragma unroll
                for (int kb = 0; kb < 4; ++kb)
                    s = __builtin_amdgcn_mfma_f32_16x16x32_bf16(aq[m][kb], b[kb], s, 0, 0, 0);
#pragma unroll
                for (int reg = 0; reg < 4; ++reg){
                    float sv = s[reg] * scl;
                    float e  = __expf(sv);
                    lp[m][reg] += e;
                    wp[m][reg] += e * sv;
                    Pt[wave][m][quad * 4 + reg][nt * 16 + col] = f2bf(e);
                }
            }
        }

#pragma unroll
        for (int m = 0; m < 2; ++m){
            s16x8 ap[2];
#pragma unroll
            for (int kb2 = 0; kb2 < 2; ++kb2)
                ap[kb2] = *(const s16x8*)&Pt[wave][m][col][kb2 * 32 + quad * 8];
#pragma unroll
            for (int dt = 0; dt < 8; ++dt)
#pragma unroll
                for (int kb2 = 0; kb2 < 2; ++kb2)
                    o[m][dt] = __builtin_amdgcn_mfma_f32_16x16x32_bf16(ap[kb2], bv[dt][kb2], o[m][dt], 0, 0, 0);
        }
    }

#pragma unroll
    for (int m = 0; m < 2; ++m)
#pragma unroll
    for (int reg = 0; reg < 4; ++reg){
        float l = lp[m][reg], w = wp[m][reg];
        l += __shfl_xor(l, 8);  w += __shfl_xor(w, 8);
        l += __shfl_xor(l, 4);  w += __shfl_xor(w, 4);
        l += __shfl_xor(l, 2);  w += __shfl_xor(w, 2);
        l += __shfl_xor(l, 1);  w += __shfl_xor(w, 1);
        if (col == 0){
            int row = m0 + m * 16 + quad * 4 + reg;
            LW[((size_t)split * NQ + row) * 2]     = l;
            LW[((size_t)split * NQ + row) * 2 + 1] = w;
        }
    }
#pragma unroll
    for (int m = 0; m < 2; ++m)
#pragma unroll
    for (int dt = 0; dt < 8; ++dt){
#pragma unroll
        for (int reg = 0; reg < 4; ++reg){
            int row = m0 + m * 16 + quad * 4 + reg;
            OP[((size_t)split * NQ + row) * DD + dt * 16 + col] = o[m][dt][reg];
        }
    }
}

// ---------------- KC: combine NSPLIT splits -> r_bar, cos, u_n.
__global__ __launch_bounds__(128)
void kC_combine(const float* __restrict__ OP, const float* __restrict__ LW,
                const float* __restrict__ Z,
                float* __restrict__ RB, float* __restrict__ COS,
                float* __restrict__ ILW){
    const int r = blockIdx.x;
    const int c = threadIdx.x;
    float v = 0.f;
#pragma unroll
    for (int s = 0; s < NSPLIT; ++s) v += OP[((size_t)s * NQ + r) * DD + c];
    __shared__ float red[128];
    red[c] = v * v; __syncthreads();
    for (int off = 64; off > 0; off >>= 1){
        if (c < off) red[c] += red[c + off];
        __syncthreads();
    }
    float scale = 1.0f / fmaxf(sqrtf(red[0]), 1e-12f);
    __syncthreads();
    float rb = v * scale;
    RB[(size_t)r * DD + c] = rb;
    float zq = Z[(size_t)r * DD + c];
    red[c] = zq * rb; __syncthreads();
    for (int off = 64; off > 0; off >>= 1){
        if (c < off) red[c] += red[c + off];
        __syncthreads();
    }
    if (c == 0){
        COS[r] = red[0];
        float l = 0.f, w = 0.f;
#pragma unroll
        for (int s = 0; s < NSPLIT; ++s){
            l += LW[((size_t)s * NQ + r) * 2];
            w += LW[((size_t)s * NQ + r) * 2 + 1];
        }
        float ent = logf(l) - w / l;
        ILW[2 * r]     = 1.0f / l;
        ILW[2 * r + 1] = ent * (1.0f / 8.317766166719343f);  // / ln(4096)
    }
}

// ---------------- K8: decoder MLP (occupancy rewrite, unchanged from v7).
__global__ __launch_bounds__(256)
void k8_decoder(const float* __restrict__ Z, const float* __restrict__ RB,
                const float* __restrict__ ILW, const float* __restrict__ COS,
                const float* __restrict__ gd, const float* __restrict__ bd,
                const float* __restrict__ W1d, const float* __restrict__ b1d,
                const float* __restrict__ W2d, const float* __restrict__ b2d,
                const float* __restrict__ beta, const float* __restrict__ W_len,
                const float* __restrict__ b_len,
                float* __restrict__ out){
    const int r0 = blockIdx.x * 4;
    const int tid = threadIdx.x;
    const int wave = tid >> 6, lane = tid & 63;

    __shared__ __align__(16) float Xs[4][256];
    __shared__ float pr[4][2];

    {
        const int row = r0 + wave;
        const int c0 = lane * 4;
        float4 v;
        if (c0 < DD) v = *(const float4*)&Z[(size_t)row * DD + c0];
        else         v = *(const float4*)&RB[(size_t)row * DD + (c0 - DD)];
        float s  = v.x + v.y + v.z + v.w;
        float sq = v.x * v.x + v.y * v.y + v.z * v.z + v.w * v.w;
#pragma unroll
        for (int off = 32; off > 0; off >>= 1){
            s  += __shfl_xor(s, off);
            sq += __shfl_xor(sq, off);
        }
        float mean = s * (1.0f / D2);
        float var  = sq * (1.0f / D2) - mean * mean;
        float rstd = rsqrtf(fmaxf(var, 0.0f) + 1e-5f);
        float4 g = *(const float4*)&gd[c0];
        float4 b = *(const float4*)&bd[c0];
        float4 xn;
        xn.x = (v.x - mean) * rstd * g.x + b.x;
        xn.y = (v.y - mean) * rstd * g.y + b.y;
        xn.z = (v.z - mean) * rstd * g.z + b.z;
        xn.w = (v.w - mean) * rstd * g.w + b.w;
        *(float4*)&Xs[wave][c0] = xn;
    }
    __syncthreads();

    const int j  = tid & 127;
    const int rp = tid >> 7;
    const float* wrow = W1d + (size_t)j * D2;
    const float* xa = &Xs[rp * 2][0];
    const float* xb = &Xs[rp * 2 + 1][0];
    float h0 = 0.f, h1 = 0.f;
#pragma unroll 8
    for (int k = 0; k < D2; k += 4){
        float4 w  = *(const float4*)&wrow[k];
        float4 a4 = *(const float4*)&xa[k];
        float4 b4 = *(const float4*)&xb[k];
        h0 += w.x * a4.x + w.y * a4.y + w.z * a4.z + w.w * a4.w;
        h1 += w.x * b4.x + w.y * b4.y + w.z * b4.z + w.w * b4.w;
    }
    float bj = b1d[j];
    h0 = gelu_exact(h0 + bj);
    h1 = gelu_exact(h1 + bj);
    float w2 = W2d[j];
    float p0 = h0 * w2, p1 = h1 * w2;
#pragma unroll
    for (int off = 32; off > 0; off >>= 1){
        p0 += __shfl_xor(p0, off);
        p1 += __shfl_xor(p1, off);
    }
    if (lane == 0){ pr[wave][0] = p0; pr[wave][1] = p1; }
    __syncthreads();

    if (tid < 4){
        const int row   = tid;
        const int rpair = row >> 1, rlo = row & 1;
        float lg = b2d[0] + pr[rpair * 2][rlo] + pr[rpair * 2 + 1][rlo];
        const int gr = r0 + row;
        float u  = ILW[2 * gr + 1];
        float cv = COS[gr];
        float dln = cv * W_len[0] + u * W_len[1] + b_len[0];
        float dt = beta[0] * u + beta[1] * tanhf(dln);
        dt = fminf(0.5f, fmaxf(-0.5f, dt));
        out[gr]      = lg;
        out[NQ + gr] = dt;
    }
}

extern "C" void kernel_launch(void* const* d_in, const int* in_sizes, int n_in,
                              void* d_out, int out_size, void* d_ws, size_t ws_size,
                              hipStream_t stream){
    const float* q      = (const float*)d_in[0];
    const float* R      = (const float*)d_in[1];
    const float* ln_q_g = (const float*)d_in[2];
    const float* ln_q_b = (const float*)d_in[3];
    const float* W1q    = (const float*)d_in[4];
    const float* b1q    = (const float*)d_in[5];
    const float* W2q    = (const float*)d_in[6];
    const float* b2q    = (const float*)d_in[7];
    const float* ln_r_g = (const float*)d_in[8];
    const float* ln_r_b = (const float*)d_in[9];
    const float* W1r    = (const float*)d_in[10];
    const float* b1r    = (const float*)d_in[11];
    const float* W2r    = (const float*)d_in[12];
    const float* b2r    = (const float*)d_in[13];
    const float* ln_d_g = (const float*)d_in[14];
    const float* ln_d_b = (const float*)d_in[15];
    const float* W1d    = (const float*)d_in[16];
    const float* b1d    = (const float*)d_in[17];
    const float* W2d    = (const float*)d_in[18];
    const float* b2d    = (const float*)d_in[19];
    const float* beta   = (const float*)d_in[20];
    const float* W_len  = (const float*)d_in[21];
    const float* b_len  = (const float*)d_in[22];

    float* WS = (float*)d_ws;
    unsigned short* Xbf  = (unsigned short*)(WS);             // 8192*2048 bf16 = 8388608 fl
    float* OP    = WS;                                        // [16][4096][128] aliases Xbf (dead after k2) — exact fit
    float* HP    = WS + 8388608;                              // 2*8192*256
    float* LW    = WS + 8388608;                              // [16][4096][2] aliases HP (dead after k3)
    unsigned short* Wbf  = (unsigned short*)(WS + 12582912);  // 512*2048 bf16
    float* Z     = WS + 13107200;                             // 8192*128
    unsigned short* Zbf  = (unsigned short*)(WS + 14155776);  // 8192*128 bf16
    unsigned short* ZbfT = (unsigned short*)(WS + 14680064);  // 128*4096 bf16
    float* RB    = WS + 14942208;                             // 4096*128
    float* COSV  = WS + 15466496;                             // 4096
    float* ILW   = WS + 15470592;                             // 4096*2
    float* out   = (float*)d_out;

    hipLaunchKernelGGL(kLN_cast, dim3(NT + 512), dim3(256), 0, stream,
                       q, R, ln_q_g, ln_q_b, ln_r_g, ln_r_b, W1q, W1r, Xbf, Wbf);
    hipLaunchKernelGGL(k2_mfma, dim3(128, 2, 2), dim3(256), 0, stream, Xbf, Wbf, HP);
    hipLaunchKernelGGL(k3_gemm2, dim3(256), dim3(256), 0, stream,
                       HP, b1q, b1r, W2q, b2q, W2r, b2r, Z, Zbf);
    hipLaunchKernelGGL(kT_transpose, dim3(64), dim3(256), 0, stream, Zbf, ZbfT);
    hipLaunchKernelGGL(kA_attn, dim3(32, NSPLIT), dim3(256), 0, stream, Zbf, ZbfT, OP, LW);
    hipLaunchKernelGGL(kC_combine, dim3(NQ), dim3(128), 0, stream, OP, LW, Z, RB, COSV, ILW);
    hipLaunchKernelGGL(k8_decoder, dim3(1024), dim3(256), 0, stream,
                       Z, RB, ILW, COSV, ln_d_g, ln_d_b, W1d, b1d, W2d, b2d,
                       beta, W_len, b_len, out);
}

// Round 8
// 263.568 us; speedup vs baseline: 1.1659x; 1.0379x over previous
//
#include <hip/hip_runtime.h>
#include <math.h>

// RouterLite v12 = v11 with kA_attn rewritten with block-shared LDS staging.
// v11 post-mortem: k2 fix landed exactly as predicted (-34us) -> scatter
// diagnosis validated. kA has the same disease PLUS 4x redundancy: all 4
// waves read the same K/V tiles from global (r0 indep of wave).
// v12 kA: stage K-tile (64x128 bf16, 16KB) + V-tile (128x64, 16KB) once per
// block per it via global_load_lds w=16, XOR-swizzled source + ds_read
// (K: c^=row&15, V: c^=row&7 -> 2-way bank alias = free). Single-buffered,
// 2 barriers/it, LDS 50KB -> 3 blocks/CU covers stage stalls. V-frag LDS
// reads halved by hoisting P-frags out of dt loop. Q frags stay in regs.
//
// ws map (float offsets), total ~61.9 MB:
//   Xbf  @0         [8192][2048] bf16 (8388608 fl) — dead after k2_mfma,
//                   ALIASED by OP @0 [16][4096][128] fp32 (exact fit)
//   HP   @8388608   [2][8192][256] fp32 partials (k2->k3, dead after),
//                   ALIASED by LW @8388608 [16][4096][2] fp32 (kA->kC)
//   Wbf  @12582912  [512][2048] bf16 (W1q rows 0..255, W1r 256..511)
//   Z    @13107200  [8192][128] fp32
//   Zbf  @14155776  [8192][128] bf16
//   ZbfT @14680064  [128][4096] bf16 (Z_r transposed)
//   RB   @14942208  [4096][128]
//   COS  @15466496  [4096]
//   ILW  @15470592  [4096][2]
// d_out: fp32, [0..4095]=raw_logit, [4096..8191]=delta_theta.

#define HD   2048
#define D2   256
#define DD   128
#define NQ   4096
#define NT   8192
#define NSPLIT 16
#define KPS  (NQ / NSPLIT)   // 256 K-rows per split
#define NIT  (KPS / 64)      // 4 iterations of 64 K-rows

typedef __attribute__((ext_vector_type(8))) short s16x8;
typedef __attribute__((ext_vector_type(4))) float f32x4;

static __device__ __forceinline__ float gelu_exact(float x){
    return 0.5f * x * (1.0f + erff(x * 0.7071067811865475f));
}
static __device__ __forceinline__ unsigned short f2bf(float f){
    unsigned int u = __float_as_uint(f);
    return (unsigned short)((u + 0x7FFFu + ((u >> 16) & 1u)) >> 16);
}
static __device__ __forceinline__ unsigned int pack2bf(float a, float b){
    return (unsigned int)f2bf(a) | ((unsigned int)f2bf(b) << 16);
}

static __device__ __forceinline__ void gload_lds16(const void* g, void* l){
    __builtin_amdgcn_global_load_lds(
        (const __attribute__((address_space(1))) unsigned int*)g,
        (__attribute__((address_space(3))) unsigned int*)l, 16, 0, 0);
}

// ---------------- KLN: LN(x) -> bf16 Xbf (blocks 0..8191); W1 -> bf16 Wbf (8192..8703)
__global__ __launch_bounds__(256)
void kLN_cast(const float* __restrict__ q, const float* __restrict__ R,
              const float* __restrict__ gq, const float* __restrict__ bq,
              const float* __restrict__ gr, const float* __restrict__ br,
              const float* __restrict__ W1q, const float* __restrict__ W1r,
              unsigned short* __restrict__ Xbf, unsigned short* __restrict__ Wbf){
    const int r = blockIdx.x;
    const int tid = threadIdx.x;
    if (r >= NT){
        const int rw = r - NT;
        const float* src = (rw >= 256) ? (W1r + (size_t)(rw - 256) * HD)
                                       : (W1q + (size_t)rw * HD);
        float4 a = *(const float4*)&src[tid * 8];
        float4 c = *(const float4*)&src[tid * 8 + 4];
        uint4 p = {pack2bf(a.x, a.y), pack2bf(a.z, a.w),
                   pack2bf(c.x, c.y), pack2bf(c.z, c.w)};
        *(uint4*)&Wbf[(size_t)rw * HD + tid * 8] = p;
        return;
    }
    const float* src = (r < NQ) ? (q + (size_t)r * HD) : (R + (size_t)(r - NQ) * HD);
    const float* g  = (r < NQ) ? gq : gr;
    const float* bb = (r < NQ) ? bq : br;
    float4 x0 = *(const float4*)&src[tid * 8];
    float4 x1 = *(const float4*)&src[tid * 8 + 4];
    float v[8] = {x0.x, x0.y, x0.z, x0.w, x1.x, x1.y, x1.z, x1.w};
    float s = 0.f, sq = 0.f;
#pragma unroll
    for (int i = 0; i < 8; ++i){ s += v[i]; sq += v[i] * v[i]; }
    __shared__ float red[256];
    __shared__ float mS, rS;
    red[tid] = s; __syncthreads();
    for (int off = 128; off > 0; off >>= 1){
        if (tid < off) red[tid] += red[tid + off];
        __syncthreads();
    }
    float sum = red[0]; __syncthreads();
    red[tid] = sq; __syncthreads();
    for (int off = 128; off > 0; off >>= 1){
        if (tid < off) red[tid] += red[tid + off];
        __syncthreads();
    }
    if (tid == 0){
        float mean = sum * (1.0f / HD);
        float var  = red[0] * (1.0f / HD) - mean * mean;
        mS = mean;
        rS = rsqrtf(fmaxf(var, 0.0f) + 1e-5f);
    }
    __syncthreads();
    float mean = mS, rstd = rS;
    float4 g0 = *(const float4*)&g[tid * 8];
    float4 g1 = *(const float4*)&g[tid * 8 + 4];
    float4 b0 = *(const float4*)&bb[tid * 8];
    float4 b1 = *(const float4*)&bb[tid * 8 + 4];
    float gg[8] = {g0.x, g0.y, g0.z, g0.w, g1.x, g1.y, g1.z, g1.w};
    float bv[8] = {b0.x, b0.y, b0.z, b0.w, b1.x, b1.y, b1.z, b1.w};
    float h[8];
#pragma unroll
    for (int i = 0; i < 8; ++i) h[i] = (v[i] - mean) * rstd * gg[i] + bv[i];
    uint4 p = {pack2bf(h[0], h[1]), pack2bf(h[2], h[3]),
               pack2bf(h[4], h[5]), pack2bf(h[6], h[7])};
    *(uint4*)&Xbf[(size_t)r * HD + tid * 8] = p;
}

// ---------------- K2 v11: HP[ks] = Xbf @ Wbf^T (K-half ks), LDS-staged.
__global__ __launch_bounds__(256)
void k2_mfma(const unsigned short* __restrict__ Xbf,
             const unsigned short* __restrict__ Wbf,
             float* __restrict__ HP){
    const int tid  = threadIdx.x;
    const int wave = tid >> 6, lane = tid & 63;
    const int quad = lane >> 4, col = lane & 15;
    const int mblk = blockIdx.x;
    const int nblk = blockIdx.y;
    const int ks   = blockIdx.z;
    const int inp  = mblk >> 6;
    const int mbase = mblk * 64;
    const int nbase = nblk * 128;
    const int wm = wave & 1, wn = wave >> 1;

    __shared__ __align__(16) char smem[49152];   // [2][ A 8192 | B 16384 ]

    const unsigned short* gA[2];
    const unsigned short* gB[4];
#pragma unroll
    for (int i = 0; i < 2; ++i){
        int s = i * 256 + wave * 64 + lane;
        int row = s >> 3, c = (s & 7) ^ (row & 7);
        gA[i] = Xbf + (size_t)(mbase + row) * HD + ks * 1024 + c * 8;
    }
#pragma unroll
    for (int j = 0; j < 4; ++j){
        int s = j * 256 + wave * 64 + lane;
        int row = s >> 3, c = (s & 7) ^ (row & 7);
        gB[j] = Wbf + (size_t)(inp * 256 + nbase + row) * HD + ks * 1024 + c * 8;
    }

#define K2_STAGE(d, k0)                                                        \
    {                                                                          \
        _Pragma("unroll")                                                      \
        for (int i = 0; i < 2; ++i)                                            \
            gload_lds16(gA[i] + (k0),                                          \
                        smem + (d) * 24576 + (i * 256 + wave * 64 + lane) * 16);\
        _Pragma("unroll")                                                      \
        for (int j = 0; j < 4; ++j)                                            \
            gload_lds16(gB[j] + (k0),                                          \
                        smem + (d) * 24576 + 8192 + (j * 256 + wave * 64 + lane) * 16);\
    }

    int aoff[2][2], boff[4][2];
#pragma unroll
    for (int mi = 0; mi < 2; ++mi){
        int ra = wm * 32 + mi * 16 + col;
#pragma unroll
        for (int kst = 0; kst < 2; ++kst){
            int cc = kst * 4 + quad;
            aoff[mi][kst] = ra * 128 + ((cc ^ (ra & 7)) << 4);
        }
    }
#pragma unroll
    for (int ni = 0; ni < 4; ++ni){
        int rb = wn * 64 + ni * 16 + col;
#pragma unroll
        for (int kst = 0; kst < 2; ++kst){
            int cc = kst * 4 + quad;
            boff[ni][kst] = rb * 128 + ((cc ^ (rb & 7)) << 4);
        }
    }

    f32x4 acc[2][4];
#pragma unroll
    for (int mi = 0; mi < 2; ++mi)
#pragma unroll
        for (int ni = 0; ni < 4; ++ni) acc[mi][ni] = (f32x4){0.f, 0.f, 0.f, 0.f};

    int cur = 0;
    K2_STAGE(0, 0);
    __syncthreads();
    for (int t = 0; t < 16; ++t){
        if (t < 15) K2_STAGE(cur ^ 1, (t + 1) * 64);
        const char* Ab = smem + cur * 24576;
        const char* Bb = Ab + 8192;
        s16x8 a[2][2], b[4][2];
#pragma unroll
        for (int mi = 0; mi < 2; ++mi)
#pragma unroll
            for (int kst = 0; kst < 2; ++kst)
                a[mi][kst] = *(const s16x8*)(Ab + aoff[mi][kst]);
#pragma unroll
        for (int ni = 0; ni < 4; ++ni)
#pragma unroll
            for (int kst = 0; kst < 2; ++kst)
                b[ni][kst] = *(const s16x8*)(Bb + boff[ni][kst]);
#pragma unroll
        for (int kst = 0; kst < 2; ++kst)
#pragma unroll
            for (int mi = 0; mi < 2; ++mi)
#pragma unroll
                for (int ni = 0; ni < 4; ++ni)
                    acc[mi][ni] = __builtin_amdgcn_mfma_f32_16x16x32_bf16(
                        a[mi][kst], b[ni][kst], acc[mi][ni], 0, 0, 0);
        __syncthreads();
        cur ^= 1;
    }
#undef K2_STAGE

    float* dst = HP + (size_t)ks * NT * D2;
#pragma unroll
    for (int mi = 0; mi < 2; ++mi){
#pragma unroll
        for (int ni = 0; ni < 4; ++ni){
#pragma unroll
            for (int reg = 0; reg < 4; ++reg){
                int m = mbase + wm * 32 + mi * 16 + quad * 4 + reg;
                int n = nbase + wn * 64 + ni * 16 + col;
                dst[(size_t)m * D2 + n] = acc[mi][ni][reg];
            }
        }
    }
}

// ---------------- K3: combine HP + bias + GELU, GEMM2, l2norm -> Z (fp32), Zbf (bf16)
__global__ __launch_bounds__(256)
void k3_gemm2(const float* __restrict__ HP,
              const float* __restrict__ b1q, const float* __restrict__ b1r,
              const float* __restrict__ W2q, const float* __restrict__ b2q,
              const float* __restrict__ W2r, const float* __restrict__ b2r,
              float* __restrict__ Z, unsigned short* __restrict__ Zbf){
    const int gstart = blockIdx.x * 32;
    const int inp = (gstart >= NQ) ? 1 : 0;
    const float* b1 = inp ? b1r : b1q;
    const float* W2 = inp ? W2r : W2q;
    const float* b2 = inp ? b2r : b2q;

    __shared__ __align__(16) float Hs[32][68];
    __shared__ __align__(16) float Wk[64][132];
    __shared__ float red[32][17];
    __shared__ float normS[32];

    const int tid = threadIdx.x;
    const int ty = tid >> 4;
    const int tx = tid & 15;

    float acc[2][8];
#pragma unroll
    for (int jj = 0; jj < 8; ++jj){ acc[0][jj] = 0.f; acc[1][jj] = 0.f; }

    for (int kc = 0; kc < 4; ++kc){
#pragma unroll
        for (int i = 0; i < 8; ++i){
            int e = tid + i * 256;
            int rr = e >> 6, kk = e & 63;
            size_t idx = (size_t)(gstart + rr) * D2 + kc * 64 + kk;
            float hv = HP[idx] + HP[(size_t)NT * D2 + idx] + b1[kc * 64 + kk];
            Hs[rr][kk] = gelu_exact(hv);
        }
#pragma unroll
        for (int i = 0; i < 32; ++i){
            int e = tid + i * 256;
            int nn = e >> 6, kk = e & 63;
            Wk[kk][nn] = W2[(size_t)nn * D2 + kc * 64 + kk];
        }
        __syncthreads();
#pragma unroll
        for (int k4 = 0; k4 < 16; ++k4){
            float a0[4], a1[4];
            float4 t0 = *(const float4*)&Hs[ty * 2][k4 * 4];
            a0[0] = t0.x; a0[1] = t0.y; a0[2] = t0.z; a0[3] = t0.w;
            float4 t1 = *(const float4*)&Hs[ty * 2 + 1][k4 * 4];
            a1[0] = t1.x; a1[1] = t1.y; a1[2] = t1.z; a1[3] = t1.w;
#pragma unroll
            for (int kq = 0; kq < 4; ++kq){
                float4 w0 = *(const float4*)&Wk[k4 * 4 + kq][tx * 8];
                float4 w1 = *(const float4*)&Wk[k4 * 4 + kq][tx * 8 + 4];
                float wv[8] = {w0.x, w0.y, w0.z, w0.w, w1.x, w1.y, w1.z, w1.w};
#pragma unroll
                for (int jj = 0; jj < 8; ++jj){
                    acc[0][jj] += a0[kq] * wv[jj];
                    acc[1][jj] += a1[kq] * wv[jj];
                }
            }
        }
        __syncthreads();
    }
    float v0[8], v1[8];
    float sq0 = 0.f, sq1 = 0.f;
#pragma unroll
    for (int jj = 0; jj < 8; ++jj){
        int c = tx * 8 + jj;
        v0[jj] = acc[0][jj] + b2[c];
        v1[jj] = acc[1][jj] + b2[c];
        sq0 += v0[jj] * v0[jj];
        sq1 += v1[jj] * v1[jj];
    }
    red[ty * 2][tx]     = sq0;
    red[ty * 2 + 1][tx] = sq1;
    __syncthreads();
    if (tid < 32){
        float s = 0.f;
#pragma unroll
        for (int t = 0; t < 16; ++t) s += red[tid][t];
        normS[tid] = 1.0f / fmaxf(sqrtf(s), 1e-12f);
    }
    __syncthreads();
    float s0 = normS[ty * 2], s1 = normS[ty * 2 + 1];
    int row0 = gstart + ty * 2, row1 = row0 + 1;
    size_t o0 = (size_t)row0 * DD + tx * 8;
    size_t o1 = (size_t)row1 * DD + tx * 8;
    float z0[8], z1[8];
#pragma unroll
    for (int jj = 0; jj < 8; ++jj){ z0[jj] = v0[jj] * s0; z1[jj] = v1[jj] * s1; }
    float4 a = {z0[0], z0[1], z0[2], z0[3]}, b = {z0[4], z0[5], z0[6], z0[7]};
    float4 c = {z1[0], z1[1], z1[2], z1[3]}, d = {z1[4], z1[5], z1[6], z1[7]};
    *(float4*)&Z[o0]     = a;  *(float4*)&Z[o0 + 4] = b;
    *(float4*)&Z[o1]     = c;  *(float4*)&Z[o1 + 4] = d;
    uint4 p0 = {pack2bf(z0[0], z0[1]), pack2bf(z0[2], z0[3]),
                pack2bf(z0[4], z0[5]), pack2bf(z0[6], z0[7])};
    uint4 p1 = {pack2bf(z1[0], z1[1]), pack2bf(z1[2], z1[3]),
                pack2bf(z1[4], z1[5]), pack2bf(z1[6], z1[7])};
    *(uint4*)&Zbf[o0] = p0;
    *(uint4*)&Zbf[o1] = p1;
}

// ---------------- KT: ZbfT[d][r] = Zbf[NQ + r][d]  (r part only), tile 64x128.
__global__ __launch_bounds__(256)
void kT_transpose(const unsigned short* __restrict__ Zbf,
                  unsigned short* __restrict__ ZbfT){
    __shared__ unsigned short Ts[64][129];
    const int r0 = blockIdx.x * 64;
    const int tid = threadIdx.x;
#pragma unroll
    for (int i = 0; i < 32; ++i){
        int e = tid + i * 256;
        int rr = e >> 7, dd = e & 127;
        Ts[rr][dd] = Zbf[(size_t)(NQ + r0 + rr) * DD + dd];
    }
    __syncthreads();
#pragma unroll
    for (int i = 0; i < 32; ++i){
        int e = tid + i * 256;
        int dd = e >> 6, rr = e & 63;
        ZbfT[(size_t)dd * NQ + r0 + rr] = Ts[rr][dd];
    }
}

// ---------------- KA v12: flash attention, block-shared LDS-staged K/V.
// Grid (32, NSPLIT), 4 waves x 32 q-rows = 128 q-rows/block. Per it:
// stage K-tile [64][128] (swz c^=row&15) + V-tile [128][64] (swz c^=row&7)
// once per block via global_load_lds; all 4 waves consume from LDS.
__global__ __launch_bounds__(256)
void kA_attn(const unsigned short* __restrict__ Zbf,
             const unsigned short* __restrict__ ZbfT,
             float* __restrict__ OP, float* __restrict__ LW){
    const int tid  = threadIdx.x;
    const int wave = tid >> 6, lane = tid & 63;
    const int quad = lane >> 4, col = lane & 15;
    const int m0   = blockIdx.x * 128 + wave * 32;
    const int split = blockIdx.y;
    const float scl = 0.08838834764831845f;   // 1/sqrt(128)

    __shared__ __align__(16) char sK[16384];   // 64 rows x 16 chunks(16B), swizzled
    __shared__ __align__(16) char sV[16384];   // 128 rows x 8 chunks(16B), swizzled
    __shared__ __align__(16) unsigned short Pt[4][2][16][72];

    // Q fragments (per wave, one-time global read).
    s16x8 aq[2][4];
#pragma unroll
    for (int m = 0; m < 2; ++m)
#pragma unroll
        for (int kb = 0; kb < 4; ++kb)
            aq[m][kb] = *(const s16x8*)&Zbf[(size_t)(m0 + m * 16 + col) * DD + kb * 32 + quad * 8];

    // Staging: 1024 K-slots + 1024 V-slots, 4 issues each per thread.
    const unsigned short* gK[4];
    const unsigned short* gV[4];
    int dK[4], dV[4];
#pragma unroll
    for (int i = 0; i < 4; ++i){
        int s = i * 256 + tid;
        int row = s >> 4, c = (s & 15) ^ (row & 15);
        gK[i] = Zbf + (size_t)(NQ + row) * DD + c * 8;   // + r0*DD per it
        dK[i] = s * 16;
        int s2 = i * 256 + tid;
        int rv = s2 >> 3, cv = (s2 & 7) ^ (rv & 7);
        gV[i] = ZbfT + (size_t)rv * NQ + cv * 8;         // + r0 per it
        dV[i] = s2 * 16;
    }

    // Swizzled ds_read offsets.
    int kOff[4][4];   // [nt][kb]
#pragma unroll
    for (int nt = 0; nt < 4; ++nt){
        int rb = nt * 16 + col;
#pragma unroll
        for (int kb = 0; kb < 4; ++kb)
            kOff[nt][kb] = rb * 256 + (((kb * 4 + quad) ^ (rb & 15)) << 4);
    }
    int vOff[8][2];   // [dt][kb2]
#pragma unroll
    for (int dt = 0; dt < 8; ++dt){
        int rv = dt * 16 + col;
#pragma unroll
        for (int kb2 = 0; kb2 < 2; ++kb2)
            vOff[dt][kb2] = rv * 128 + (((kb2 * 4 + quad) ^ (rv & 7)) << 4);
    }

    f32x4 o[2][8];
#pragma unroll
    for (int m = 0; m < 2; ++m)
#pragma unroll
        for (int dt = 0; dt < 8; ++dt) o[m][dt] = (f32x4){0.f, 0.f, 0.f, 0.f};
    float lp[2][4] = {{0.f,0.f,0.f,0.f},{0.f,0.f,0.f,0.f}};
    float wp[2][4] = {{0.f,0.f,0.f,0.f},{0.f,0.f,0.f,0.f}};

    for (int it = 0; it < NIT; ++it){
        const int r0 = split * KPS + it * 64;
        // ---- stage K and V tiles (block-cooperative).
#pragma unroll
        for (int i = 0; i < 4; ++i)
            gload_lds16(gK[i] + (size_t)r0 * DD, sK + dK[i]);
#pragma unroll
        for (int i = 0; i < 4; ++i)
            gload_lds16(gV[i] + r0, sV + dV[i]);
        __syncthreads();   // drains vmcnt -> tiles visible

        // ---- QK^T + exp for both m-subtiles (K from LDS).
#pragma unroll
        for (int nt = 0; nt < 4; ++nt){
            s16x8 b[4];
#pragma unroll
            for (int kb = 0; kb < 4; ++kb)
                b[kb] = *(const s16x8*)(sK + kOff[nt][kb]);
#pragma unroll
            for (int m = 0; m < 2; ++m){
                f32x4 s = (f32x4){0.f, 0.f, 0.f, 0.f};
#pragma unroll
                for (int kb = 0; kb < 4; ++kb)
                    s = __builtin_amdgcn_mfma_f32_16x16x32_bf16(aq[m][kb], b[kb], s, 0, 0, 0);
#pragma unroll
                for (int reg = 0; reg < 4; ++reg){
                    float sv = s[reg] * scl;
                    float e  = __expf(sv);
                    lp[m][reg] += e;
                    wp[m][reg] += e * sv;
                    Pt[wave][m][quad * 4 + reg][nt * 16 + col] = f2bf(e);
                }
            }
        }

        // ---- PV (V from LDS; P-frags hoisted, V-frag shared across m).
        s16x8 ap[2][2];
#pragma unroll
        for (int m = 0; m < 2; ++m)
#pragma unroll
            for (int kb2 = 0; kb2 < 2; ++kb2)
                ap[m][kb2] = *(const s16x8*)&Pt[wave][m][col][kb2 * 32 + quad * 8];
#pragma unroll
        for (int dt = 0; dt < 8; ++dt){
#pragma unroll
            for (int kb2 = 0; kb2 < 2; ++kb2){
                s16x8 b = *(const s16x8*)(sV + vOff[dt][kb2]);
                o[0][dt] = __builtin_amdgcn_mfma_f32_16x16x32_bf16(ap[0][kb2], b, o[0][dt], 0, 0, 0);
                o[1][dt] = __builtin_amdgcn_mfma_f32_16x16x32_bf16(ap[1][kb2], b, o[1][dt], 0, 0, 0);
            }
        }
        __syncthreads();   // all waves done reading before next stage
    }

#pragma unroll
    for (int m = 0; m < 2; ++m)
#pragma unroll
    for (int reg = 0; reg < 4; ++reg){
        float l = lp[m][reg], w = wp[m][reg];
        l += __shfl_xor(l, 8);  w += __shfl_xor(w, 8);
        l += __shfl_xor(l, 4);  w += __shfl_xor(w, 4);
        l += __shfl_xor(l, 2);  w += __shfl_xor(w, 2);
        l += __shfl_xor(l, 1);  w += __shfl_xor(w, 1);
        if (col == 0){
            int row = m0 + m * 16 + quad * 4 + reg;
            LW[((size_t)split * NQ + row) * 2]     = l;
            LW[((size_t)split * NQ + row) * 2 + 1] = w;
        }
    }
#pragma unroll
    for (int m = 0; m < 2; ++m)
#pragma unroll
    for (int dt = 0; dt < 8; ++dt){
#pragma unroll
        for (int reg = 0; reg < 4; ++reg){
            int row = m0 + m * 16 + quad * 4 + reg;
            OP[((size_t)split * NQ + row) * DD + dt * 16 + col] = o[m][dt][reg];
        }
    }
}

// ---------------- KC: combine NSPLIT splits -> r_bar, cos, u_n.
__global__ __launch_bounds__(128)
void kC_combine(const float* __restrict__ OP, const float* __restrict__ LW,
                const float* __restrict__ Z,
                float* __restrict__ RB, float* __restrict__ COS,
                float* __restrict__ ILW){
    const int r = blockIdx.x;
    const int c = threadIdx.x;
    float v = 0.f;
#pragma unroll
    for (int s = 0; s < NSPLIT; ++s) v += OP[((size_t)s * NQ + r) * DD + c];
    __shared__ float red[128];
    red[c] = v * v; __syncthreads();
    for (int off = 64; off > 0; off >>= 1){
        if (c < off) red[c] += red[c + off];
        __syncthreads();
    }
    float scale = 1.0f / fmaxf(sqrtf(red[0]), 1e-12f);
    __syncthreads();
    float rb = v * scale;
    RB[(size_t)r * DD + c] = rb;
    float zq = Z[(size_t)r * DD + c];
    red[c] = zq * rb; __syncthreads();
    for (int off = 64; off > 0; off >>= 1){
        if (c < off) red[c] += red[c + off];
        __syncthreads();
    }
    if (c == 0){
        COS[r] = red[0];
        float l = 0.f, w = 0.f;
#pragma unroll
        for (int s = 0; s < NSPLIT; ++s){
            l += LW[((size_t)s * NQ + r) * 2];
            w += LW[((size_t)s * NQ + r) * 2 + 1];
        }
        float ent = logf(l) - w / l;
        ILW[2 * r]     = 1.0f / l;
        ILW[2 * r + 1] = ent * (1.0f / 8.317766166719343f);  // / ln(4096)
    }
}

// ---------------- K8: decoder MLP (occupancy rewrite, unchanged from v7).
__global__ __launch_bounds__(256)
void k8_decoder(const float* __restrict__ Z, const float* __restrict__ RB,
                const float* __restrict__ ILW, const float* __restrict__ COS,
                const float* __restrict__ gd, const float* __restrict__ bd,
                const float* __restrict__ W1d, const float* __restrict__ b1d,
                const float* __restrict__ W2d, const float* __restrict__ b2d,
                const float* __restrict__ beta, const float* __restrict__ W_len,
                const float* __restrict__ b_len,
                float* __restrict__ out){
    const int r0 = blockIdx.x * 4;
    const int tid = threadIdx.x;
    const int wave = tid >> 6, lane = tid & 63;

    __shared__ __align__(16) float Xs[4][256];
    __shared__ float pr[4][2];

    {
        const int row = r0 + wave;
        const int c0 = lane * 4;
        float4 v;
        if (c0 < DD) v = *(const float4*)&Z[(size_t)row * DD + c0];
        else         v = *(const float4*)&RB[(size_t)row * DD + (c0 - DD)];
        float s  = v.x + v.y + v.z + v.w;
        float sq = v.x * v.x + v.y * v.y + v.z * v.z + v.w * v.w;
#pragma unroll
        for (int off = 32; off > 0; off >>= 1){
            s  += __shfl_xor(s, off);
            sq += __shfl_xor(sq, off);
        }
        float mean = s * (1.0f / D2);
        float var  = sq * (1.0f / D2) - mean * mean;
        float rstd = rsqrtf(fmaxf(var, 0.0f) + 1e-5f);
        float4 g = *(const float4*)&gd[c0];
        float4 b = *(const float4*)&bd[c0];
        float4 xn;
        xn.x = (v.x - mean) * rstd * g.x + b.x;
        xn.y = (v.y - mean) * rstd * g.y + b.y;
        xn.z = (v.z - mean) * rstd * g.z + b.z;
        xn.w = (v.w - mean) * rstd * g.w + b.w;
        *(float4*)&Xs[wave][c0] = xn;
    }
    __syncthreads();

    const int j  = tid & 127;
    const int rp = tid >> 7;
    const float* wrow = W1d + (size_t)j * D2;
    const float* xa = &Xs[rp * 2][0];
    const float* xb = &Xs[rp * 2 + 1][0];
    float h0 = 0.f, h1 = 0.f;
#pragma unroll 8
    for (int k = 0; k < D2; k += 4){
        float4 w  = *(const float4*)&wrow[k];
        float4 a4 = *(const float4*)&xa[k];
        float4 b4 = *(const float4*)&xb[k];
        h0 += w.x * a4.x + w.y * a4.y + w.z * a4.z + w.w * a4.w;
        h1 += w.x * b4.x + w.y * b4.y + w.z * b4.z + w.w * b4.w;
    }
    float bj = b1d[j];
    h0 = gelu_exact(h0 + bj);
    h1 = gelu_exact(h1 + bj);
    float w2 = W2d[j];
    float p0 = h0 * w2, p1 = h1 * w2;
#pragma unroll
    for (int off = 32; off > 0; off >>= 1){
        p0 += __shfl_xor(p0, off);
        p1 += __shfl_xor(p1, off);
    }
    if (lane == 0){ pr[wave][0] = p0; pr[wave][1] = p1; }
    __syncthreads();

    if (tid < 4){
        const int row   = tid;
        const int rpair = row >> 1, rlo = row & 1;
        float lg = b2d[0] + pr[rpair * 2][rlo] + pr[rpair * 2 + 1][rlo];
        const int gr = r0 + row;
        float u  = ILW[2 * gr + 1];
        float cv = COS[gr];
        float dln = cv * W_len[0] + u * W_len[1] + b_len[0];
        float dt = beta[0] * u + beta[1] * tanhf(dln);
        dt = fminf(0.5f, fmaxf(-0.5f, dt));
        out[gr]      = lg;
        out[NQ + gr] = dt;
    }
}

extern "C" void kernel_launch(void* const* d_in, const int* in_sizes, int n_in,
                              void* d_out, int out_size, void* d_ws, size_t ws_size,
                              hipStream_t stream){
    const float* q      = (const float*)d_in[0];
    const float* R      = (const float*)d_in[1];
    const float* ln_q_g = (const float*)d_in[2];
    const float* ln_q_b = (const float*)d_in[3];
    const float* W1q    = (const float*)d_in[4];
    const float* b1q    = (const float*)d_in[5];
    const float* W2q    = (const float*)d_in[6];
    const float* b2q    = (const float*)d_in[7];
    const float* ln_r_g = (const float*)d_in[8];
    const float* ln_r_b = (const float*)d_in[9];
    const float* W1r    = (const float*)d_in[10];
    const float* b1r    = (const float*)d_in[11];
    const float* W2r    = (const float*)d_in[12];
    const float* b2r    = (const float*)d_in[13];
    const float* ln_d_g = (const float*)d_in[14];
    const float* ln_d_b = (const float*)d_in[15];
    const float* W1d    = (const float*)d_in[16];
    const float* b1d    = (const float*)d_in[17];
    const float* W2d    = (const float*)d_in[18];
    const float* b2d    = (const float*)d_in[19];
    const float* beta   = (const float*)d_in[20];
    const float* W_len  = (const float*)d_in[21];
    const float* b_len  = (const float*)d_in[22];

    float* WS = (float*)d_ws;
    unsigned short* Xbf  = (unsigned short*)(WS);             // 8192*2048 bf16 = 8388608 fl
    float* OP    = WS;                                        // [16][4096][128] aliases Xbf (dead after k2) — exact fit
    float* HP    = WS + 8388608;                              // 2*8192*256
    float* LW    = WS + 8388608;                              // [16][4096][2] aliases HP (dead after k3)
    unsigned short* Wbf  = (unsigned short*)(WS + 12582912);  // 512*2048 bf16
    float* Z     = WS + 13107200;                             // 8192*128
    unsigned short* Zbf  = (unsigned short*)(WS + 14155776);  // 8192*128 bf16
    unsigned short* ZbfT = (unsigned short*)(WS + 14680064);  // 128*4096 bf16
    float* RB    = WS + 14942208;                             // 4096*128
    float* COSV  = WS + 15466496;                             // 4096
    float* ILW   = WS + 15470592;                             // 4096*2
    float* out   = (float*)d_out;

    hipLaunchKernelGGL(kLN_cast, dim3(NT + 512), dim3(256), 0, stream,
                       q, R, ln_q_g, ln_q_b, ln_r_g, ln_r_b, W1q, W1r, Xbf, Wbf);
    hipLaunchKernelGGL(k2_mfma, dim3(128, 2, 2), dim3(256), 0, stream, Xbf, Wbf, HP);
    hipLaunchKernelGGL(k3_gemm2, dim3(256), dim3(256), 0, stream,
                       HP, b1q, b1r, W2q, b2q, W2r, b2r, Z, Zbf);
    hipLaunchKernelGGL(kT_transpose, dim3(64), dim3(256), 0, stream, Zbf, ZbfT);
    hipLaunchKernelGGL(kA_attn, dim3(32, NSPLIT), dim3(256), 0, stream, Zbf, ZbfT, OP, LW);
    hipLaunchKernelGGL(kC_combine, dim3(NQ), dim3(128), 0, stream, OP, LW, Z, RB, COSV, ILW);
    hipLaunchKernelGGL(k8_decoder, dim3(1024), dim3(256), 0, stream,
                       Z, RB, ILW, COSV, ln_d_g, ln_d_b, W1d, b1d, W2d, b2d,
                       beta, W_len, b_len, out);
}

// Round 9
// 260.815 us; speedup vs baseline: 1.1783x; 1.0106x over previous
//
#include <hip/hip_runtime.h>
#include <math.h>

// RouterLite v13 = v12 with the three untouched "auxiliary" kernels de-barriered.
// Accounting: round-0 counters show {kLN,k3,kT,kC}+overhead ~= 165us of total;
// after k8/kA/k2 fixes these dominate. Shared disease = barrier/occupancy
// latency: kLN had 16 syncthreads/block (2 sequential LDS trees), k3 had
// grid 256 = 1 block/CU with 8 barriers, kC had ~15 barriers + serial LW loop.
// v13: kLN -> shfl reduce (1 barrier); k3 -> 16 rows/block, 512 blocks
// (2/CU, cross-block overlap); kC -> shfl reduce + parallel LW (2 barriers).
// k2/kA/kT/k8 unchanged from v12.
//
// ws map (float offsets), total ~61.9 MB:
//   Xbf  @0         [8192][2048] bf16 (8388608 fl) — dead after k2_mfma,
//                   ALIASED by OP @0 [16][4096][128] fp32 (exact fit)
//   HP   @8388608   [2][8192][256] fp32 partials (k2->k3, dead after),
//                   ALIASED by LW @8388608 [16][4096][2] fp32 (kA->kC)
//   Wbf  @12582912  [512][2048] bf16 (W1q rows 0..255, W1r 256..511)
//   Z    @13107200  [8192][128] fp32
//   Zbf  @14155776  [8192][128] bf16
//   ZbfT @14680064  [128][4096] bf16 (Z_r transposed)
//   RB   @14942208  [4096][128]
//   COS  @15466496  [4096]
//   ILW  @15470592  [4096][2]
// d_out: fp32, [0..4095]=raw_logit, [4096..8191]=delta_theta.

#define HD   2048
#define D2   256
#define DD   128
#define NQ   4096
#define NT   8192
#define NSPLIT 16
#define KPS  (NQ / NSPLIT)   // 256 K-rows per split
#define NIT  (KPS / 64)      // 4 iterations of 64 K-rows

typedef __attribute__((ext_vector_type(8))) short s16x8;
typedef __attribute__((ext_vector_type(4))) float f32x4;

static __device__ __forceinline__ float gelu_exact(float x){
    return 0.5f * x * (1.0f + erff(x * 0.7071067811865475f));
}
static __device__ __forceinline__ unsigned short f2bf(float f){
    unsigned int u = __float_as_uint(f);
    return (unsigned short)((u + 0x7FFFu + ((u >> 16) & 1u)) >> 16);
}
static __device__ __forceinline__ unsigned int pack2bf(float a, float b){
    return (unsigned int)f2bf(a) | ((unsigned int)f2bf(b) << 16);
}

static __device__ __forceinline__ void gload_lds16(const void* g, void* l){
    __builtin_amdgcn_global_load_lds(
        (const __attribute__((address_space(1))) unsigned int*)g,
        (__attribute__((address_space(3))) unsigned int*)l, 16, 0, 0);
}

// ---------------- KLN v13: LN(x) -> bf16 Xbf; W1 -> bf16 Wbf.
// Wave-shfl reduction of sum+sumsq together, 1 barrier (was 16).
__global__ __launch_bounds__(256)
void kLN_cast(const float* __restrict__ q, const float* __restrict__ R,
              const float* __restrict__ gq, const float* __restrict__ bq,
              const float* __restrict__ gr, const float* __restrict__ br,
              const float* __restrict__ W1q, const float* __restrict__ W1r,
              unsigned short* __restrict__ Xbf, unsigned short* __restrict__ Wbf){
    const int r = blockIdx.x;
    const int tid = threadIdx.x;
    if (r >= NT){
        const int rw = r - NT;
        const float* src = (rw >= 256) ? (W1r + (size_t)(rw - 256) * HD)
                                       : (W1q + (size_t)rw * HD);
        float4 a = *(const float4*)&src[tid * 8];
        float4 c = *(const float4*)&src[tid * 8 + 4];
        uint4 p = {pack2bf(a.x, a.y), pack2bf(a.z, a.w),
                   pack2bf(c.x, c.y), pack2bf(c.z, c.w)};
        *(uint4*)&Wbf[(size_t)rw * HD + tid * 8] = p;
        return;
    }
    const float* src = (r < NQ) ? (q + (size_t)r * HD) : (R + (size_t)(r - NQ) * HD);
    const float* g  = (r < NQ) ? gq : gr;
    const float* bb = (r < NQ) ? bq : br;
    float4 x0 = *(const float4*)&src[tid * 8];
    float4 x1 = *(const float4*)&src[tid * 8 + 4];
    float v[8] = {x0.x, x0.y, x0.z, x0.w, x1.x, x1.y, x1.z, x1.w};
    float s = 0.f, sq = 0.f;
#pragma unroll
    for (int i = 0; i < 8; ++i){ s += v[i]; sq += v[i] * v[i]; }
#pragma unroll
    for (int off = 32; off > 0; off >>= 1){
        s  += __shfl_xor(s, off);
        sq += __shfl_xor(sq, off);
    }
    __shared__ float wS[4], wQ[4];
    const int wave = tid >> 6, lane = tid & 63;
    if (lane == 0){ wS[wave] = s; wQ[wave] = sq; }
    __syncthreads();
    float sum = wS[0] + wS[1] + wS[2] + wS[3];
    float sqs = wQ[0] + wQ[1] + wQ[2] + wQ[3];
    float mean = sum * (1.0f / HD);
    float var  = sqs * (1.0f / HD) - mean * mean;
    float rstd = rsqrtf(fmaxf(var, 0.0f) + 1e-5f);
    float4 g0 = *(const float4*)&g[tid * 8];
    float4 g1 = *(const float4*)&g[tid * 8 + 4];
    float4 b0 = *(const float4*)&bb[tid * 8];
    float4 b1 = *(const float4*)&bb[tid * 8 + 4];
    float gg[8] = {g0.x, g0.y, g0.z, g0.w, g1.x, g1.y, g1.z, g1.w};
    float bv[8] = {b0.x, b0.y, b0.z, b0.w, b1.x, b1.y, b1.z, b1.w};
    float h[8];
#pragma unroll
    for (int i = 0; i < 8; ++i) h[i] = (v[i] - mean) * rstd * gg[i] + bv[i];
    uint4 p = {pack2bf(h[0], h[1]), pack2bf(h[2], h[3]),
               pack2bf(h[4], h[5]), pack2bf(h[6], h[7])};
    *(uint4*)&Xbf[(size_t)r * HD + tid * 8] = p;
}

// ---------------- K2 v11: HP[ks] = Xbf @ Wbf^T (K-half ks), LDS-staged.
__global__ __launch_bounds__(256)
void k2_mfma(const unsigned short* __restrict__ Xbf,
             const unsigned short* __restrict__ Wbf,
             float* __restrict__ HP){
    const int tid  = threadIdx.x;
    const int wave = tid >> 6, lane = tid & 63;
    const int quad = lane >> 4, col = lane & 15;
    const int mblk = blockIdx.x;
    const int nblk = blockIdx.y;
    const int ks   = blockIdx.z;
    const int inp  = mblk >> 6;
    const int mbase = mblk * 64;
    const int nbase = nblk * 128;
    const int wm = wave & 1, wn = wave >> 1;

    __shared__ __align__(16) char smem[49152];   // [2][ A 8192 | B 16384 ]

    const unsigned short* gA[2];
    const unsigned short* gB[4];
#pragma unroll
    for (int i = 0; i < 2; ++i){
        int s = i * 256 + wave * 64 + lane;
        int row = s >> 3, c = (s & 7) ^ (row & 7);
        gA[i] = Xbf + (size_t)(mbase + row) * HD + ks * 1024 + c * 8;
    }
#pragma unroll
    for (int j = 0; j < 4; ++j){
        int s = j * 256 + wave * 64 + lane;
        int row = s >> 3, c = (s & 7) ^ (row & 7);
        gB[j] = Wbf + (size_t)(inp * 256 + nbase + row) * HD + ks * 1024 + c * 8;
    }

#define K2_STAGE(d, k0)                                                        \
    {                                                                          \
        _Pragma("unroll")                                                      \
        for (int i = 0; i < 2; ++i)                                            \
            gload_lds16(gA[i] + (k0),                                          \
                        smem + (d) * 24576 + (i * 256 + wave * 64 + lane) * 16);\
        _Pragma("unroll")                                                      \
        for (int j = 0; j < 4; ++j)                                            \
            gload_lds16(gB[j] + (k0),                                          \
                        smem + (d) * 24576 + 8192 + (j * 256 + wave * 64 + lane) * 16);\
    }

    int aoff[2][2], boff[4][2];
#pragma unroll
    for (int mi = 0; mi < 2; ++mi){
        int ra = wm * 32 + mi * 16 + col;
#pragma unroll
        for (int kst = 0; kst < 2; ++kst){
            int cc = kst * 4 + quad;
            aoff[mi][kst] = ra * 128 + ((cc ^ (ra & 7)) << 4);
        }
    }
#pragma unroll
    for (int ni = 0; ni < 4; ++ni){
        int rb = wn * 64 + ni * 16 + col;
#pragma unroll
        for (int kst = 0; kst < 2; ++kst){
            int cc = kst * 4 + quad;
            boff[ni][kst] = rb * 128 + ((cc ^ (rb & 7)) << 4);
        }
    }

    f32x4 acc[2][4];
#pragma unroll
    for (int mi = 0; mi < 2; ++mi)
#pragma unroll
        for (int ni = 0; ni < 4; ++ni) acc[mi][ni] = (f32x4){0.f, 0.f, 0.f, 0.f};

    int cur = 0;
    K2_STAGE(0, 0);
    __syncthreads();
    for (int t = 0; t < 16; ++t){
        if (t < 15) K2_STAGE(cur ^ 1, (t + 1) * 64);
        const char* Ab = smem + cur * 24576;
        const char* Bb = Ab + 8192;
        s16x8 a[2][2], b[4][2];
#pragma unroll
        for (int mi = 0; mi < 2; ++mi)
#pragma unroll
            for (int kst = 0; kst < 2; ++kst)
                a[mi][kst] = *(const s16x8*)(Ab + aoff[mi][kst]);
#pragma unroll
        for (int ni = 0; ni < 4; ++ni)
#pragma unroll
            for (int kst = 0; kst < 2; ++kst)
                b[ni][kst] = *(const s16x8*)(Bb + boff[ni][kst]);
#pragma unroll
        for (int kst = 0; kst < 2; ++kst)
#pragma unroll
            for (int mi = 0; mi < 2; ++mi)
#pragma unroll
                for (int ni = 0; ni < 4; ++ni)
                    acc[mi][ni] = __builtin_amdgcn_mfma_f32_16x16x32_bf16(
                        a[mi][kst], b[ni][kst], acc[mi][ni], 0, 0, 0);
        __syncthreads();
        cur ^= 1;
    }
#undef K2_STAGE

    float* dst = HP + (size_t)ks * NT * D2;
#pragma unroll
    for (int mi = 0; mi < 2; ++mi){
#pragma unroll
        for (int ni = 0; ni < 4; ++ni){
#pragma unroll
            for (int reg = 0; reg < 4; ++reg){
                int m = mbase + wm * 32 + mi * 16 + quad * 4 + reg;
                int n = nbase + wn * 64 + ni * 16 + col;
                dst[(size_t)m * D2 + n] = acc[mi][ni][reg];
            }
        }
    }
}

// ---------------- K3 v13: combine HP + bias + GELU, GEMM2, l2norm.
// 16 rows/block -> grid 512 (2 blocks/CU; was 256 = 1/CU, occupancy-starved).
__global__ __launch_bounds__(256)
void k3_gemm2(const float* __restrict__ HP,
              const float* __restrict__ b1q, const float* __restrict__ b1r,
              const float* __restrict__ W2q, const float* __restrict__ b2q,
              const float* __restrict__ W2r, const float* __restrict__ b2r,
              float* __restrict__ Z, unsigned short* __restrict__ Zbf){
    const int gstart = blockIdx.x * 16;
    const int inp = (gstart >= NQ) ? 1 : 0;
    const float* b1 = inp ? b1r : b1q;
    const float* W2 = inp ? W2r : W2q;
    const float* b2 = inp ? b2r : b2q;

    __shared__ __align__(16) float Hs[16][68];
    __shared__ __align__(16) float Wk[64][132];
    __shared__ float red[16][17];
    __shared__ float normS[16];

    const int tid = threadIdx.x;
    const int ty = tid >> 4;     // row 0..15
    const int tx = tid & 15;     // col group 0..15

    float acc[8];
#pragma unroll
    for (int jj = 0; jj < 8; ++jj) acc[jj] = 0.f;

    for (int kc = 0; kc < 4; ++kc){
#pragma unroll
        for (int i = 0; i < 4; ++i){
            int e = tid + i * 256;
            int rr = e >> 6, kk = e & 63;
            size_t idx = (size_t)(gstart + rr) * D2 + kc * 64 + kk;
            float hv = HP[idx] + HP[(size_t)NT * D2 + idx] + b1[kc * 64 + kk];
            Hs[rr][kk] = gelu_exact(hv);
        }
#pragma unroll
        for (int i = 0; i < 32; ++i){
            int e = tid + i * 256;
            int nn = e >> 6, kk = e & 63;
            Wk[kk][nn] = W2[(size_t)nn * D2 + kc * 64 + kk];
        }
        __syncthreads();
#pragma unroll
        for (int k4 = 0; k4 < 16; ++k4){
            float a0[4];
            float4 t0 = *(const float4*)&Hs[ty][k4 * 4];
            a0[0] = t0.x; a0[1] = t0.y; a0[2] = t0.z; a0[3] = t0.w;
#pragma unroll
            for (int kq = 0; kq < 4; ++kq){
                float4 w0 = *(const float4*)&Wk[k4 * 4 + kq][tx * 8];
                float4 w1 = *(const float4*)&Wk[k4 * 4 + kq][tx * 8 + 4];
                float wv[8] = {w0.x, w0.y, w0.z, w0.w, w1.x, w1.y, w1.z, w1.w};
#pragma unroll
                for (int jj = 0; jj < 8; ++jj)
                    acc[jj] += a0[kq] * wv[jj];
            }
        }
        __syncthreads();
    }
    float v0[8];
    float sq0 = 0.f;
#pragma unroll
    for (int jj = 0; jj < 8; ++jj){
        int c = tx * 8 + jj;
        v0[jj] = acc[jj] + b2[c];
        sq0 += v0[jj] * v0[jj];
    }
    red[ty][tx] = sq0;
    __syncthreads();
    if (tid < 16){
        float s = 0.f;
#pragma unroll
        for (int t = 0; t < 16; ++t) s += red[tid][t];
        normS[tid] = 1.0f / fmaxf(sqrtf(s), 1e-12f);
    }
    __syncthreads();
    float s0 = normS[ty];
    int row0 = gstart + ty;
    size_t o0 = (size_t)row0 * DD + tx * 8;
    float z0[8];
#pragma unroll
    for (int jj = 0; jj < 8; ++jj) z0[jj] = v0[jj] * s0;
    float4 a = {z0[0], z0[1], z0[2], z0[3]}, b = {z0[4], z0[5], z0[6], z0[7]};
    *(float4*)&Z[o0]     = a;  *(float4*)&Z[o0 + 4] = b;
    uint4 p0 = {pack2bf(z0[0], z0[1]), pack2bf(z0[2], z0[3]),
                pack2bf(z0[4], z0[5]), pack2bf(z0[6], z0[7])};
    *(uint4*)&Zbf[o0] = p0;
}

// ---------------- KT: ZbfT[d][r] = Zbf[NQ + r][d]  (r part only), tile 64x128.
__global__ __launch_bounds__(256)
void kT_transpose(const unsigned short* __restrict__ Zbf,
                  unsigned short* __restrict__ ZbfT){
    __shared__ unsigned short Ts[64][129];
    const int r0 = blockIdx.x * 64;
    const int tid = threadIdx.x;
#pragma unroll
    for (int i = 0; i < 32; ++i){
        int e = tid + i * 256;
        int rr = e >> 7, dd = e & 127;
        Ts[rr][dd] = Zbf[(size_t)(NQ + r0 + rr) * DD + dd];
    }
    __syncthreads();
#pragma unroll
    for (int i = 0; i < 32; ++i){
        int e = tid + i * 256;
        int dd = e >> 6, rr = e & 63;
        ZbfT[(size_t)dd * NQ + r0 + rr] = Ts[rr][dd];
    }
}

// ---------------- KA v12: flash attention, block-shared LDS-staged K/V.
__global__ __launch_bounds__(256)
void kA_attn(const unsigned short* __restrict__ Zbf,
             const unsigned short* __restrict__ ZbfT,
             float* __restrict__ OP, float* __restrict__ LW){
    const int tid  = threadIdx.x;
    const int wave = tid >> 6, lane = tid & 63;
    const int quad = lane >> 4, col = lane & 15;
    const int m0   = blockIdx.x * 128 + wave * 32;
    const int split = blockIdx.y;
    const float scl = 0.08838834764831845f;   // 1/sqrt(128)

    __shared__ __align__(16) char sK[16384];
    __shared__ __align__(16) char sV[16384];
    __shared__ __align__(16) unsigned short Pt[4][2][16][72];

    s16x8 aq[2][4];
#pragma unroll
    for (int m = 0; m < 2; ++m)
#pragma unroll
        for (int kb = 0; kb < 4; ++kb)
            aq[m][kb] = *(const s16x8*)&Zbf[(size_t)(m0 + m * 16 + col) * DD + kb * 32 + quad * 8];

    const unsigned short* gK[4];
    const unsigned short* gV[4];
    int dK[4], dV[4];
#pragma unroll
    for (int i = 0; i < 4; ++i){
        int s = i * 256 + tid;
        int row = s >> 4, c = (s & 15) ^ (row & 15);
        gK[i] = Zbf + (size_t)(NQ + row) * DD + c * 8;
        dK[i] = s * 16;
        int s2 = i * 256 + tid;
        int rv = s2 >> 3, cv = (s2 & 7) ^ (rv & 7);
        gV[i] = ZbfT + (size_t)rv * NQ + cv * 8;
        dV[i] = s2 * 16;
    }

    int kOff[4][4];
#pragma unroll
    for (int nt = 0; nt < 4; ++nt){
        int rb = nt * 16 + col;
#pragma unroll
        for (int kb = 0; kb < 4; ++kb)
            kOff[nt][kb] = rb * 256 + (((kb * 4 + quad) ^ (rb & 15)) << 4);
    }
    int vOff[8][2];
#pragma unroll
    for (int dt = 0; dt < 8; ++dt){
        int rv = dt * 16 + col;
#pragma unroll
        for (int kb2 = 0; kb2 < 2; ++kb2)
            vOff[dt][kb2] = rv * 128 + (((kb2 * 4 + quad) ^ (rv & 7)) << 4);
    }

    f32x4 o[2][8];
#pragma unroll
    for (int m = 0; m < 2; ++m)
#pragma unroll
        for (int dt = 0; dt < 8; ++dt) o[m][dt] = (f32x4){0.f, 0.f, 0.f, 0.f};
    float lp[2][4] = {{0.f,0.f,0.f,0.f},{0.f,0.f,0.f,0.f}};
    float wp[2][4] = {{0.f,0.f,0.f,0.f},{0.f,0.f,0.f,0.f}};

    for (int it = 0; it < NIT; ++it){
        const int r0 = split * KPS + it * 64;
#pragma unroll
        for (int i = 0; i < 4; ++i)
            gload_lds16(gK[i] + (size_t)r0 * DD, sK + dK[i]);
#pragma unroll
        for (int i = 0; i < 4; ++i)
            gload_lds16(gV[i] + r0, sV + dV[i]);
        __syncthreads();

#pragma unroll
        for (int nt = 0; nt < 4; ++nt){
            s16x8 b[4];
#pragma unroll
            for (int kb = 0; kb < 4; ++kb)
                b[kb] = *(const s16x8*)(sK + kOff[nt][kb]);
#pragma unroll
            for (int m = 0; m < 2; ++m){
                f32x4 s = (f32x4){0.f, 0.f, 0.f, 0.f};
#pragma unroll
                for (int kb = 0; kb < 4; ++kb)
                    s = __builtin_amdgcn_mfma_f32_16x16x32_bf16(aq[m][kb], b[kb], s, 0, 0, 0);
#pragma unroll
                for (int reg = 0; reg < 4; ++reg){
                    float sv = s[reg] * scl;
                    float e  = __expf(sv);
                    lp[m][reg] += e;
                    wp[m][reg] += e * sv;
                    Pt[wave][m][quad * 4 + reg][nt * 16 + col] = f2bf(e);
                }
            }
        }

        s16x8 ap[2][2];
#pragma unroll
        for (int m = 0; m < 2; ++m)
#pragma unroll
            for (int kb2 = 0; kb2 < 2; ++kb2)
                ap[m][kb2] = *(const s16x8*)&Pt[wave][m][col][kb2 * 32 + quad * 8];
#pragma unroll
        for (int dt = 0; dt < 8; ++dt){
#pragma unroll
            for (int kb2 = 0; kb2 < 2; ++kb2){
                s16x8 b = *(const s16x8*)(sV + vOff[dt][kb2]);
                o[0][dt] = __builtin_amdgcn_mfma_f32_16x16x32_bf16(ap[0][kb2], b, o[0][dt], 0, 0, 0);
                o[1][dt] = __builtin_amdgcn_mfma_f32_16x16x32_bf16(ap[1][kb2], b, o[1][dt], 0, 0, 0);
            }
        }
        __syncthreads();
    }

#pragma unroll
    for (int m = 0; m < 2; ++m)
#pragma unroll
    for (int reg = 0; reg < 4; ++reg){
        float l = lp[m][reg], w = wp[m][reg];
        l += __shfl_xor(l, 8);  w += __shfl_xor(w, 8);
        l += __shfl_xor(l, 4);  w += __shfl_xor(w, 4);
        l += __shfl_xor(l, 2);  w += __shfl_xor(w, 2);
        l += __shfl_xor(l, 1);  w += __shfl_xor(w, 1);
        if (col == 0){
            int row = m0 + m * 16 + quad * 4 + reg;
            LW[((size_t)split * NQ + row) * 2]     = l;
            LW[((size_t)split * NQ + row) * 2 + 1] = w;
        }
    }
#pragma unroll
    for (int m = 0; m < 2; ++m)
#pragma unroll
    for (int dt = 0; dt < 8; ++dt){
#pragma unroll
        for (int reg = 0; reg < 4; ++reg){
            int row = m0 + m * 16 + quad * 4 + reg;
            OP[((size_t)split * NQ + row) * DD + dt * 16 + col] = o[m][dt][reg];
        }
    }
}

// ---------------- KC v13: combine NSPLIT splits -> r_bar, cos, u_n.
// Shfl reductions + parallel LW sum: 2 barriers (was ~15 + serial loop).
__global__ __launch_bounds__(128)
void kC_combine(const float* __restrict__ OP, const float* __restrict__ LW,
                const float* __restrict__ Z,
                float* __restrict__ RB, float* __restrict__ COS,
                float* __restrict__ ILW){
    const int r = blockIdx.x;
    const int c = threadIdx.x;
    const int lane = c & 63, wv = c >> 6;
    float v = 0.f;
#pragma unroll
    for (int s = 0; s < NSPLIT; ++s) v += OP[((size_t)s * NQ + r) * DD + c];

    __shared__ float sred[2][2];
    float t = v * v;
#pragma unroll
    for (int off = 32; off > 0; off >>= 1) t += __shfl_xor(t, off);
    if (lane == 0) sred[0][wv] = t;
    __syncthreads();
    float scale = 1.0f / fmaxf(sqrtf(sred[0][0] + sred[0][1]), 1e-12f);
    float rb = v * scale;
    RB[(size_t)r * DD + c] = rb;
    float zq = Z[(size_t)r * DD + c];
    float cz = zq * rb;
#pragma unroll
    for (int off = 32; off > 0; off >>= 1) cz += __shfl_xor(cz, off);
    if (lane == 0) sred[1][wv] = cz;

    // parallel LW sum: lanes 0..15 (wave 0) each load one split.
    float l_p = 0.f, w_p = 0.f;
    if (c < NSPLIT){
        l_p = LW[((size_t)c * NQ + r) * 2];
        w_p = LW[((size_t)c * NQ + r) * 2 + 1];
    }
#pragma unroll
    for (int off = 8; off > 0; off >>= 1){
        l_p += __shfl_xor(l_p, off);
        w_p += __shfl_xor(w_p, off);
    }
    __syncthreads();
    if (c == 0){
        COS[r] = sred[1][0] + sred[1][1];
        float ent = logf(l_p) - w_p / l_p;
        ILW[2 * r]     = 1.0f / l_p;
        ILW[2 * r + 1] = ent * (1.0f / 8.317766166719343f);  // / ln(4096)
    }
}

// ---------------- K8: decoder MLP (occupancy rewrite, unchanged from v7).
__global__ __launch_bounds__(256)
void k8_decoder(const float* __restrict__ Z, const float* __restrict__ RB,
                const float* __restrict__ ILW, const float* __restrict__ COS,
                const float* __restrict__ gd, const float* __restrict__ bd,
                const float* __restrict__ W1d, const float* __restrict__ b1d,
                const float* __restrict__ W2d, const float* __restrict__ b2d,
                const float* __restrict__ beta, const float* __restrict__ W_len,
                const float* __restrict__ b_len,
                float* __restrict__ out){
    const int r0 = blockIdx.x * 4;
    const int tid = threadIdx.x;
    const int wave = tid >> 6, lane = tid & 63;

    __shared__ __align__(16) float Xs[4][256];
    __shared__ float pr[4][2];

    {
        const int row = r0 + wave;
        const int c0 = lane * 4;
        float4 v;
        if (c0 < DD) v = *(const float4*)&Z[(size_t)row * DD + c0];
        else         v = *(const float4*)&RB[(size_t)row * DD + (c0 - DD)];
        float s  = v.x + v.y + v.z + v.w;
        float sq = v.x * v.x + v.y * v.y + v.z * v.z + v.w * v.w;
#pragma unroll
        for (int off = 32; off > 0; off >>= 1){
            s  += __shfl_xor(s, off);
            sq += __shfl_xor(sq, off);
        }
        float mean = s * (1.0f / D2);
        float var  = sq * (1.0f / D2) - mean * mean;
        float rstd = rsqrtf(fmaxf(var, 0.0f) + 1e-5f);
        float4 g = *(const float4*)&gd[c0];
        float4 b = *(const float4*)&bd[c0];
        float4 xn;
        xn.x = (v.x - mean) * rstd * g.x + b.x;
        xn.y = (v.y - mean) * rstd * g.y + b.y;
        xn.z = (v.z - mean) * rstd * g.z + b.z;
        xn.w = (v.w - mean) * rstd * g.w + b.w;
        *(float4*)&Xs[wave][c0] = xn;
    }
    __syncthreads();

    const int j  = tid & 127;
    const int rp = tid >> 7;
    const float* wrow = W1d + (size_t)j * D2;
    const float* xa = &Xs[rp * 2][0];
    const float* xb = &Xs[rp * 2 + 1][0];
    float h0 = 0.f, h1 = 0.f;
#pragma unroll 8
    for (int k = 0; k < D2; k += 4){
        float4 w  = *(const float4*)&wrow[k];
        float4 a4 = *(const float4*)&xa[k];
        float4 b4 = *(const float4*)&xb[k];
        h0 += w.x * a4.x + w.y * a4.y + w.z * a4.z + w.w * a4.w;
        h1 += w.x * b4.x + w.y * b4.y + w.z * b4.z + w.w * b4.w;
    }
    float bj = b1d[j];
    h0 = gelu_exact(h0 + bj);
    h1 = gelu_exact(h1 + bj);
    float w2 = W2d[j];
    float p0 = h0 * w2, p1 = h1 * w2;
#pragma unroll
    for (int off = 32; off > 0; off >>= 1){
        p0 += __shfl_xor(p0, off);
        p1 += __shfl_xor(p1, off);
    }
    if (lane == 0){ pr[wave][0] = p0; pr[wave][1] = p1; }
    __syncthreads();

    if (tid < 4){
        const int row   = tid;
        const int rpair = row >> 1, rlo = row & 1;
        float lg = b2d[0] + pr[rpair * 2][rlo] + pr[rpair * 2 + 1][rlo];
        const int gr = r0 + row;
        float u  = ILW[2 * gr + 1];
        float cv = COS[gr];
        float dln = cv * W_len[0] + u * W_len[1] + b_len[0];
        float dt = beta[0] * u + beta[1] * tanhf(dln);
        dt = fminf(0.5f, fmaxf(-0.5f, dt));
        out[gr]      = lg;
        out[NQ + gr] = dt;
    }
}

extern "C" void kernel_launch(void* const* d_in, const int* in_sizes, int n_in,
                              void* d_out, int out_size, void* d_ws, size_t ws_size,
                              hipStream_t stream){
    const float* q      = (const float*)d_in[0];
    const float* R      = (const float*)d_in[1];
    const float* ln_q_g = (const float*)d_in[2];
    const float* ln_q_b = (const float*)d_in[3];
    const float* W1q    = (const float*)d_in[4];
    const float* b1q    = (const float*)d_in[5];
    const float* W2q    = (const float*)d_in[6];
    const float* b2q    = (const float*)d_in[7];
    const float* ln_r_g = (const float*)d_in[8];
    const float* ln_r_b = (const float*)d_in[9];
    const float* W1r    = (const float*)d_in[10];
    const float* b1r    = (const float*)d_in[11];
    const float* W2r    = (const float*)d_in[12];
    const float* b2r    = (const float*)d_in[13];
    const float* ln_d_g = (const float*)d_in[14];
    const float* ln_d_b = (const float*)d_in[15];
    const float* W1d    = (const float*)d_in[16];
    const float* b1d    = (const float*)d_in[17];
    const float* W2d    = (const float*)d_in[18];
    const float* b2d    = (const float*)d_in[19];
    const float* beta   = (const float*)d_in[20];
    const float* W_len  = (const float*)d_in[21];
    const float* b_len  = (const float*)d_in[22];

    float* WS = (float*)d_ws;
    unsigned short* Xbf  = (unsigned short*)(WS);             // 8192*2048 bf16 = 8388608 fl
    float* OP    = WS;                                        // [16][4096][128] aliases Xbf (dead after k2) — exact fit
    float* HP    = WS + 8388608;                              // 2*8192*256
    float* LW    = WS + 8388608;                              // [16][4096][2] aliases HP (dead after k3)
    unsigned short* Wbf  = (unsigned short*)(WS + 12582912);  // 512*2048 bf16
    float* Z     = WS + 13107200;                             // 8192*128
    unsigned short* Zbf  = (unsigned short*)(WS + 14155776);  // 8192*128 bf16
    unsigned short* ZbfT = (unsigned short*)(WS + 14680064);  // 128*4096 bf16
    float* RB    = WS + 14942208;                             // 4096*128
    float* COSV  = WS + 15466496;                             // 4096
    float* ILW   = WS + 15470592;                             // 4096*2
    float* out   = (float*)d_out;

    hipLaunchKernelGGL(kLN_cast, dim3(NT + 512), dim3(256), 0, stream,
                       q, R, ln_q_g, ln_q_b, ln_r_g, ln_r_b, W1q, W1r, Xbf, Wbf);
    hipLaunchKernelGGL(k2_mfma, dim3(128, 2, 2), dim3(256), 0, stream, Xbf, Wbf, HP);
    hipLaunchKernelGGL(k3_gemm2, dim3(512), dim3(256), 0, stream,
                       HP, b1q, b1r, W2q, b2q, W2r, b2r, Z, Zbf);
    hipLaunchKernelGGL(kT_transpose, dim3(64), dim3(256), 0, stream, Zbf, ZbfT);
    hipLaunchKernelGGL(kA_attn, dim3(32, NSPLIT), dim3(256), 0, stream, Zbf, ZbfT, OP, LW);
    hipLaunchKernelGGL(kC_combine, dim3(NQ), dim3(128), 0, stream, OP, LW, Z, RB, COSV, ILW);
    hipLaunchKernelGGL(k8_decoder, dim3(1024), dim3(256), 0, stream,
                       Z, RB, ILW, COSV, ln_d_g, ln_d_b, W1d, b1d, W2d, b2d,
                       beta, W_len, b_len, out);
}

// Round 10
// 247.674 us; speedup vs baseline: 1.2408x; 1.0531x over previous
//
#include <hip/hip_runtime.h>
#include <math.h>

// RouterLite v14 = v13 with k8_decoder's W1d reads de-scattered.
// v13 post-mortem: aux de-barriering was null (-2.8us) -> barriers weren't
// the cost. Re-accounting: v7's k8 fix only delivered -32 (75 -> ~40), and
// v7 k8 has the k2-scatter disease: each thread reads its OWN 1KB W1d row,
// so each wave-load fans to 64 cache lines (16.7M scattered 16B requests,
// request-rate bound ~30-40us). v14 k8: LDS-stage W1d in 8 coalesced chunks
// [128][33] (pad -> 2-way bank alias = free), compute from LDS with float4;
// global W1d traffic = 128KB/block coalesced. All else unchanged from v13.
//
// ws map (float offsets), total ~61.9 MB:
//   Xbf  @0         [8192][2048] bf16 (8388608 fl) — dead after k2_mfma,
//                   ALIASED by OP @0 [16][4096][128] fp32 (exact fit)
//   HP   @8388608   [2][8192][256] fp32 partials (k2->k3, dead after),
//                   ALIASED by LW @8388608 [16][4096][2] fp32 (kA->kC)
//   Wbf  @12582912  [512][2048] bf16 (W1q rows 0..255, W1r 256..511)
//   Z    @13107200  [8192][128] fp32
//   Zbf  @14155776  [8192][128] bf16
//   ZbfT @14680064  [128][4096] bf16 (Z_r transposed)
//   RB   @14942208  [4096][128]
//   COS  @15466496  [4096]
//   ILW  @15470592  [4096][2]
// d_out: fp32, [0..4095]=raw_logit, [4096..8191]=delta_theta.

#define HD   2048
#define D2   256
#define DD   128
#define NQ   4096
#define NT   8192
#define NSPLIT 16
#define KPS  (NQ / NSPLIT)   // 256 K-rows per split
#define NIT  (KPS / 64)      // 4 iterations of 64 K-rows

typedef __attribute__((ext_vector_type(8))) short s16x8;
typedef __attribute__((ext_vector_type(4))) float f32x4;

static __device__ __forceinline__ float gelu_exact(float x){
    return 0.5f * x * (1.0f + erff(x * 0.7071067811865475f));
}
static __device__ __forceinline__ unsigned short f2bf(float f){
    unsigned int u = __float_as_uint(f);
    return (unsigned short)((u + 0x7FFFu + ((u >> 16) & 1u)) >> 16);
}
static __device__ __forceinline__ unsigned int pack2bf(float a, float b){
    return (unsigned int)f2bf(a) | ((unsigned int)f2bf(b) << 16);
}

static __device__ __forceinline__ void gload_lds16(const void* g, void* l){
    __builtin_amdgcn_global_load_lds(
        (const __attribute__((address_space(1))) unsigned int*)g,
        (__attribute__((address_space(3))) unsigned int*)l, 16, 0, 0);
}

// ---------------- KLN v13: LN(x) -> bf16 Xbf; W1 -> bf16 Wbf.
__global__ __launch_bounds__(256)
void kLN_cast(const float* __restrict__ q, const float* __restrict__ R,
              const float* __restrict__ gq, const float* __restrict__ bq,
              const float* __restrict__ gr, const float* __restrict__ br,
              const float* __restrict__ W1q, const float* __restrict__ W1r,
              unsigned short* __restrict__ Xbf, unsigned short* __restrict__ Wbf){
    const int r = blockIdx.x;
    const int tid = threadIdx.x;
    if (r >= NT){
        const int rw = r - NT;
        const float* src = (rw >= 256) ? (W1r + (size_t)(rw - 256) * HD)
                                       : (W1q + (size_t)rw * HD);
        float4 a = *(const float4*)&src[tid * 8];
        float4 c = *(const float4*)&src[tid * 8 + 4];
        uint4 p = {pack2bf(a.x, a.y), pack2bf(a.z, a.w),
                   pack2bf(c.x, c.y), pack2bf(c.z, c.w)};
        *(uint4*)&Wbf[(size_t)rw * HD + tid * 8] = p;
        return;
    }
    const float* src = (r < NQ) ? (q + (size_t)r * HD) : (R + (size_t)(r - NQ) * HD);
    const float* g  = (r < NQ) ? gq : gr;
    const float* bb = (r < NQ) ? bq : br;
    float4 x0 = *(const float4*)&src[tid * 8];
    float4 x1 = *(const float4*)&src[tid * 8 + 4];
    float v[8] = {x0.x, x0.y, x0.z, x0.w, x1.x, x1.y, x1.z, x1.w};
    float s = 0.f, sq = 0.f;
#pragma unroll
    for (int i = 0; i < 8; ++i){ s += v[i]; sq += v[i] * v[i]; }
#pragma unroll
    for (int off = 32; off > 0; off >>= 1){
        s  += __shfl_xor(s, off);
        sq += __shfl_xor(sq, off);
    }
    __shared__ float wS[4], wQ[4];
    const int wave = tid >> 6, lane = tid & 63;
    if (lane == 0){ wS[wave] = s; wQ[wave] = sq; }
    __syncthreads();
    float sum = wS[0] + wS[1] + wS[2] + wS[3];
    float sqs = wQ[0] + wQ[1] + wQ[2] + wQ[3];
    float mean = sum * (1.0f / HD);
    float var  = sqs * (1.0f / HD) - mean * mean;
    float rstd = rsqrtf(fmaxf(var, 0.0f) + 1e-5f);
    float4 g0 = *(const float4*)&g[tid * 8];
    float4 g1 = *(const float4*)&g[tid * 8 + 4];
    float4 b0 = *(const float4*)&bb[tid * 8];
    float4 b1 = *(const float4*)&bb[tid * 8 + 4];
    float gg[8] = {g0.x, g0.y, g0.z, g0.w, g1.x, g1.y, g1.z, g1.w};
    float bv[8] = {b0.x, b0.y, b0.z, b0.w, b1.x, b1.y, b1.z, b1.w};
    float h[8];
#pragma unroll
    for (int i = 0; i < 8; ++i) h[i] = (v[i] - mean) * rstd * gg[i] + bv[i];
    uint4 p = {pack2bf(h[0], h[1]), pack2bf(h[2], h[3]),
               pack2bf(h[4], h[5]), pack2bf(h[6], h[7])};
    *(uint4*)&Xbf[(size_t)r * HD + tid * 8] = p;
}

// ---------------- K2 v11: HP[ks] = Xbf @ Wbf^T (K-half ks), LDS-staged.
__global__ __launch_bounds__(256)
void k2_mfma(const unsigned short* __restrict__ Xbf,
             const unsigned short* __restrict__ Wbf,
             float* __restrict__ HP){
    const int tid  = threadIdx.x;
    const int wave = tid >> 6, lane = tid & 63;
    const int quad = lane >> 4, col = lane & 15;
    const int mblk = blockIdx.x;
    const int nblk = blockIdx.y;
    const int ks   = blockIdx.z;
    const int inp  = mblk >> 6;
    const int mbase = mblk * 64;
    const int nbase = nblk * 128;
    const int wm = wave & 1, wn = wave >> 1;

    __shared__ __align__(16) char smem[49152];   // [2][ A 8192 | B 16384 ]

    const unsigned short* gA[2];
    const unsigned short* gB[4];
#pragma unroll
    for (int i = 0; i < 2; ++i){
        int s = i * 256 + wave * 64 + lane;
        int row = s >> 3, c = (s & 7) ^ (row & 7);
        gA[i] = Xbf + (size_t)(mbase + row) * HD + ks * 1024 + c * 8;
    }
#pragma unroll
    for (int j = 0; j < 4; ++j){
        int s = j * 256 + wave * 64 + lane;
        int row = s >> 3, c = (s & 7) ^ (row & 7);
        gB[j] = Wbf + (size_t)(inp * 256 + nbase + row) * HD + ks * 1024 + c * 8;
    }

#define K2_STAGE(d, k0)                                                        \
    {                                                                          \
        _Pragma("unroll")                                                      \
        for (int i = 0; i < 2; ++i)                                            \
            gload_lds16(gA[i] + (k0),                                          \
                        smem + (d) * 24576 + (i * 256 + wave * 64 + lane) * 16);\
        _Pragma("unroll")                                                      \
        for (int j = 0; j < 4; ++j)                                            \
            gload_lds16(gB[j] + (k0),                                          \
                        smem + (d) * 24576 + 8192 + (j * 256 + wave * 64 + lane) * 16);\
    }

    int aoff[2][2], boff[4][2];
#pragma unroll
    for (int mi = 0; mi < 2; ++mi){
        int ra = wm * 32 + mi * 16 + col;
#pragma unroll
        for (int kst = 0; kst < 2; ++kst){
            int cc = kst * 4 + quad;
            aoff[mi][kst] = ra * 128 + ((cc ^ (ra & 7)) << 4);
        }
    }
#pragma unroll
    for (int ni = 0; ni < 4; ++ni){
        int rb = wn * 64 + ni * 16 + col;
#pragma unroll
        for (int kst = 0; kst < 2; ++kst){
            int cc = kst * 4 + quad;
            boff[ni][kst] = rb * 128 + ((cc ^ (rb & 7)) << 4);
        }
    }

    f32x4 acc[2][4];
#pragma unroll
    for (int mi = 0; mi < 2; ++mi)
#pragma unroll
        for (int ni = 0; ni < 4; ++ni) acc[mi][ni] = (f32x4){0.f, 0.f, 0.f, 0.f};

    int cur = 0;
    K2_STAGE(0, 0);
    __syncthreads();
    for (int t = 0; t < 16; ++t){
        if (t < 15) K2_STAGE(cur ^ 1, (t + 1) * 64);
        const char* Ab = smem + cur * 24576;
        const char* Bb = Ab + 8192;
        s16x8 a[2][2], b[4][2];
#pragma unroll
        for (int mi = 0; mi < 2; ++mi)
#pragma unroll
            for (int kst = 0; kst < 2; ++kst)
                a[mi][kst] = *(const s16x8*)(Ab + aoff[mi][kst]);
#pragma unroll
        for (int ni = 0; ni < 4; ++ni)
#pragma unroll
            for (int kst = 0; kst < 2; ++kst)
                b[ni][kst] = *(const s16x8*)(Bb + boff[ni][kst]);
#pragma unroll
        for (int kst = 0; kst < 2; ++kst)
#pragma unroll
            for (int mi = 0; mi < 2; ++mi)
#pragma unroll
                for (int ni = 0; ni < 4; ++ni)
                    acc[mi][ni] = __builtin_amdgcn_mfma_f32_16x16x32_bf16(
                        a[mi][kst], b[ni][kst], acc[mi][ni], 0, 0, 0);
        __syncthreads();
        cur ^= 1;
    }
#undef K2_STAGE

    float* dst = HP + (size_t)ks * NT * D2;
#pragma unroll
    for (int mi = 0; mi < 2; ++mi){
#pragma unroll
        for (int ni = 0; ni < 4; ++ni){
#pragma unroll
            for (int reg = 0; reg < 4; ++reg){
                int m = mbase + wm * 32 + mi * 16 + quad * 4 + reg;
                int n = nbase + wn * 64 + ni * 16 + col;
                dst[(size_t)m * D2 + n] = acc[mi][ni][reg];
            }
        }
    }
}

// ---------------- K3 v13: combine HP + bias + GELU, GEMM2, l2norm.
__global__ __launch_bounds__(256)
void k3_gemm2(const float* __restrict__ HP,
              const float* __restrict__ b1q, const float* __restrict__ b1r,
              const float* __restrict__ W2q, const float* __restrict__ b2q,
              const float* __restrict__ W2r, const float* __restrict__ b2r,
              float* __restrict__ Z, unsigned short* __restrict__ Zbf){
    const int gstart = blockIdx.x * 16;
    const int inp = (gstart >= NQ) ? 1 : 0;
    const float* b1 = inp ? b1r : b1q;
    const float* W2 = inp ? W2r : W2q;
    const float* b2 = inp ? b2r : b2q;

    __shared__ __align__(16) float Hs[16][68];
    __shared__ __align__(16) float Wk[64][132];
    __shared__ float red[16][17];
    __shared__ float normS[16];

    const int tid = threadIdx.x;
    const int ty = tid >> 4;     // row 0..15
    const int tx = tid & 15;     // col group 0..15

    float acc[8];
#pragma unroll
    for (int jj = 0; jj < 8; ++jj) acc[jj] = 0.f;

    for (int kc = 0; kc < 4; ++kc){
#pragma unroll
        for (int i = 0; i < 4; ++i){
            int e = tid + i * 256;
            int rr = e >> 6, kk = e & 63;
            size_t idx = (size_t)(gstart + rr) * D2 + kc * 64 + kk;
            float hv = HP[idx] + HP[(size_t)NT * D2 + idx] + b1[kc * 64 + kk];
            Hs[rr][kk] = gelu_exact(hv);
        }
#pragma unroll
        for (int i = 0; i < 32; ++i){
            int e = tid + i * 256;
            int nn = e >> 6, kk = e & 63;
            Wk[kk][nn] = W2[(size_t)nn * D2 + kc * 64 + kk];
        }
        __syncthreads();
#pragma unroll
        for (int k4 = 0; k4 < 16; ++k4){
            float a0[4];
            float4 t0 = *(const float4*)&Hs[ty][k4 * 4];
            a0[0] = t0.x; a0[1] = t0.y; a0[2] = t0.z; a0[3] = t0.w;
#pragma unroll
            for (int kq = 0; kq < 4; ++kq){
                float4 w0 = *(const float4*)&Wk[k4 * 4 + kq][tx * 8];
                float4 w1 = *(const float4*)&Wk[k4 * 4 + kq][tx * 8 + 4];
                float wv[8] = {w0.x, w0.y, w0.z, w0.w, w1.x, w1.y, w1.z, w1.w};
#pragma unroll
                for (int jj = 0; jj < 8; ++jj)
                    acc[jj] += a0[kq] * wv[jj];
            }
        }
        __syncthreads();
    }
    float v0[8];
    float sq0 = 0.f;
#pragma unroll
    for (int jj = 0; jj < 8; ++jj){
        int c = tx * 8 + jj;
        v0[jj] = acc[jj] + b2[c];
        sq0 += v0[jj] * v0[jj];
    }
    red[ty][tx] = sq0;
    __syncthreads();
    if (tid < 16){
        float s = 0.f;
#pragma unroll
        for (int t = 0; t < 16; ++t) s += red[tid][t];
        normS[tid] = 1.0f / fmaxf(sqrtf(s), 1e-12f);
    }
    __syncthreads();
    float s0 = normS[ty];
    int row0 = gstart + ty;
    size_t o0 = (size_t)row0 * DD + tx * 8;
    float z0[8];
#pragma unroll
    for (int jj = 0; jj < 8; ++jj) z0[jj] = v0[jj] * s0;
    float4 a = {z0[0], z0[1], z0[2], z0[3]}, b = {z0[4], z0[5], z0[6], z0[7]};
    *(float4*)&Z[o0]     = a;  *(float4*)&Z[o0 + 4] = b;
    uint4 p0 = {pack2bf(z0[0], z0[1]), pack2bf(z0[2], z0[3]),
                pack2bf(z0[4], z0[5]), pack2bf(z0[6], z0[7])};
    *(uint4*)&Zbf[o0] = p0;
}

// ---------------- KT: ZbfT[d][r] = Zbf[NQ + r][d]  (r part only), tile 64x128.
__global__ __launch_bounds__(256)
void kT_transpose(const unsigned short* __restrict__ Zbf,
                  unsigned short* __restrict__ ZbfT){
    __shared__ unsigned short Ts[64][129];
    const int r0 = blockIdx.x * 64;
    const int tid = threadIdx.x;
#pragma unroll
    for (int i = 0; i < 32; ++i){
        int e = tid + i * 256;
        int rr = e >> 7, dd = e & 127;
        Ts[rr][dd] = Zbf[(size_t)(NQ + r0 + rr) * DD + dd];
    }
    __syncthreads();
#pragma unroll
    for (int i = 0; i < 32; ++i){
        int e = tid + i * 256;
        int dd = e >> 6, rr = e & 63;
        ZbfT[(size_t)dd * NQ + r0 + rr] = Ts[rr][dd];
    }
}

// ---------------- KA v12: flash attention, block-shared LDS-staged K/V.
__global__ __launch_bounds__(256)
void kA_attn(const unsigned short* __restrict__ Zbf,
             const unsigned short* __restrict__ ZbfT,
             float* __restrict__ OP, float* __restrict__ LW){
    const int tid  = threadIdx.x;
    const int wave = tid >> 6, lane = tid & 63;
    const int quad = lane >> 4, col = lane & 15;
    const int m0   = blockIdx.x * 128 + wave * 32;
    const int split = blockIdx.y;
    const float scl = 0.08838834764831845f;   // 1/sqrt(128)

    __shared__ __align__(16) char sK[16384];
    __shared__ __align__(16) char sV[16384];
    __shared__ __align__(16) unsigned short Pt[4][2][16][72];

    s16x8 aq[2][4];
#pragma unroll
    for (int m = 0; m < 2; ++m)
#pragma unroll
        for (int kb = 0; kb < 4; ++kb)
            aq[m][kb] = *(const s16x8*)&Zbf[(size_t)(m0 + m * 16 + col) * DD + kb * 32 + quad * 8];

    const unsigned short* gK[4];
    const unsigned short* gV[4];
    int dK[4], dV[4];
#pragma unroll
    for (int i = 0; i < 4; ++i){
        int s = i * 256 + tid;
        int row = s >> 4, c = (s & 15) ^ (row & 15);
        gK[i] = Zbf + (size_t)(NQ + row) * DD + c * 8;
        dK[i] = s * 16;
        int s2 = i * 256 + tid;
        int rv = s2 >> 3, cv = (s2 & 7) ^ (rv & 7);
        gV[i] = ZbfT + (size_t)rv * NQ + cv * 8;
        dV[i] = s2 * 16;
    }

    int kOff[4][4];
#pragma unroll
    for (int nt = 0; nt < 4; ++nt){
        int rb = nt * 16 + col;
#pragma unroll
        for (int kb = 0; kb < 4; ++kb)
            kOff[nt][kb] = rb * 256 + (((kb * 4 + quad) ^ (rb & 15)) << 4);
    }
    int vOff[8][2];
#pragma unroll
    for (int dt = 0; dt < 8; ++dt){
        int rv = dt * 16 + col;
#pragma unroll
        for (int kb2 = 0; kb2 < 2; ++kb2)
            vOff[dt][kb2] = rv * 128 + (((kb2 * 4 + quad) ^ (rv & 7)) << 4);
    }

    f32x4 o[2][8];
#pragma unroll
    for (int m = 0; m < 2; ++m)
#pragma unroll
        for (int dt = 0; dt < 8; ++dt) o[m][dt] = (f32x4){0.f, 0.f, 0.f, 0.f};
    float lp[2][4] = {{0.f,0.f,0.f,0.f},{0.f,0.f,0.f,0.f}};
    float wp[2][4] = {{0.f,0.f,0.f,0.f},{0.f,0.f,0.f,0.f}};

    for (int it = 0; it < NIT; ++it){
        const int r0 = split * KPS + it * 64;
#pragma unroll
        for (int i = 0; i < 4; ++i)
            gload_lds16(gK[i] + (size_t)r0 * DD, sK + dK[i]);
#pragma unroll
        for (int i = 0; i < 4; ++i)
            gload_lds16(gV[i] + r0, sV + dV[i]);
        __syncthreads();

#pragma unroll
        for (int nt = 0; nt < 4; ++nt){
            s16x8 b[4];
#pragma unroll
            for (int kb = 0; kb < 4; ++kb)
                b[kb] = *(const s16x8*)(sK + kOff[nt][kb]);
#pragma unroll
            for (int m = 0; m < 2; ++m){
                f32x4 s = (f32x4){0.f, 0.f, 0.f, 0.f};
#pragma unroll
                for (int kb = 0; kb < 4; ++kb)
                    s = __builtin_amdgcn_mfma_f32_16x16x32_bf16(aq[m][kb], b[kb], s, 0, 0, 0);
#pragma unroll
                for (int reg = 0; reg < 4; ++reg){
                    float sv = s[reg] * scl;
                    float e  = __expf(sv);
                    lp[m][reg] += e;
                    wp[m][reg] += e * sv;
                    Pt[wave][m][quad * 4 + reg][nt * 16 + col] = f2bf(e);
                }
            }
        }

        s16x8 ap[2][2];
#pragma unroll
        for (int m = 0; m < 2; ++m)
#pragma unroll
            for (int kb2 = 0; kb2 < 2; ++kb2)
                ap[m][kb2] = *(const s16x8*)&Pt[wave][m][col][kb2 * 32 + quad * 8];
#pragma unroll
        for (int dt = 0; dt < 8; ++dt){
#pragma unroll
            for (int kb2 = 0; kb2 < 2; ++kb2){
                s16x8 b = *(const s16x8*)(sV + vOff[dt][kb2]);
                o[0][dt] = __builtin_amdgcn_mfma_f32_16x16x32_bf16(ap[0][kb2], b, o[0][dt], 0, 0, 0);
                o[1][dt] = __builtin_amdgcn_mfma_f32_16x16x32_bf16(ap[1][kb2], b, o[1][dt], 0, 0, 0);
            }
        }
        __syncthreads();
    }

#pragma unroll
    for (int m = 0; m < 2; ++m)
#pragma unroll
    for (int reg = 0; reg < 4; ++reg){
        float l = lp[m][reg], w = wp[m][reg];
        l += __shfl_xor(l, 8);  w += __shfl_xor(w, 8);
        l += __shfl_xor(l, 4);  w += __shfl_xor(w, 4);
        l += __shfl_xor(l, 2);  w += __shfl_xor(w, 2);
        l += __shfl_xor(l, 1);  w += __shfl_xor(w, 1);
        if (col == 0){
            int row = m0 + m * 16 + quad * 4 + reg;
            LW[((size_t)split * NQ + row) * 2]     = l;
            LW[((size_t)split * NQ + row) * 2 + 1] = w;
        }
    }
#pragma unroll
    for (int m = 0; m < 2; ++m)
#pragma unroll
    for (int dt = 0; dt < 8; ++dt){
#pragma unroll
        for (int reg = 0; reg < 4; ++reg){
            int row = m0 + m * 16 + quad * 4 + reg;
            OP[((size_t)split * NQ + row) * DD + dt * 16 + col] = o[m][dt][reg];
        }
    }
}

// ---------------- KC v13: combine NSPLIT splits -> r_bar, cos, u_n.
__global__ __launch_bounds__(128)
void kC_combine(const float* __restrict__ OP, const float* __restrict__ LW,
                const float* __restrict__ Z,
                float* __restrict__ RB, float* __restrict__ COS,
                float* __restrict__ ILW){
    const int r = blockIdx.x;
    const int c = threadIdx.x;
    const int lane = c & 63, wv = c >> 6;
    float v = 0.f;
#pragma unroll
    for (int s = 0; s < NSPLIT; ++s) v += OP[((size_t)s * NQ + r) * DD + c];

    __shared__ float sred[2][2];
    float t = v * v;
#pragma unroll
    for (int off = 32; off > 0; off >>= 1) t += __shfl_xor(t, off);
    if (lane == 0) sred[0][wv] = t;
    __syncthreads();
    float scale = 1.0f / fmaxf(sqrtf(sred[0][0] + sred[0][1]), 1e-12f);
    float rb = v * scale;
    RB[(size_t)r * DD + c] = rb;
    float zq = Z[(size_t)r * DD + c];
    float cz = zq * rb;
#pragma unroll
    for (int off = 32; off > 0; off >>= 1) cz += __shfl_xor(cz, off);
    if (lane == 0) sred[1][wv] = cz;

    // parallel LW sum: lanes 0..15 (wave 0) each load one split.
    float l_p = 0.f, w_p = 0.f;
    if (c < NSPLIT){
        l_p = LW[((size_t)c * NQ + r) * 2];
        w_p = LW[((size_t)c * NQ + r) * 2 + 1];
    }
#pragma unroll
    for (int off = 8; off > 0; off >>= 1){
        l_p += __shfl_xor(l_p, off);
        w_p += __shfl_xor(w_p, off);
    }
    __syncthreads();
    if (c == 0){
        COS[r] = sred[1][0] + sred[1][1];
        float ent = logf(l_p) - w_p / l_p;
        ILW[2 * r]     = 1.0f / l_p;
        ILW[2 * r + 1] = ent * (1.0f / 8.317766166719343f);  // / ln(4096)
    }
}

// ---------------- K8 v14: decoder MLP with LDS-staged W1d.
// v7's W1d pattern (thread reads its own 1KB row) = 64 cache lines per
// wave-load -> request-rate bound. v14: 8 chunks of W1d[128][32] staged
// coalesced into Wd[128][33] (+1 pad -> 2-way bank alias = free), compute
// reads from LDS (Wd strided free + Xs broadcast). Work partition and
// numerics identical to v7.
__global__ __launch_bounds__(256)
void k8_decoder(const float* __restrict__ Z, const float* __restrict__ RB,
                const float* __restrict__ ILW, const float* __restrict__ COS,
                const float* __restrict__ gd, const float* __restrict__ bd,
                const float* __restrict__ W1d, const float* __restrict__ b1d,
                const float* __restrict__ W2d, const float* __restrict__ b2d,
                const float* __restrict__ beta, const float* __restrict__ W_len,
                const float* __restrict__ b_len,
                float* __restrict__ out){
    const int r0 = blockIdx.x * 4;
    const int tid = threadIdx.x;
    const int wave = tid >> 6, lane = tid & 63;

    __shared__ __align__(16) float Xs[4][256];
    __shared__ __align__(16) float Wd[128][33];
    __shared__ float pr[4][2];

    // ---- LN for row (r0+wave), one wave per row, shfl-only reduction.
    {
        const int row = r0 + wave;
        const int c0 = lane * 4;
        float4 v;
        if (c0 < DD) v = *(const float4*)&Z[(size_t)row * DD + c0];
        else         v = *(const float4*)&RB[(size_t)row * DD + (c0 - DD)];
        float s  = v.x + v.y + v.z + v.w;
        float sq = v.x * v.x + v.y * v.y + v.z * v.z + v.w * v.w;
#pragma unroll
        for (int off = 32; off > 0; off >>= 1){
            s  += __shfl_xor(s, off);
            sq += __shfl_xor(sq, off);
        }
        float mean = s * (1.0f / D2);
        float var  = sq * (1.0f / D2) - mean * mean;
        float rstd = rsqrtf(fmaxf(var, 0.0f) + 1e-5f);
        float4 g = *(const float4*)&gd[c0];
        float4 b = *(const float4*)&bd[c0];
        float4 xn;
        xn.x = (v.x - mean) * rstd * g.x + b.x;
        xn.y = (v.y - mean) * rstd * g.y + b.y;
        xn.z = (v.z - mean) * rstd * g.z + b.z;
        xn.w = (v.w - mean) * rstd * g.w + b.w;
        *(float4*)&Xs[wave][c0] = xn;
    }
    __syncthreads();

    // ---- GEMM1 + GELU + W2 dot, W1d via LDS chunks.
    const int j  = tid & 127;
    const int rp = tid >> 7;     // waves 0,1 -> rows 0,1 ; waves 2,3 -> rows 2,3
    const float* xa = &Xs[rp * 2][0];
    const float* xb = &Xs[rp * 2 + 1][0];
    float h0 = 0.f, h1 = 0.f;
    for (int cch = 0; cch < 8; ++cch){
        // stage chunk: Wd[j2][kk] = W1d[j2][cch*32+kk] — coalesced 128B runs.
#pragma unroll
        for (int i = 0; i < 16; ++i){
            int e = tid + i * 256;
            int j2 = e >> 5, kk = e & 31;
            Wd[j2][kk] = W1d[(size_t)j2 * D2 + cch * 32 + kk];
        }
        __syncthreads();
#pragma unroll
        for (int k4 = 0; k4 < 8; ++k4){
            float4 w  = *(const float4*)&Wd[j][k4 * 4];
            float4 a4 = *(const float4*)&xa[cch * 32 + k4 * 4];
            float4 b4 = *(const float4*)&xb[cch * 32 + k4 * 4];
            h0 += w.x * a4.x + w.y * a4.y + w.z * a4.z + w.w * a4.w;
            h1 += w.x * b4.x + w.y * b4.y + w.z * b4.z + w.w * b4.w;
        }
        __syncthreads();
    }
    float bj = b1d[j];
    h0 = gelu_exact(h0 + bj);
    h1 = gelu_exact(h1 + bj);
    float w2 = W2d[j];
    float p0 = h0 * w2, p1 = h1 * w2;
#pragma unroll
    for (int off = 32; off > 0; off >>= 1){
        p0 += __shfl_xor(p0, off);
        p1 += __shfl_xor(p1, off);
    }
    if (lane == 0){ pr[wave][0] = p0; pr[wave][1] = p1; }
    __syncthreads();

    // ---- Final logit + scalar heads: threads 0..3, one row each.
    if (tid < 4){
        const int row   = tid;
        const int rpair = row >> 1, rlo = row & 1;
        float lg = b2d[0] + pr[rpair * 2][rlo] + pr[rpair * 2 + 1][rlo];
        const int gr = r0 + row;
        float u  = ILW[2 * gr + 1];
        float cv = COS[gr];
        float dln = cv * W_len[0] + u * W_len[1] + b_len[0];
        float dt = beta[0] * u + beta[1] * tanhf(dln);
        dt = fminf(0.5f, fmaxf(-0.5f, dt));
        out[gr]      = lg;
        out[NQ + gr] = dt;
    }
}

extern "C" void kernel_launch(void* const* d_in, const int* in_sizes, int n_in,
                              void* d_out, int out_size, void* d_ws, size_t ws_size,
                              hipStream_t stream){
    const float* q      = (const float*)d_in[0];
    const float* R      = (const float*)d_in[1];
    const float* ln_q_g = (const float*)d_in[2];
    const float* ln_q_b = (const float*)d_in[3];
    const float* W1q    = (const float*)d_in[4];
    const float* b1q    = (const float*)d_in[5];
    const float* W2q    = (const float*)d_in[6];
    const float* b2q    = (const float*)d_in[7];
    const float* ln_r_g = (const float*)d_in[8];
    const float* ln_r_b = (const float*)d_in[9];
    const float* W1r    = (const float*)d_in[10];
    const float* b1r    = (const float*)d_in[11];
    const float* W2r    = (const float*)d_in[12];
    const float* b2r    = (const float*)d_in[13];
    const float* ln_d_g = (const float*)d_in[14];
    const float* ln_d_b = (const float*)d_in[15];
    const float* W1d    = (const float*)d_in[16];
    const float* b1d    = (const float*)d_in[17];
    const float* W2d    = (const float*)d_in[18];
    const float* b2d    = (const float*)d_in[19];
    const float* beta   = (const float*)d_in[20];
    const float* W_len  = (const float*)d_in[21];
    const float* b_len  = (const float*)d_in[22];

    float* WS = (float*)d_ws;
    unsigned short* Xbf  = (unsigned short*)(WS);             // 8192*2048 bf16 = 8388608 fl
    float* OP    = WS;                                        // [16][4096][128] aliases Xbf (dead after k2) — exact fit
    float* HP    = WS + 8388608;                              // 2*8192*256
    float* LW    = WS + 8388608;                              // [16][4096][2] aliases HP (dead after k3)
    unsigned short* Wbf  = (unsigned short*)(WS + 12582912);  // 512*2048 bf16
    float* Z     = WS + 13107200;                             // 8192*128
    unsigned short* Zbf  = (unsigned short*)(WS + 14155776);  // 8192*128 bf16
    unsigned short* ZbfT = (unsigned short*)(WS + 14680064);  // 128*4096 bf16
    float* RB    = WS + 14942208;                             // 4096*128
    float* COSV  = WS + 15466496;                             // 4096
    float* ILW   = WS + 15470592;                             // 4096*2
    float* out   = (float*)d_out;

    hipLaunchKernelGGL(kLN_cast, dim3(NT + 512), dim3(256), 0, stream,
                       q, R, ln_q_g, ln_q_b, ln_r_g, ln_r_b, W1q, W1r, Xbf, Wbf);
    hipLaunchKernelGGL(k2_mfma, dim3(128, 2, 2), dim3(256), 0, stream, Xbf, Wbf, HP);
    hipLaunchKernelGGL(k3_gemm2, dim3(512), dim3(256), 0, stream,
                       HP, b1q, b1r, W2q, b2q, W2r, b2r, Z, Zbf);
    hipLaunchKernelGGL(kT_transpose, dim3(64), dim3(256), 0, stream, Zbf, ZbfT);
    hipLaunchKernelGGL(kA_attn, dim3(32, NSPLIT), dim3(256), 0, stream, Zbf, ZbfT, OP, LW);
    hipLaunchKernelGGL(kC_combine, dim3(NQ), dim3(128), 0, stream, OP, LW, Z, RB, COSV, ILW);
    hipLaunchKernelGGL(k8_decoder, dim3(1024), dim3(256), 0, stream,
                       Z, RB, ILW, COSV, ln_d_g, ln_d_b, W1d, b1d, W2d, b2d,
                       beta, W_len, b_len, out);
}

// Round 11
// 242.521 us; speedup vs baseline: 1.2671x; 1.0212x over previous
//
#include <hip/hip_runtime.h>
#include <math.h>

// RouterLite v15 = v14 with kC_combine FUSED into k8_decoder (7 -> 6 kernels).
// v14 post-mortem: k8 W1d de-scatter -13.1us (4th scatter-fix win). Attribution
// now blind (top-5 = harness fills); remaining cost is partly launch overhead
// and buffer round-trips. kC's outputs (RB/COS/ILW) feed ONLY k8 and its work
// is tiny -> fuse. OP/LW relaid as [row][split][..] (kA write coalescing
// unchanged; k8 reads become contiguous 8KB/row). ILW[2r]=1/l was never read
// -> dropped. RB/COS/ILW buffers deleted.
//
// ws map (float offsets), total ~61.9 MB:
//   Xbf  @0         [8192][2048] bf16 (8388608 fl) — dead after k2_mfma,
//                   ALIASED by OP @0 [4096][16][128] fp32 (exact fit)
//   HP   @8388608   [2][8192][256] fp32 partials (k2->k3, dead after),
//                   ALIASED by LW @8388608 [4096][16][2] fp32 (kA->k8)
//   Wbf  @12582912  [512][2048] bf16 (W1q rows 0..255, W1r 256..511)
//   Z    @13107200  [8192][128] fp32
//   Zbf  @14155776  [8192][128] bf16
//   ZbfT @14680064  [128][4096] bf16 (Z_r transposed)
// d_out: fp32, [0..4095]=raw_logit, [4096..8191]=delta_theta.

#define HD   2048
#define D2   256
#define DD   128
#define NQ   4096
#define NT   8192
#define NSPLIT 16
#define KPS  (NQ / NSPLIT)   // 256 K-rows per split
#define NIT  (KPS / 64)      // 4 iterations of 64 K-rows

typedef __attribute__((ext_vector_type(8))) short s16x8;
typedef __attribute__((ext_vector_type(4))) float f32x4;

static __device__ __forceinline__ float gelu_exact(float x){
    return 0.5f * x * (1.0f + erff(x * 0.7071067811865475f));
}
static __device__ __forceinline__ unsigned short f2bf(float f){
    unsigned int u = __float_as_uint(f);
    return (unsigned short)((u + 0x7FFFu + ((u >> 16) & 1u)) >> 16);
}
static __device__ __forceinline__ unsigned int pack2bf(float a, float b){
    return (unsigned int)f2bf(a) | ((unsigned int)f2bf(b) << 16);
}

static __device__ __forceinline__ void gload_lds16(const void* g, void* l){
    __builtin_amdgcn_global_load_lds(
        (const __attribute__((address_space(1))) unsigned int*)g,
        (__attribute__((address_space(3))) unsigned int*)l, 16, 0, 0);
}

// ---------------- KLN v13: LN(x) -> bf16 Xbf; W1 -> bf16 Wbf.
__global__ __launch_bounds__(256)
void kLN_cast(const float* __restrict__ q, const float* __restrict__ R,
              const float* __restrict__ gq, const float* __restrict__ bq,
              const float* __restrict__ gr, const float* __restrict__ br,
              const float* __restrict__ W1q, const float* __restrict__ W1r,
              unsigned short* __restrict__ Xbf, unsigned short* __restrict__ Wbf){
    const int r = blockIdx.x;
    const int tid = threadIdx.x;
    if (r >= NT){
        const int rw = r - NT;
        const float* src = (rw >= 256) ? (W1r + (size_t)(rw - 256) * HD)
                                       : (W1q + (size_t)rw * HD);
        float4 a = *(const float4*)&src[tid * 8];
        float4 c = *(const float4*)&src[tid * 8 + 4];
        uint4 p = {pack2bf(a.x, a.y), pack2bf(a.z, a.w),
                   pack2bf(c.x, c.y), pack2bf(c.z, c.w)};
        *(uint4*)&Wbf[(size_t)rw * HD + tid * 8] = p;
        return;
    }
    const float* src = (r < NQ) ? (q + (size_t)r * HD) : (R + (size_t)(r - NQ) * HD);
    const float* g  = (r < NQ) ? gq : gr;
    const float* bb = (r < NQ) ? bq : br;
    float4 x0 = *(const float4*)&src[tid * 8];
    float4 x1 = *(const float4*)&src[tid * 8 + 4];
    float v[8] = {x0.x, x0.y, x0.z, x0.w, x1.x, x1.y, x1.z, x1.w};
    float s = 0.f, sq = 0.f;
#pragma unroll
    for (int i = 0; i < 8; ++i){ s += v[i]; sq += v[i] * v[i]; }
#pragma unroll
    for (int off = 32; off > 0; off >>= 1){
        s  += __shfl_xor(s, off);
        sq += __shfl_xor(sq, off);
    }
    __shared__ float wS[4], wQ[4];
    const int wave = tid >> 6, lane = tid & 63;
    if (lane == 0){ wS[wave] = s; wQ[wave] = sq; }
    __syncthreads();
    float sum = wS[0] + wS[1] + wS[2] + wS[3];
    float sqs = wQ[0] + wQ[1] + wQ[2] + wQ[3];
    float mean = sum * (1.0f / HD);
    float var  = sqs * (1.0f / HD) - mean * mean;
    float rstd = rsqrtf(fmaxf(var, 0.0f) + 1e-5f);
    float4 g0 = *(const float4*)&g[tid * 8];
    float4 g1 = *(const float4*)&g[tid * 8 + 4];
    float4 b0 = *(const float4*)&bb[tid * 8];
    float4 b1 = *(const float4*)&bb[tid * 8 + 4];
    float gg[8] = {g0.x, g0.y, g0.z, g0.w, g1.x, g1.y, g1.z, g1.w};
    float bv[8] = {b0.x, b0.y, b0.z, b0.w, b1.x, b1.y, b1.z, b1.w};
    float h[8];
#pragma unroll
    for (int i = 0; i < 8; ++i) h[i] = (v[i] - mean) * rstd * gg[i] + bv[i];
    uint4 p = {pack2bf(h[0], h[1]), pack2bf(h[2], h[3]),
               pack2bf(h[4], h[5]), pack2bf(h[6], h[7])};
    *(uint4*)&Xbf[(size_t)r * HD + tid * 8] = p;
}

// ---------------- K2 v11: HP[ks] = Xbf @ Wbf^T (K-half ks), LDS-staged.
__global__ __launch_bounds__(256)
void k2_mfma(const unsigned short* __restrict__ Xbf,
             const unsigned short* __restrict__ Wbf,
             float* __restrict__ HP){
    const int tid  = threadIdx.x;
    const int wave = tid >> 6, lane = tid & 63;
    const int quad = lane >> 4, col = lane & 15;
    const int mblk = blockIdx.x;
    const int nblk = blockIdx.y;
    const int ks   = blockIdx.z;
    const int inp  = mblk >> 6;
    const int mbase = mblk * 64;
    const int nbase = nblk * 128;
    const int wm = wave & 1, wn = wave >> 1;

    __shared__ __align__(16) char smem[49152];   // [2][ A 8192 | B 16384 ]

    const unsigned short* gA[2];
    const unsigned short* gB[4];
#pragma unroll
    for (int i = 0; i < 2; ++i){
        int s = i * 256 + wave * 64 + lane;
        int row = s >> 3, c = (s & 7) ^ (row & 7);
        gA[i] = Xbf + (size_t)(mbase + row) * HD + ks * 1024 + c * 8;
    }
#pragma unroll
    for (int j = 0; j < 4; ++j){
        int s = j * 256 + wave * 64 + lane;
        int row = s >> 3, c = (s & 7) ^ (row & 7);
        gB[j] = Wbf + (size_t)(inp * 256 + nbase + row) * HD + ks * 1024 + c * 8;
    }

#define K2_STAGE(d, k0)                                                        \
    {                                                                          \
        _Pragma("unroll")                                                      \
        for (int i = 0; i < 2; ++i)                                            \
            gload_lds16(gA[i] + (k0),                                          \
                        smem + (d) * 24576 + (i * 256 + wave * 64 + lane) * 16);\
        _Pragma("unroll")                                                      \
        for (int j = 0; j < 4; ++j)                                            \
            gload_lds16(gB[j] + (k0),                                          \
                        smem + (d) * 24576 + 8192 + (j * 256 + wave * 64 + lane) * 16);\
    }

    int aoff[2][2], boff[4][2];
#pragma unroll
    for (int mi = 0; mi < 2; ++mi){
        int ra = wm * 32 + mi * 16 + col;
#pragma unroll
        for (int kst = 0; kst < 2; ++kst){
            int cc = kst * 4 + quad;
            aoff[mi][kst] = ra * 128 + ((cc ^ (ra & 7)) << 4);
        }
    }
#pragma unroll
    for (int ni = 0; ni < 4; ++ni){
        int rb = wn * 64 + ni * 16 + col;
#pragma unroll
        for (int kst = 0; kst < 2; ++kst){
            int cc = kst * 4 + quad;
            boff[ni][kst] = rb * 128 + ((cc ^ (rb & 7)) << 4);
        }
    }

    f32x4 acc[2][4];
#pragma unroll
    for (int mi = 0; mi < 2; ++mi)
#pragma unroll
        for (int ni = 0; ni < 4; ++ni) acc[mi][ni] = (f32x4){0.f, 0.f, 0.f, 0.f};

    int cur = 0;
    K2_STAGE(0, 0);
    __syncthreads();
    for (int t = 0; t < 16; ++t){
        if (t < 15) K2_STAGE(cur ^ 1, (t + 1) * 64);
        const char* Ab = smem + cur * 24576;
        const char* Bb = Ab + 8192;
        s16x8 a[2][2], b[4][2];
#pragma unroll
        for (int mi = 0; mi < 2; ++mi)
#pragma unroll
            for (int kst = 0; kst < 2; ++kst)
                a[mi][kst] = *(const s16x8*)(Ab + aoff[mi][kst]);
#pragma unroll
        for (int ni = 0; ni < 4; ++ni)
#pragma unroll
            for (int kst = 0; kst < 2; ++kst)
                b[ni][kst] = *(const s16x8*)(Bb + boff[ni][kst]);
#pragma unroll
        for (int kst = 0; kst < 2; ++kst)
#pragma unroll
            for (int mi = 0; mi < 2; ++mi)
#pragma unroll
                for (int ni = 0; ni < 4; ++ni)
                    acc[mi][ni] = __builtin_amdgcn_mfma_f32_16x16x32_bf16(
                        a[mi][kst], b[ni][kst], acc[mi][ni], 0, 0, 0);
        __syncthreads();
        cur ^= 1;
    }
#undef K2_STAGE

    float* dst = HP + (size_t)ks * NT * D2;
#pragma unroll
    for (int mi = 0; mi < 2; ++mi){
#pragma unroll
        for (int ni = 0; ni < 4; ++ni){
#pragma unroll
            for (int reg = 0; reg < 4; ++reg){
                int m = mbase + wm * 32 + mi * 16 + quad * 4 + reg;
                int n = nbase + wn * 64 + ni * 16 + col;
                dst[(size_t)m * D2 + n] = acc[mi][ni][reg];
            }
        }
    }
}

// ---------------- K3 v13: combine HP + bias + GELU, GEMM2, l2norm.
__global__ __launch_bounds__(256)
void k3_gemm2(const float* __restrict__ HP,
              const float* __restrict__ b1q, const float* __restrict__ b1r,
              const float* __restrict__ W2q, const float* __restrict__ b2q,
              const float* __restrict__ W2r, const float* __restrict__ b2r,
              float* __restrict__ Z, unsigned short* __restrict__ Zbf){
    const int gstart = blockIdx.x * 16;
    const int inp = (gstart >= NQ) ? 1 : 0;
    const float* b1 = inp ? b1r : b1q;
    const float* W2 = inp ? W2r : W2q;
    const float* b2 = inp ? b2r : b2q;

    __shared__ __align__(16) float Hs[16][68];
    __shared__ __align__(16) float Wk[64][132];
    __shared__ float red[16][17];
    __shared__ float normS[16];

    const int tid = threadIdx.x;
    const int ty = tid >> 4;     // row 0..15
    const int tx = tid & 15;     // col group 0..15

    float acc[8];
#pragma unroll
    for (int jj = 0; jj < 8; ++jj) acc[jj] = 0.f;

    for (int kc = 0; kc < 4; ++kc){
#pragma unroll
        for (int i = 0; i < 4; ++i){
            int e = tid + i * 256;
            int rr = e >> 6, kk = e & 63;
            size_t idx = (size_t)(gstart + rr) * D2 + kc * 64 + kk;
            float hv = HP[idx] + HP[(size_t)NT * D2 + idx] + b1[kc * 64 + kk];
            Hs[rr][kk] = gelu_exact(hv);
        }
#pragma unroll
        for (int i = 0; i < 32; ++i){
            int e = tid + i * 256;
            int nn = e >> 6, kk = e & 63;
            Wk[kk][nn] = W2[(size_t)nn * D2 + kc * 64 + kk];
        }
        __syncthreads();
#pragma unroll
        for (int k4 = 0; k4 < 16; ++k4){
            float a0[4];
            float4 t0 = *(const float4*)&Hs[ty][k4 * 4];
            a0[0] = t0.x; a0[1] = t0.y; a0[2] = t0.z; a0[3] = t0.w;
#pragma unroll
            for (int kq = 0; kq < 4; ++kq){
                float4 w0 = *(const float4*)&Wk[k4 * 4 + kq][tx * 8];
                float4 w1 = *(const float4*)&Wk[k4 * 4 + kq][tx * 8 + 4];
                float wv[8] = {w0.x, w0.y, w0.z, w0.w, w1.x, w1.y, w1.z, w1.w};
#pragma unroll
                for (int jj = 0; jj < 8; ++jj)
                    acc[jj] += a0[kq] * wv[jj];
            }
        }
        __syncthreads();
    }
    float v0[8];
    float sq0 = 0.f;
#pragma unroll
    for (int jj = 0; jj < 8; ++jj){
        int c = tx * 8 + jj;
        v0[jj] = acc[jj] + b2[c];
        sq0 += v0[jj] * v0[jj];
    }
    red[ty][tx] = sq0;
    __syncthreads();
    if (tid < 16){
        float s = 0.f;
#pragma unroll
        for (int t = 0; t < 16; ++t) s += red[tid][t];
        normS[tid] = 1.0f / fmaxf(sqrtf(s), 1e-12f);
    }
    __syncthreads();
    float s0 = normS[ty];
    int row0 = gstart + ty;
    size_t o0 = (size_t)row0 * DD + tx * 8;
    float z0[8];
#pragma unroll
    for (int jj = 0; jj < 8; ++jj) z0[jj] = v0[jj] * s0;
    float4 a = {z0[0], z0[1], z0[2], z0[3]}, b = {z0[4], z0[5], z0[6], z0[7]};
    *(float4*)&Z[o0]     = a;  *(float4*)&Z[o0 + 4] = b;
    uint4 p0 = {pack2bf(z0[0], z0[1]), pack2bf(z0[2], z0[3]),
                pack2bf(z0[4], z0[5]), pack2bf(z0[6], z0[7])};
    *(uint4*)&Zbf[o0] = p0;
}

// ---------------- KT: ZbfT[d][r] = Zbf[NQ + r][d]  (r part only), tile 64x128.
__global__ __launch_bounds__(256)
void kT_transpose(const unsigned short* __restrict__ Zbf,
                  unsigned short* __restrict__ ZbfT){
    __shared__ unsigned short Ts[64][129];
    const int r0 = blockIdx.x * 64;
    const int tid = threadIdx.x;
#pragma unroll
    for (int i = 0; i < 32; ++i){
        int e = tid + i * 256;
        int rr = e >> 7, dd = e & 127;
        Ts[rr][dd] = Zbf[(size_t)(NQ + r0 + rr) * DD + dd];
    }
    __syncthreads();
#pragma unroll
    for (int i = 0; i < 32; ++i){
        int e = tid + i * 256;
        int dd = e >> 6, rr = e & 63;
        ZbfT[(size_t)dd * NQ + r0 + rr] = Ts[rr][dd];
    }
}

// ---------------- KA v15: flash attention, block-shared LDS-staged K/V.
// Same as v12 except OP/LW are [row][split][..] so k8's reads are contiguous.
__global__ __launch_bounds__(256)
void kA_attn(const unsigned short* __restrict__ Zbf,
             const unsigned short* __restrict__ ZbfT,
             float* __restrict__ OP, float* __restrict__ LW){
    const int tid  = threadIdx.x;
    const int wave = tid >> 6, lane = tid & 63;
    const int quad = lane >> 4, col = lane & 15;
    const int m0   = blockIdx.x * 128 + wave * 32;
    const int split = blockIdx.y;
    const float scl = 0.08838834764831845f;   // 1/sqrt(128)

    __shared__ __align__(16) char sK[16384];
    __shared__ __align__(16) char sV[16384];
    __shared__ __align__(16) unsigned short Pt[4][2][16][72];

    s16x8 aq[2][4];
#pragma unroll
    for (int m = 0; m < 2; ++m)
#pragma unroll
        for (int kb = 0; kb < 4; ++kb)
            aq[m][kb] = *(const s16x8*)&Zbf[(size_t)(m0 + m * 16 + col) * DD + kb * 32 + quad * 8];

    const unsigned short* gK[4];
    const unsigned short* gV[4];
    int dK[4], dV[4];
#pragma unroll
    for (int i = 0; i < 4; ++i){
        int s = i * 256 + tid;
        int row = s >> 4, c = (s & 15) ^ (row & 15);
        gK[i] = Zbf + (size_t)(NQ + row) * DD + c * 8;
        dK[i] = s * 16;
        int s2 = i * 256 + tid;
        int rv = s2 >> 3, cv = (s2 & 7) ^ (rv & 7);
        gV[i] = ZbfT + (size_t)rv * NQ + cv * 8;
        dV[i] = s2 * 16;
    }

    int kOff[4][4];
#pragma unroll
    for (int nt = 0; nt < 4; ++nt){
        int rb = nt * 16 + col;
#pragma unroll
        for (int kb = 0; kb < 4; ++kb)
            kOff[nt][kb] = rb * 256 + (((kb * 4 + quad) ^ (rb & 15)) << 4);
    }
    int vOff[8][2];
#pragma unroll
    for (int dt = 0; dt < 8; ++dt){
        int rv = dt * 16 + col;
#pragma unroll
        for (int kb2 = 0; kb2 < 2; ++kb2)
            vOff[dt][kb2] = rv * 128 + (((kb2 * 4 + quad) ^ (rv & 7)) << 4);
    }

    f32x4 o[2][8];
#pragma unroll
    for (int m = 0; m < 2; ++m)
#pragma unroll
        for (int dt = 0; dt < 8; ++dt) o[m][dt] = (f32x4){0.f, 0.f, 0.f, 0.f};
    float lp[2][4] = {{0.f,0.f,0.f,0.f},{0.f,0.f,0.f,0.f}};
    float wp[2][4] = {{0.f,0.f,0.f,0.f},{0.f,0.f,0.f,0.f}};

    for (int it = 0; it < NIT; ++it){
        const int r0 = split * KPS + it * 64;
#pragma unroll
        for (int i = 0; i < 4; ++i)
            gload_lds16(gK[i] + (size_t)r0 * DD, sK + dK[i]);
#pragma unroll
        for (int i = 0; i < 4; ++i)
            gload_lds16(gV[i] + r0, sV + dV[i]);
        __syncthreads();

#pragma unroll
        for (int nt = 0; nt < 4; ++nt){
            s16x8 b[4];
#pragma unroll
            for (int kb = 0; kb < 4; ++kb)
                b[kb] = *(const s16x8*)(sK + kOff[nt][kb]);
#pragma unroll
            for (int m = 0; m < 2; ++m){
                f32x4 s = (f32x4){0.f, 0.f, 0.f, 0.f};
#pragma unroll
                for (int kb = 0; kb < 4; ++kb)
                    s = __builtin_amdgcn_mfma_f32_16x16x32_bf16(aq[m][kb], b[kb], s, 0, 0, 0);
#pragma unroll
                for (int reg = 0; reg < 4; ++reg){
                    float sv = s[reg] * scl;
                    float e  = __expf(sv);
                    lp[m][reg] += e;
                    wp[m][reg] += e * sv;
                    Pt[wave][m][quad * 4 + reg][nt * 16 + col] = f2bf(e);
                }
            }
        }

        s16x8 ap[2][2];
#pragma unroll
        for (int m = 0; m < 2; ++m)
#pragma unroll
            for (int kb2 = 0; kb2 < 2; ++kb2)
                ap[m][kb2] = *(const s16x8*)&Pt[wave][m][col][kb2 * 32 + quad * 8];
#pragma unroll
        for (int dt = 0; dt < 8; ++dt){
#pragma unroll
            for (int kb2 = 0; kb2 < 2; ++kb2){
                s16x8 b = *(const s16x8*)(sV + vOff[dt][kb2]);
                o[0][dt] = __builtin_amdgcn_mfma_f32_16x16x32_bf16(ap[0][kb2], b, o[0][dt], 0, 0, 0);
                o[1][dt] = __builtin_amdgcn_mfma_f32_16x16x32_bf16(ap[1][kb2], b, o[1][dt], 0, 0, 0);
            }
        }
        __syncthreads();
    }

#pragma unroll
    for (int m = 0; m < 2; ++m)
#pragma unroll
    for (int reg = 0; reg < 4; ++reg){
        float l = lp[m][reg], w = wp[m][reg];
        l += __shfl_xor(l, 8);  w += __shfl_xor(w, 8);
        l += __shfl_xor(l, 4);  w += __shfl_xor(w, 4);
        l += __shfl_xor(l, 2);  w += __shfl_xor(w, 2);
        l += __shfl_xor(l, 1);  w += __shfl_xor(w, 1);
        if (col == 0){
            int row = m0 + m * 16 + quad * 4 + reg;
            LW[((size_t)row * NSPLIT + split) * 2]     = l;
            LW[((size_t)row * NSPLIT + split) * 2 + 1] = w;
        }
    }
#pragma unroll
    for (int m = 0; m < 2; ++m)
#pragma unroll
    for (int dt = 0; dt < 8; ++dt){
#pragma unroll
        for (int reg = 0; reg < 4; ++reg){
            int row = m0 + m * 16 + quad * 4 + reg;
            OP[((size_t)row * NSPLIT + split) * DD + dt * 16 + col] = o[m][dt][reg];
        }
    }
}

// ---------------- K8 v15: kC fused + decoder MLP (W1d LDS-staged).
// Phase A (per wave = per row): sum 16 OP splits (contiguous 8KB/row),
// l2norm via shfl -> rb (to LDS), cos via Z dot, entropy from LW (16
// contiguous pairs). Phase B: LN over concat(Z, rb). Then MLP as v14.
__global__ __launch_bounds__(256)
void k8_decoder(const float* __restrict__ Z, const float* __restrict__ OP,
                const float* __restrict__ LW,
                const float* __restrict__ gd, const float* __restrict__ bd,
                const float* __restrict__ W1d, const float* __restrict__ b1d,
                const float* __restrict__ W2d, const float* __restrict__ b2d,
                const float* __restrict__ beta, const float* __restrict__ W_len,
                const float* __restrict__ b_len,
                float* __restrict__ out){
    const int r0 = blockIdx.x * 4;
    const int tid = threadIdx.x;
    const int wave = tid >> 6, lane = tid & 63;
    const int row = r0 + wave;

    __shared__ __align__(16) float Xs[4][256];
    __shared__ __align__(16) float Wd[128][33];
    __shared__ float RBs[4][128];
    __shared__ float pr[4][2];
    __shared__ float cosS[4], uS[4];

    // ---- Phase A: combine OP splits -> rb, cos, entropy (per wave/row).
    {
        const int c0 = lane * 2;
        float v0 = 0.f, v1 = 0.f;
#pragma unroll
        for (int s = 0; s < NSPLIT; ++s){
            float2 t = *(const float2*)&OP[((size_t)row * NSPLIT + s) * DD + c0];
            v0 += t.x; v1 += t.y;
        }
        float ss = v0 * v0 + v1 * v1;
#pragma unroll
        for (int off = 32; off > 0; off >>= 1) ss += __shfl_xor(ss, off);
        float scale = 1.0f / fmaxf(sqrtf(ss), 1e-12f);
        float rb0 = v0 * scale, rb1 = v1 * scale;
        RBs[wave][c0]     = rb0;
        RBs[wave][c0 + 1] = rb1;
        float2 zq = *(const float2*)&Z[(size_t)row * DD + c0];
        float cz = zq.x * rb0 + zq.y * rb1;
#pragma unroll
        for (int off = 32; off > 0; off >>= 1) cz += __shfl_xor(cz, off);
        float l_p = 0.f, w_p = 0.f;
        if (lane < NSPLIT){
            float2 lw = *(const float2*)&LW[((size_t)row * NSPLIT + lane) * 2];
            l_p = lw.x; w_p = lw.y;
        }
#pragma unroll
        for (int off = 8; off > 0; off >>= 1){
            l_p += __shfl_xor(l_p, off);
            w_p += __shfl_xor(w_p, off);
        }
        if (lane == 0){
            cosS[wave] = cz;
            float ent = logf(l_p) - w_p / l_p;
            uS[wave] = ent * (1.0f / 8.317766166719343f);  // / ln(4096)
        }
    }
    __syncthreads();

    // ---- Phase B: LN for row, one wave per row, shfl-only reduction.
    {
        const int c0 = lane * 4;
        float4 v;
        if (c0 < DD) v = *(const float4*)&Z[(size_t)row * DD + c0];
        else         v = *(const float4*)&RBs[wave][c0 - DD];
        float s  = v.x + v.y + v.z + v.w;
        float sq = v.x * v.x + v.y * v.y + v.z * v.z + v.w * v.w;
#pragma unroll
        for (int off = 32; off > 0; off >>= 1){
            s  += __shfl_xor(s, off);
            sq += __shfl_xor(sq, off);
        }
        float mean = s * (1.0f / D2);
        float var  = sq * (1.0f / D2) - mean * mean;
        float rstd = rsqrtf(fmaxf(var, 0.0f) + 1e-5f);
        float4 g = *(const float4*)&gd[c0];
        float4 b = *(const float4*)&bd[c0];
        float4 xn;
        xn.x = (v.x - mean) * rstd * g.x + b.x;
        xn.y = (v.y - mean) * rstd * g.y + b.y;
        xn.z = (v.z - mean) * rstd * g.z + b.z;
        xn.w = (v.w - mean) * rstd * g.w + b.w;
        *(float4*)&Xs[wave][c0] = xn;
    }
    __syncthreads();

    // ---- GEMM1 + GELU + W2 dot, W1d via LDS chunks.
    const int j  = tid & 127;
    const int rp = tid >> 7;     // waves 0,1 -> rows 0,1 ; waves 2,3 -> rows 2,3
    const float* xa = &Xs[rp * 2][0];
    const float* xb = &Xs[rp * 2 + 1][0];
    float h0 = 0.f, h1 = 0.f;
    for (int cch = 0; cch < 8; ++cch){
#pragma unroll
        for (int i = 0; i < 16; ++i){
            int e = tid + i * 256;
            int j2 = e >> 5, kk = e & 31;
            Wd[j2][kk] = W1d[(size_t)j2 * D2 + cch * 32 + kk];
        }
        __syncthreads();
#pragma unroll
        for (int k4 = 0; k4 < 8; ++k4){
            float4 w  = *(const float4*)&Wd[j][k4 * 4];
            float4 a4 = *(const float4*)&xa[cch * 32 + k4 * 4];
            float4 b4 = *(const float4*)&xb[cch * 32 + k4 * 4];
            h0 += w.x * a4.x + w.y * a4.y + w.z * a4.z + w.w * a4.w;
            h1 += w.x * b4.x + w.y * b4.y + w.z * b4.z + w.w * b4.w;
        }
        __syncthreads();
    }
    float bj = b1d[j];
    h0 = gelu_exact(h0 + bj);
    h1 = gelu_exact(h1 + bj);
    float w2 = W2d[j];
    float p0 = h0 * w2, p1 = h1 * w2;
#pragma unroll
    for (int off = 32; off > 0; off >>= 1){
        p0 += __shfl_xor(p0, off);
        p1 += __shfl_xor(p1, off);
    }
    if (lane == 0){ pr[wave][0] = p0; pr[wave][1] = p1; }
    __syncthreads();

    // ---- Final logit + scalar heads: threads 0..3, one row each.
    if (tid < 4){
        const int rw    = tid;
        const int rpair = rw >> 1, rlo = rw & 1;
        float lg = b2d[0] + pr[rpair * 2][rlo] + pr[rpair * 2 + 1][rlo];
        const int gr = r0 + rw;
        float u  = uS[rw];
        float cv = cosS[rw];
        float dln = cv * W_len[0] + u * W_len[1] + b_len[0];
        float dt = beta[0] * u + beta[1] * tanhf(dln);
        dt = fminf(0.5f, fmaxf(-0.5f, dt));
        out[gr]      = lg;
        out[NQ + gr] = dt;
    }
}

extern "C" void kernel_launch(void* const* d_in, const int* in_sizes, int n_in,
                              void* d_out, int out_size, void* d_ws, size_t ws_size,
                              hipStream_t stream){
    const float* q      = (const float*)d_in[0];
    const float* R      = (const float*)d_in[1];
    const float* ln_q_g = (const float*)d_in[2];
    const float* ln_q_b = (const float*)d_in[3];
    const float* W1q    = (const float*)d_in[4];
    const float* b1q    = (const float*)d_in[5];
    const float* W2q    = (const float*)d_in[6];
    const float* b2q    = (const float*)d_in[7];
    const float* ln_r_g = (const float*)d_in[8];
    const float* ln_r_b = (const float*)d_in[9];
    const float* W1r    = (const float*)d_in[10];
    const float* b1r    = (const float*)d_in[11];
    const float* W2r    = (const float*)d_in[12];
    const float* b2r    = (const float*)d_in[13];
    const float* ln_d_g = (const float*)d_in[14];
    const float* ln_d_b = (const float*)d_in[15];
    const float* W1d    = (const float*)d_in[16];
    const float* b1d    = (const float*)d_in[17];
    const float* W2d    = (const float*)d_in[18];
    const float* b2d    = (const float*)d_in[19];
    const float* beta   = (const float*)d_in[20];
    const float* W_len  = (const float*)d_in[21];
    const float* b_len  = (const float*)d_in[22];

    float* WS = (float*)d_ws;
    unsigned short* Xbf  = (unsigned short*)(WS);             // 8192*2048 bf16 = 8388608 fl
    float* OP    = WS;                                        // [4096][16][128] aliases Xbf (dead after k2) — exact fit
    float* HP    = WS + 8388608;                              // 2*8192*256
    float* LW    = WS + 8388608;                              // [4096][16][2] aliases HP (dead after k3)
    unsigned short* Wbf  = (unsigned short*)(WS + 12582912);  // 512*2048 bf16
    float* Z     = WS + 13107200;                             // 8192*128
    unsigned short* Zbf  = (unsigned short*)(WS + 14155776);  // 8192*128 bf16
    unsigned short* ZbfT = (unsigned short*)(WS + 14680064);  // 128*4096 bf16
    float* out   = (float*)d_out;

    hipLaunchKernelGGL(kLN_cast, dim3(NT + 512), dim3(256), 0, stream,
                       q, R, ln_q_g, ln_q_b, ln_r_g, ln_r_b, W1q, W1r, Xbf, Wbf);
    hipLaunchKernelGGL(k2_mfma, dim3(128, 2, 2), dim3(256), 0, stream, Xbf, Wbf, HP);
    hipLaunchKernelGGL(k3_gemm2, dim3(512), dim3(256), 0, stream,
                       HP, b1q, b1r, W2q, b2q, W2r, b2r, Z, Zbf);
    hipLaunchKernelGGL(kT_transpose, dim3(64), dim3(256), 0, stream, Zbf, ZbfT);
    hipLaunchKernelGGL(kA_attn, dim3(32, NSPLIT), dim3(256), 0, stream, Zbf, ZbfT, OP, LW);
    hipLaunchKernelGGL(k8_decoder, dim3(1024), dim3(256), 0, stream,
                       Z, OP, LW, ln_d_g, ln_d_b, W1d, b1d, W2d, b2d,
                       beta, W_len, b_len, out);
}

// Round 12
// 236.591 us; speedup vs baseline: 1.2989x; 1.0251x over previous
//
#include <hip/hip_runtime.h>
#include <math.h>

// RouterLite v16 = v15 with (a) OP/LW layout REVERTED to [split][row] (the
// v15 [row][split] relayout cost kA >=5us on writes: 64B segments at 8KB
// stride spray 33MB instead of 2MB slab; k8's strided reads are fine at
// 512B/split/wave), and (b) kA K/V staging DOUBLE-BUFFERED (k2's recipe):
// STAGE(next) issued before compute(cur), ONE barrier/it. Pt shrunk 18->9KB
// by processing m-subtiles sequentially (per-wave buffer, no barrier).
// LDS 73KB via dynamic extern __shared__ (74752B at launch) -> 2 blocks/CU.
//
// ws map (float offsets), total ~61.9 MB:
//   Xbf  @0         [8192][2048] bf16 (8388608 fl) — dead after k2_mfma,
//                   ALIASED by OP @0 [16][4096][128] fp32 (exact fit)
//   HP   @8388608   [2][8192][256] fp32 partials (k2->k3, dead after),
//                   ALIASED by LW @8388608 [16][4096][2] fp32 (kA->k8)
//   Wbf  @12582912  [512][2048] bf16 (W1q rows 0..255, W1r 256..511)
//   Z    @13107200  [8192][128] fp32
//   Zbf  @14155776  [8192][128] bf16
//   ZbfT @14680064  [128][4096] bf16 (Z_r transposed)
// d_out: fp32, [0..4095]=raw_logit, [4096..8191]=delta_theta.

#define HD   2048
#define D2   256
#define DD   128
#define NQ   4096
#define NT   8192
#define NSPLIT 16
#define KPS  (NQ / NSPLIT)   // 256 K-rows per split
#define NIT  (KPS / 64)      // 4 iterations of 64 K-rows

typedef __attribute__((ext_vector_type(8))) short s16x8;
typedef __attribute__((ext_vector_type(4))) float f32x4;

static __device__ __forceinline__ float gelu_exact(float x){
    return 0.5f * x * (1.0f + erff(x * 0.7071067811865475f));
}
static __device__ __forceinline__ unsigned short f2bf(float f){
    unsigned int u = __float_as_uint(f);
    return (unsigned short)((u + 0x7FFFu + ((u >> 16) & 1u)) >> 16);
}
static __device__ __forceinline__ unsigned int pack2bf(float a, float b){
    return (unsigned int)f2bf(a) | ((unsigned int)f2bf(b) << 16);
}

static __device__ __forceinline__ void gload_lds16(const void* g, void* l){
    __builtin_amdgcn_global_load_lds(
        (const __attribute__((address_space(1))) unsigned int*)g,
        (__attribute__((address_space(3))) unsigned int*)l, 16, 0, 0);
}

// ---------------- KLN v13: LN(x) -> bf16 Xbf; W1 -> bf16 Wbf.
__global__ __launch_bounds__(256)
void kLN_cast(const float* __restrict__ q, const float* __restrict__ R,
              const float* __restrict__ gq, const float* __restrict__ bq,
              const float* __restrict__ gr, const float* __restrict__ br,
              const float* __restrict__ W1q, const float* __restrict__ W1r,
              unsigned short* __restrict__ Xbf, unsigned short* __restrict__ Wbf){
    const int r = blockIdx.x;
    const int tid = threadIdx.x;
    if (r >= NT){
        const int rw = r - NT;
        const float* src = (rw >= 256) ? (W1r + (size_t)(rw - 256) * HD)
                                       : (W1q + (size_t)rw * HD);
        float4 a = *(const float4*)&src[tid * 8];
        float4 c = *(const float4*)&src[tid * 8 + 4];
        uint4 p = {pack2bf(a.x, a.y), pack2bf(a.z, a.w),
                   pack2bf(c.x, c.y), pack2bf(c.z, c.w)};
        *(uint4*)&Wbf[(size_t)rw * HD + tid * 8] = p;
        return;
    }
    const float* src = (r < NQ) ? (q + (size_t)r * HD) : (R + (size_t)(r - NQ) * HD);
    const float* g  = (r < NQ) ? gq : gr;
    const float* bb = (r < NQ) ? bq : br;
    float4 x0 = *(const float4*)&src[tid * 8];
    float4 x1 = *(const float4*)&src[tid * 8 + 4];
    float v[8] = {x0.x, x0.y, x0.z, x0.w, x1.x, x1.y, x1.z, x1.w};
    float s = 0.f, sq = 0.f;
#pragma unroll
    for (int i = 0; i < 8; ++i){ s += v[i]; sq += v[i] * v[i]; }
#pragma unroll
    for (int off = 32; off > 0; off >>= 1){
        s  += __shfl_xor(s, off);
        sq += __shfl_xor(sq, off);
    }
    __shared__ float wS[4], wQ[4];
    const int wave = tid >> 6, lane = tid & 63;
    if (lane == 0){ wS[wave] = s; wQ[wave] = sq; }
    __syncthreads();
    float sum = wS[0] + wS[1] + wS[2] + wS[3];
    float sqs = wQ[0] + wQ[1] + wQ[2] + wQ[3];
    float mean = sum * (1.0f / HD);
    float var  = sqs * (1.0f / HD) - mean * mean;
    float rstd = rsqrtf(fmaxf(var, 0.0f) + 1e-5f);
    float4 g0 = *(const float4*)&g[tid * 8];
    float4 g1 = *(const float4*)&g[tid * 8 + 4];
    float4 b0 = *(const float4*)&bb[tid * 8];
    float4 b1 = *(const float4*)&bb[tid * 8 + 4];
    float gg[8] = {g0.x, g0.y, g0.z, g0.w, g1.x, g1.y, g1.z, g1.w};
    float bv[8] = {b0.x, b0.y, b0.z, b0.w, b1.x, b1.y, b1.z, b1.w};
    float h[8];
#pragma unroll
    for (int i = 0; i < 8; ++i) h[i] = (v[i] - mean) * rstd * gg[i] + bv[i];
    uint4 p = {pack2bf(h[0], h[1]), pack2bf(h[2], h[3]),
               pack2bf(h[4], h[5]), pack2bf(h[6], h[7])};
    *(uint4*)&Xbf[(size_t)r * HD + tid * 8] = p;
}

// ---------------- K2 v11: HP[ks] = Xbf @ Wbf^T (K-half ks), LDS-staged.
__global__ __launch_bounds__(256)
void k2_mfma(const unsigned short* __restrict__ Xbf,
             const unsigned short* __restrict__ Wbf,
             float* __restrict__ HP){
    const int tid  = threadIdx.x;
    const int wave = tid >> 6, lane = tid & 63;
    const int quad = lane >> 4, col = lane & 15;
    const int mblk = blockIdx.x;
    const int nblk = blockIdx.y;
    const int ks   = blockIdx.z;
    const int inp  = mblk >> 6;
    const int mbase = mblk * 64;
    const int nbase = nblk * 128;
    const int wm = wave & 1, wn = wave >> 1;

    __shared__ __align__(16) char smem[49152];   // [2][ A 8192 | B 16384 ]

    const unsigned short* gA[2];
    const unsigned short* gB[4];
#pragma unroll
    for (int i = 0; i < 2; ++i){
        int s = i * 256 + wave * 64 + lane;
        int row = s >> 3, c = (s & 7) ^ (row & 7);
        gA[i] = Xbf + (size_t)(mbase + row) * HD + ks * 1024 + c * 8;
    }
#pragma unroll
    for (int j = 0; j < 4; ++j){
        int s = j * 256 + wave * 64 + lane;
        int row = s >> 3, c = (s & 7) ^ (row & 7);
        gB[j] = Wbf + (size_t)(inp * 256 + nbase + row) * HD + ks * 1024 + c * 8;
    }

#define K2_STAGE(d, k0)                                                        \
    {                                                                          \
        _Pragma("unroll")                                                      \
        for (int i = 0; i < 2; ++i)                                            \
            gload_lds16(gA[i] + (k0),                                          \
                        smem + (d) * 24576 + (i * 256 + wave * 64 + lane) * 16);\
        _Pragma("unroll")                                                      \
        for (int j = 0; j < 4; ++j)                                            \
            gload_lds16(gB[j] + (k0),                                          \
                        smem + (d) * 24576 + 8192 + (j * 256 + wave * 64 + lane) * 16);\
    }

    int aoff[2][2], boff[4][2];
#pragma unroll
    for (int mi = 0; mi < 2; ++mi){
        int ra = wm * 32 + mi * 16 + col;
#pragma unroll
        for (int kst = 0; kst < 2; ++kst){
            int cc = kst * 4 + quad;
            aoff[mi][kst] = ra * 128 + ((cc ^ (ra & 7)) << 4);
        }
    }
#pragma unroll
    for (int ni = 0; ni < 4; ++ni){
        int rb = wn * 64 + ni * 16 + col;
#pragma unroll
        for (int kst = 0; kst < 2; ++kst){
            int cc = kst * 4 + quad;
            boff[ni][kst] = rb * 128 + ((cc ^ (rb & 7)) << 4);
        }
    }

    f32x4 acc[2][4];
#pragma unroll
    for (int mi = 0; mi < 2; ++mi)
#pragma unroll
        for (int ni = 0; ni < 4; ++ni) acc[mi][ni] = (f32x4){0.f, 0.f, 0.f, 0.f};

    int cur = 0;
    K2_STAGE(0, 0);
    __syncthreads();
    for (int t = 0; t < 16; ++t){
        if (t < 15) K2_STAGE(cur ^ 1, (t + 1) * 64);
        const char* Ab = smem + cur * 24576;
        const char* Bb = Ab + 8192;
        s16x8 a[2][2], b[4][2];
#pragma unroll
        for (int mi = 0; mi < 2; ++mi)
#pragma unroll
            for (int kst = 0; kst < 2; ++kst)
                a[mi][kst] = *(const s16x8*)(Ab + aoff[mi][kst]);
#pragma unroll
        for (int ni = 0; ni < 4; ++ni)
#pragma unroll
            for (int kst = 0; kst < 2; ++kst)
                b[ni][kst] = *(const s16x8*)(Bb + boff[ni][kst]);
#pragma unroll
        for (int kst = 0; kst < 2; ++kst)
#pragma unroll
            for (int mi = 0; mi < 2; ++mi)
#pragma unroll
                for (int ni = 0; ni < 4; ++ni)
                    acc[mi][ni] = __builtin_amdgcn_mfma_f32_16x16x32_bf16(
                        a[mi][kst], b[ni][kst], acc[mi][ni], 0, 0, 0);
        __syncthreads();
        cur ^= 1;
    }
#undef K2_STAGE

    float* dst = HP + (size_t)ks * NT * D2;
#pragma unroll
    for (int mi = 0; mi < 2; ++mi){
#pragma unroll
        for (int ni = 0; ni < 4; ++ni){
#pragma unroll
            for (int reg = 0; reg < 4; ++reg){
                int m = mbase + wm * 32 + mi * 16 + quad * 4 + reg;
                int n = nbase + wn * 64 + ni * 16 + col;
                dst[(size_t)m * D2 + n] = acc[mi][ni][reg];
            }
        }
    }
}

// ---------------- K3 v13: combine HP + bias + GELU, GEMM2, l2norm.
__global__ __launch_bounds__(256)
void k3_gemm2(const float* __restrict__ HP,
              const float* __restrict__ b1q, const float* __restrict__ b1r,
              const float* __restrict__ W2q, const float* __restrict__ b2q,
              const float* __restrict__ W2r, const float* __restrict__ b2r,
              float* __restrict__ Z, unsigned short* __restrict__ Zbf){
    const int gstart = blockIdx.x * 16;
    const int inp = (gstart >= NQ) ? 1 : 0;
    const float* b1 = inp ? b1r : b1q;
    const float* W2 = inp ? W2r : W2q;
    const float* b2 = inp ? b2r : b2q;

    __shared__ __align__(16) float Hs[16][68];
    __shared__ __align__(16) float Wk[64][132];
    __shared__ float red[16][17];
    __shared__ float normS[16];

    const int tid = threadIdx.x;
    const int ty = tid >> 4;     // row 0..15
    const int tx = tid & 15;     // col group 0..15

    float acc[8];
#pragma unroll
    for (int jj = 0; jj < 8; ++jj) acc[jj] = 0.f;

    for (int kc = 0; kc < 4; ++kc){
#pragma unroll
        for (int i = 0; i < 4; ++i){
            int e = tid + i * 256;
            int rr = e >> 6, kk = e & 63;
            size_t idx = (size_t)(gstart + rr) * D2 + kc * 64 + kk;
            float hv = HP[idx] + HP[(size_t)NT * D2 + idx] + b1[kc * 64 + kk];
            Hs[rr][kk] = gelu_exact(hv);
        }
#pragma unroll
        for (int i = 0; i < 32; ++i){
            int e = tid + i * 256;
            int nn = e >> 6, kk = e & 63;
            Wk[kk][nn] = W2[(size_t)nn * D2 + kc * 64 + kk];
        }
        __syncthreads();
#pragma unroll
        for (int k4 = 0; k4 < 16; ++k4){
            float a0[4];
            float4 t0 = *(const float4*)&Hs[ty][k4 * 4];
            a0[0] = t0.x; a0[1] = t0.y; a0[2] = t0.z; a0[3] = t0.w;
#pragma unroll
            for (int kq = 0; kq < 4; ++kq){
                float4 w0 = *(const float4*)&Wk[k4 * 4 + kq][tx * 8];
                float4 w1 = *(const float4*)&Wk[k4 * 4 + kq][tx * 8 + 4];
                float wv[8] = {w0.x, w0.y, w0.z, w0.w, w1.x, w1.y, w1.z, w1.w};
#pragma unroll
                for (int jj = 0; jj < 8; ++jj)
                    acc[jj] += a0[kq] * wv[jj];
            }
        }
        __syncthreads();
    }
    float v0[8];
    float sq0 = 0.f;
#pragma unroll
    for (int jj = 0; jj < 8; ++jj){
        int c = tx * 8 + jj;
        v0[jj] = acc[jj] + b2[c];
        sq0 += v0[jj] * v0[jj];
    }
    red[ty][tx] = sq0;
    __syncthreads();
    if (tid < 16){
        float s = 0.f;
#pragma unroll
        for (int t = 0; t < 16; ++t) s += red[tid][t];
        normS[tid] = 1.0f / fmaxf(sqrtf(s), 1e-12f);
    }
    __syncthreads();
    float s0 = normS[ty];
    int row0 = gstart + ty;
    size_t o0 = (size_t)row0 * DD + tx * 8;
    float z0[8];
#pragma unroll
    for (int jj = 0; jj < 8; ++jj) z0[jj] = v0[jj] * s0;
    float4 a = {z0[0], z0[1], z0[2], z0[3]}, b = {z0[4], z0[5], z0[6], z0[7]};
    *(float4*)&Z[o0]     = a;  *(float4*)&Z[o0 + 4] = b;
    uint4 p0 = {pack2bf(z0[0], z0[1]), pack2bf(z0[2], z0[3]),
                pack2bf(z0[4], z0[5]), pack2bf(z0[6], z0[7])};
    *(uint4*)&Zbf[o0] = p0;
}

// ---------------- KT: ZbfT[d][r] = Zbf[NQ + r][d]  (r part only), tile 64x128.
__global__ __launch_bounds__(256)
void kT_transpose(const unsigned short* __restrict__ Zbf,
                  unsigned short* __restrict__ ZbfT){
    __shared__ unsigned short Ts[64][129];
    const int r0 = blockIdx.x * 64;
    const int tid = threadIdx.x;
#pragma unroll
    for (int i = 0; i < 32; ++i){
        int e = tid + i * 256;
        int rr = e >> 7, dd = e & 127;
        Ts[rr][dd] = Zbf[(size_t)(NQ + r0 + rr) * DD + dd];
    }
    __syncthreads();
#pragma unroll
    for (int i = 0; i < 32; ++i){
        int e = tid + i * 256;
        int dd = e >> 6, rr = e & 63;
        ZbfT[(size_t)dd * NQ + r0 + rr] = Ts[rr][dd];
    }
}

// ---------------- KA v16: flash attention, double-buffered LDS K/V staging.
// Dynamic LDS 74752B: sK[2]@0/16K, sV[2]@32K/48K, Pt@64K (4 waves x [16][72]).
// Pipeline: STAGE(next) -> compute(cur) [m=0: QK,exp,PV; m=1: QK,exp,PV]
// -> ONE barrier. Pt per-wave, reused across m (no barrier needed).
// OP/LW layout [split][row] (v12 layout — compact 2MB write slab per split).
__global__ __launch_bounds__(256)
void kA_attn(const unsigned short* __restrict__ Zbf,
             const unsigned short* __restrict__ ZbfT,
             float* __restrict__ OP, float* __restrict__ LW){
    extern __shared__ __align__(16) char smem[];
    const int tid  = threadIdx.x;
    const int wave = tid >> 6, lane = tid & 63;
    const int quad = lane >> 4, col = lane & 15;
    const int m0   = blockIdx.x * 128 + wave * 32;
    const int split = blockIdx.y;
    const float scl = 0.08838834764831845f;   // 1/sqrt(128)

    unsigned short (*Pt)[16][72] = (unsigned short(*)[16][72])(smem + 65536);

    s16x8 aq[2][4];
#pragma unroll
    for (int m = 0; m < 2; ++m)
#pragma unroll
        for (int kb = 0; kb < 4; ++kb)
            aq[m][kb] = *(const s16x8*)&Zbf[(size_t)(m0 + m * 16 + col) * DD + kb * 32 + quad * 8];

    const unsigned short* gK[4];
    const unsigned short* gV[4];
    int dK[4], dV[4];
#pragma unroll
    for (int i = 0; i < 4; ++i){
        int s = i * 256 + tid;
        int row = s >> 4, c = (s & 15) ^ (row & 15);
        gK[i] = Zbf + (size_t)(NQ + row) * DD + c * 8;
        dK[i] = s * 16;
        int s2 = i * 256 + tid;
        int rv = s2 >> 3, cv = (s2 & 7) ^ (rv & 7);
        gV[i] = ZbfT + (size_t)rv * NQ + cv * 8;
        dV[i] = s2 * 16;
    }

#define KA_STAGE(d, t)                                                         \
    {                                                                          \
        const int rr0 = split * KPS + (t) * 64;                                \
        char* kb_ = smem + (d) * 16384;                                        \
        char* vb_ = smem + 32768 + (d) * 16384;                                \
        _Pragma("unroll")                                                      \
        for (int i = 0; i < 4; ++i)                                            \
            gload_lds16(gK[i] + (size_t)rr0 * DD, kb_ + dK[i]);                \
        _Pragma("unroll")                                                      \
        for (int i = 0; i < 4; ++i)                                            \
            gload_lds16(gV[i] + rr0, vb_ + dV[i]);                             \
    }

    int kOff[4][4];
#pragma unroll
    for (int nt = 0; nt < 4; ++nt){
        int rb = nt * 16 + col;
#pragma unroll
        for (int kb = 0; kb < 4; ++kb)
            kOff[nt][kb] = rb * 256 + (((kb * 4 + quad) ^ (rb & 15)) << 4);
    }
    int vOff[8][2];
#pragma unroll
    for (int dt = 0; dt < 8; ++dt){
        int rv = dt * 16 + col;
#pragma unroll
        for (int kb2 = 0; kb2 < 2; ++kb2)
            vOff[dt][kb2] = rv * 128 + (((kb2 * 4 + quad) ^ (rv & 7)) << 4);
    }

    f32x4 o[2][8];
#pragma unroll
    for (int m = 0; m < 2; ++m)
#pragma unroll
        for (int dt = 0; dt < 8; ++dt) o[m][dt] = (f32x4){0.f, 0.f, 0.f, 0.f};
    float lp[2][4] = {{0.f,0.f,0.f,0.f},{0.f,0.f,0.f,0.f}};
    float wp[2][4] = {{0.f,0.f,0.f,0.f},{0.f,0.f,0.f,0.f}};

    KA_STAGE(0, 0);
    __syncthreads();
    int cur = 0;
    for (int it = 0; it < NIT; ++it){
        if (it + 1 < NIT) KA_STAGE(cur ^ 1, it + 1);
        const char* Kb = smem + cur * 16384;
        const char* Vb = smem + 32768 + cur * 16384;

#pragma unroll
        for (int m = 0; m < 2; ++m){
            // QK^T + exp for this m-subtile (K from LDS).
#pragma unroll
            for (int nt = 0; nt < 4; ++nt){
                s16x8 b[4];
#pragma unroll
                for (int kb = 0; kb < 4; ++kb)
                    b[kb] = *(const s16x8*)(Kb + kOff[nt][kb]);
                f32x4 s = (f32x4){0.f, 0.f, 0.f, 0.f};
#pragma unroll
                for (int kb = 0; kb < 4; ++kb)
                    s = __builtin_amdgcn_mfma_f32_16x16x32_bf16(aq[m][kb], b[kb], s, 0, 0, 0);
#pragma unroll
                for (int reg = 0; reg < 4; ++reg){
                    float sv = s[reg] * scl;
                    float e  = __expf(sv);
                    lp[m][reg] += e;
                    wp[m][reg] += e * sv;
                    Pt[wave][quad * 4 + reg][nt * 16 + col] = f2bf(e);
                }
            }
            // PV for this m-subtile (V from LDS; Pt is per-wave, lgkmcnt orders).
            s16x8 ap[2];
#pragma unroll
            for (int kb2 = 0; kb2 < 2; ++kb2)
                ap[kb2] = *(const s16x8*)&Pt[wave][col][kb2 * 32 + quad * 8];
#pragma unroll
            for (int dt = 0; dt < 8; ++dt){
#pragma unroll
                for (int kb2 = 0; kb2 < 2; ++kb2){
                    s16x8 b = *(const s16x8*)(Vb + vOff[dt][kb2]);
                    o[m][dt] = __builtin_amdgcn_mfma_f32_16x16x32_bf16(ap[kb2], b, o[m][dt], 0, 0, 0);
                }
            }
        }
        __syncthreads();
        cur ^= 1;
    }
#undef KA_STAGE

#pragma unroll
    for (int m = 0; m < 2; ++m)
#pragma unroll
    for (int reg = 0; reg < 4; ++reg){
        float l = lp[m][reg], w = wp[m][reg];
        l += __shfl_xor(l, 8);  w += __shfl_xor(w, 8);
        l += __shfl_xor(l, 4);  w += __shfl_xor(w, 4);
        l += __shfl_xor(l, 2);  w += __shfl_xor(w, 2);
        l += __shfl_xor(l, 1);  w += __shfl_xor(w, 1);
        if (col == 0){
            int row = m0 + m * 16 + quad * 4 + reg;
            LW[((size_t)split * NQ + row) * 2]     = l;
            LW[((size_t)split * NQ + row) * 2 + 1] = w;
        }
    }
#pragma unroll
    for (int m = 0; m < 2; ++m)
#pragma unroll
    for (int dt = 0; dt < 8; ++dt){
#pragma unroll
        for (int reg = 0; reg < 4; ++reg){
            int row = m0 + m * 16 + quad * 4 + reg;
            OP[((size_t)split * NQ + row) * DD + dt * 16 + col] = o[m][dt][reg];
        }
    }
}

// ---------------- K8 v16: kC fused + decoder MLP (W1d LDS-staged).
// Phase A reads OP/LW in [split][row] layout (strided: 512B/split/wave — fine).
__global__ __launch_bounds__(256)
void k8_decoder(const float* __restrict__ Z, const float* __restrict__ OP,
                const float* __restrict__ LW,
                const float* __restrict__ gd, const float* __restrict__ bd,
                const float* __restrict__ W1d, const float* __restrict__ b1d,
                const float* __restrict__ W2d, const float* __restrict__ b2d,
                const float* __restrict__ beta, const float* __restrict__ W_len,
                const float* __restrict__ b_len,
                float* __restrict__ out){
    const int r0 = blockIdx.x * 4;
    const int tid = threadIdx.x;
    const int wave = tid >> 6, lane = tid & 63;
    const int row = r0 + wave;

    __shared__ __align__(16) float Xs[4][256];
    __shared__ __align__(16) float Wd[128][33];
    __shared__ float RBs[4][128];
    __shared__ float pr[4][2];
    __shared__ float cosS[4], uS[4];

    // ---- Phase A: combine OP splits -> rb, cos, entropy (per wave/row).
    {
        const int c0 = lane * 2;
        float v0 = 0.f, v1 = 0.f;
#pragma unroll
        for (int s = 0; s < NSPLIT; ++s){
            float2 t = *(const float2*)&OP[((size_t)s * NQ + row) * DD + c0];
            v0 += t.x; v1 += t.y;
        }
        float ss = v0 * v0 + v1 * v1;
#pragma unroll
        for (int off = 32; off > 0; off >>= 1) ss += __shfl_xor(ss, off);
        float scale = 1.0f / fmaxf(sqrtf(ss), 1e-12f);
        float rb0 = v0 * scale, rb1 = v1 * scale;
        RBs[wave][c0]     = rb0;
        RBs[wave][c0 + 1] = rb1;
        float2 zq = *(const float2*)&Z[(size_t)row * DD + c0];
        float cz = zq.x * rb0 + zq.y * rb1;
#pragma unroll
        for (int off = 32; off > 0; off >>= 1) cz += __shfl_xor(cz, off);
        float l_p = 0.f, w_p = 0.f;
        if (lane < NSPLIT){
            float2 lw = *(const float2*)&LW[((size_t)lane * NQ + row) * 2];
            l_p = lw.x; w_p = lw.y;
        }
#pragma unroll
        for (int off = 8; off > 0; off >>= 1){
            l_p += __shfl_xor(l_p, off);
            w_p += __shfl_xor(w_p, off);
        }
        if (lane == 0){
            cosS[wave] = cz;
            float ent = logf(l_p) - w_p / l_p;
            uS[wave] = ent * (1.0f / 8.317766166719343f);  // / ln(4096)
        }
    }
    __syncthreads();

    // ---- Phase B: LN for row, one wave per row, shfl-only reduction.
    {
        const int c0 = lane * 4;
        float4 v;
        if (c0 < DD) v = *(const float4*)&Z[(size_t)row * DD + c0];
        else         v = *(const float4*)&RBs[wave][c0 - DD];
        float s  = v.x + v.y + v.z + v.w;
        float sq = v.x * v.x + v.y * v.y + v.z * v.z + v.w * v.w;
#pragma unroll
        for (int off = 32; off > 0; off >>= 1){
            s  += __shfl_xor(s, off);
            sq += __shfl_xor(sq, off);
        }
        float mean = s * (1.0f / D2);
        float var  = sq * (1.0f / D2) - mean * mean;
        float rstd = rsqrtf(fmaxf(var, 0.0f) + 1e-5f);
        float4 g = *(const float4*)&gd[c0];
        float4 b = *(const float4*)&bd[c0];
        float4 xn;
        xn.x = (v.x - mean) * rstd * g.x + b.x;
        xn.y = (v.y - mean) * rstd * g.y + b.y;
        xn.z = (v.z - mean) * rstd * g.z + b.z;
        xn.w = (v.w - mean) * rstd * g.w + b.w;
        *(float4*)&Xs[wave][c0] = xn;
    }
    __syncthreads();

    // ---- GEMM1 + GELU + W2 dot, W1d via LDS chunks.
    const int j  = tid & 127;
    const int rp = tid >> 7;     // waves 0,1 -> rows 0,1 ; waves 2,3 -> rows 2,3
    const float* xa = &Xs[rp * 2][0];
    const float* xb = &Xs[rp * 2 + 1][0];
    float h0 = 0.f, h1 = 0.f;
    for (int cch = 0; cch < 8; ++cch){
#pragma unroll
        for (int i = 0; i < 16; ++i){
            int e = tid + i * 256;
            int j2 = e >> 5, kk = e & 31;
            Wd[j2][kk] = W1d[(size_t)j2 * D2 + cch * 32 + kk];
        }
        __syncthreads();
#pragma unroll
        for (int k4 = 0; k4 < 8; ++k4){
            float4 w  = *(const float4*)&Wd[j][k4 * 4];
            float4 a4 = *(const float4*)&xa[cch * 32 + k4 * 4];
            float4 b4 = *(const float4*)&xb[cch * 32 + k4 * 4];
            h0 += w.x * a4.x + w.y * a4.y + w.z * a4.z + w.w * a4.w;
            h1 += w.x * b4.x + w.y * b4.y + w.z * b4.z + w.w * b4.w;
        }
        __syncthreads();
    }
    float bj = b1d[j];
    h0 = gelu_exact(h0 + bj);
    h1 = gelu_exact(h1 + bj);
    float w2 = W2d[j];
    float p0 = h0 * w2, p1 = h1 * w2;
#pragma unroll
    for (int off = 32; off > 0; off >>= 1){
        p0 += __shfl_xor(p0, off);
        p1 += __shfl_xor(p1, off);
    }
    if (lane == 0){ pr[wave][0] = p0; pr[wave][1] = p1; }
    __syncthreads();

    // ---- Final logit + scalar heads: threads 0..3, one row each.
    if (tid < 4){
        const int rw    = tid;
        const int rpair = rw >> 1, rlo = rw & 1;
        float lg = b2d[0] + pr[rpair * 2][rlo] + pr[rpair * 2 + 1][rlo];
        const int gr = r0 + rw;
        float u  = uS[rw];
        float cv = cosS[rw];
        float dln = cv * W_len[0] + u * W_len[1] + b_len[0];
        float dt = beta[0] * u + beta[1] * tanhf(dln);
        dt = fminf(0.5f, fmaxf(-0.5f, dt));
        out[gr]      = lg;
        out[NQ + gr] = dt;
    }
}

extern "C" void kernel_launch(void* const* d_in, const int* in_sizes, int n_in,
                              void* d_out, int out_size, void* d_ws, size_t ws_size,
                              hipStream_t stream){
    const float* q      = (const float*)d_in[0];
    const float* R      = (const float*)d_in[1];
    const float* ln_q_g = (const float*)d_in[2];
    const float* ln_q_b = (const float*)d_in[3];
    const float* W1q    = (const float*)d_in[4];
    const float* b1q    = (const float*)d_in[5];
    const float* W2q    = (const float*)d_in[6];
    const float* b2q    = (const float*)d_in[7];
    const float* ln_r_g = (const float*)d_in[8];
    const float* ln_r_b = (const float*)d_in[9];
    const float* W1r    = (const float*)d_in[10];
    const float* b1r    = (const float*)d_in[11];
    const float* W2r    = (const float*)d_in[12];
    const float* b2r    = (const float*)d_in[13];
    const float* ln_d_g = (const float*)d_in[14];
    const float* ln_d_b = (const float*)d_in[15];
    const float* W1d    = (const float*)d_in[16];
    const float* b1d    = (const float*)d_in[17];
    const float* W2d    = (const float*)d_in[18];
    const float* b2d    = (const float*)d_in[19];
    const float* beta   = (const float*)d_in[20];
    const float* W_len  = (const float*)d_in[21];
    const float* b_len  = (const float*)d_in[22];

    float* WS = (float*)d_ws;
    unsigned short* Xbf  = (unsigned short*)(WS);             // 8192*2048 bf16 = 8388608 fl
    float* OP    = WS;                                        // [16][4096][128] aliases Xbf (dead after k2) — exact fit
    float* HP    = WS + 8388608;                              // 2*8192*256
    float* LW    = WS + 8388608;                              // [16][4096][2] aliases HP (dead after k3)
    unsigned short* Wbf  = (unsigned short*)(WS + 12582912);  // 512*2048 bf16
    float* Z     = WS + 13107200;                             // 8192*128
    unsigned short* Zbf  = (unsigned short*)(WS + 14155776);  // 8192*128 bf16
    unsigned short* ZbfT = (unsigned short*)(WS + 14680064);  // 128*4096 bf16
    float* out   = (float*)d_out;

    hipLaunchKernelGGL(kLN_cast, dim3(NT + 512), dim3(256), 0, stream,
                       q, R, ln_q_g, ln_q_b, ln_r_g, ln_r_b, W1q, W1r, Xbf, Wbf);
    hipLaunchKernelGGL(k2_mfma, dim3(128, 2, 2), dim3(256), 0, stream, Xbf, Wbf, HP);
    hipLaunchKernelGGL(k3_gemm2, dim3(512), dim3(256), 0, stream,
                       HP, b1q, b1r, W2q, b2q, W2r, b2r, Z, Zbf);
    hipLaunchKernelGGL(kT_transpose, dim3(64), dim3(256), 0, stream, Zbf, ZbfT);
    hipLaunchKernelGGL(kA_attn, dim3(32, NSPLIT), dim3(256), 74752, stream,
                       Zbf, ZbfT, OP, LW);
    hipLaunchKernelGGL(k8_decoder, dim3(1024), dim3(256), 0, stream,
                       Z, OP, LW, ln_d_g, ln_d_b, W1d, b1d, W2d, b2d,
                       beta, W_len, b_len, out);
}

// Round 13
// 234.665 us; speedup vs baseline: 1.3096x; 1.0082x over previous
//
#include <hip/hip_runtime.h>
#include <math.h>

// RouterLite v17 = v16 with NSPLIT 16 -> 8 (kA split-combine traffic halved).
// v16 post-mortem: dbuf kA recovered to < fills; total 236.6. Remaining
// reducible traffic: OP 33.5MB write (kA) + 33.5MB read (k8). The 16-way
// split dated from the v8 TLP experiment (obsolete: kA occupancy is
// LDS-bound at 2 blocks/CU regardless). v17: split 8, grid (64,8) = 512
// blocks, 64 q-rows/block (1 m-subtile of 16 per wave, NIT=8). OP/LW halve;
// k8 Phase A sums 8 splits. kA loop body = proven v16 body minus m-loop.
//
// ws map (float offsets), total ~61.9 MB:
//   Xbf  @0         [8192][2048] bf16 (8388608 fl) — dead after k2_mfma,
//                   ALIASED by OP @0 [8][4096][128] fp32
//   HP   @8388608   [2][8192][256] fp32 partials (k2->k3, dead after),
//                   ALIASED by LW @8388608 [8][4096][2] fp32 (kA->k8)
//   Wbf  @12582912  [512][2048] bf16 (W1q rows 0..255, W1r 256..511)
//   Z    @13107200  [8192][128] fp32
//   Zbf  @14155776  [8192][128] bf16
//   ZbfT @14680064  [128][4096] bf16 (Z_r transposed)
// d_out: fp32, [0..4095]=raw_logit, [4096..8191]=delta_theta.

#define HD   2048
#define D2   256
#define DD   128
#define NQ   4096
#define NT   8192
#define NSPLIT 8
#define KPS  (NQ / NSPLIT)   // 512 K-rows per split
#define NIT  (KPS / 64)      // 8 iterations of 64 K-rows

typedef __attribute__((ext_vector_type(8))) short s16x8;
typedef __attribute__((ext_vector_type(4))) float f32x4;

static __device__ __forceinline__ float gelu_exact(float x){
    return 0.5f * x * (1.0f + erff(x * 0.7071067811865475f));
}
static __device__ __forceinline__ unsigned short f2bf(float f){
    unsigned int u = __float_as_uint(f);
    return (unsigned short)((u + 0x7FFFu + ((u >> 16) & 1u)) >> 16);
}
static __device__ __forceinline__ unsigned int pack2bf(float a, float b){
    return (unsigned int)f2bf(a) | ((unsigned int)f2bf(b) << 16);
}

static __device__ __forceinline__ void gload_lds16(const void* g, void* l){
    __builtin_amdgcn_global_load_lds(
        (const __attribute__((address_space(1))) unsigned int*)g,
        (__attribute__((address_space(3))) unsigned int*)l, 16, 0, 0);
}

// ---------------- KLN v13: LN(x) -> bf16 Xbf; W1 -> bf16 Wbf.
__global__ __launch_bounds__(256)
void kLN_cast(const float* __restrict__ q, const float* __restrict__ R,
              const float* __restrict__ gq, const float* __restrict__ bq,
              const float* __restrict__ gr, const float* __restrict__ br,
              const float* __restrict__ W1q, const float* __restrict__ W1r,
              unsigned short* __restrict__ Xbf, unsigned short* __restrict__ Wbf){
    const int r = blockIdx.x;
    const int tid = threadIdx.x;
    if (r >= NT){
        const int rw = r - NT;
        const float* src = (rw >= 256) ? (W1r + (size_t)(rw - 256) * HD)
                                       : (W1q + (size_t)rw * HD);
        float4 a = *(const float4*)&src[tid * 8];
        float4 c = *(const float4*)&src[tid * 8 + 4];
        uint4 p = {pack2bf(a.x, a.y), pack2bf(a.z, a.w),
                   pack2bf(c.x, c.y), pack2bf(c.z, c.w)};
        *(uint4*)&Wbf[(size_t)rw * HD + tid * 8] = p;
        return;
    }
    const float* src = (r < NQ) ? (q + (size_t)r * HD) : (R + (size_t)(r - NQ) * HD);
    const float* g  = (r < NQ) ? gq : gr;
    const float* bb = (r < NQ) ? bq : br;
    float4 x0 = *(const float4*)&src[tid * 8];
    float4 x1 = *(const float4*)&src[tid * 8 + 4];
    float v[8] = {x0.x, x0.y, x0.z, x0.w, x1.x, x1.y, x1.z, x1.w};
    float s = 0.f, sq = 0.f;
#pragma unroll
    for (int i = 0; i < 8; ++i){ s += v[i]; sq += v[i] * v[i]; }
#pragma unroll
    for (int off = 32; off > 0; off >>= 1){
        s  += __shfl_xor(s, off);
        sq += __shfl_xor(sq, off);
    }
    __shared__ float wS[4], wQ[4];
    const int wave = tid >> 6, lane = tid & 63;
    if (lane == 0){ wS[wave] = s; wQ[wave] = sq; }
    __syncthreads();
    float sum = wS[0] + wS[1] + wS[2] + wS[3];
    float sqs = wQ[0] + wQ[1] + wQ[2] + wQ[3];
    float mean = sum * (1.0f / HD);
    float var  = sqs * (1.0f / HD) - mean * mean;
    float rstd = rsqrtf(fmaxf(var, 0.0f) + 1e-5f);
    float4 g0 = *(const float4*)&g[tid * 8];
    float4 g1 = *(const float4*)&g[tid * 8 + 4];
    float4 b0 = *(const float4*)&bb[tid * 8];
    float4 b1 = *(const float4*)&bb[tid * 8 + 4];
    float gg[8] = {g0.x, g0.y, g0.z, g0.w, g1.x, g1.y, g1.z, g1.w};
    float bv[8] = {b0.x, b0.y, b0.z, b0.w, b1.x, b1.y, b1.z, b1.w};
    float h[8];
#pragma unroll
    for (int i = 0; i < 8; ++i) h[i] = (v[i] - mean) * rstd * gg[i] + bv[i];
    uint4 p = {pack2bf(h[0], h[1]), pack2bf(h[2], h[3]),
               pack2bf(h[4], h[5]), pack2bf(h[6], h[7])};
    *(uint4*)&Xbf[(size_t)r * HD + tid * 8] = p;
}

// ---------------- K2 v11: HP[ks] = Xbf @ Wbf^T (K-half ks), LDS-staged.
__global__ __launch_bounds__(256)
void k2_mfma(const unsigned short* __restrict__ Xbf,
             const unsigned short* __restrict__ Wbf,
             float* __restrict__ HP){
    const int tid  = threadIdx.x;
    const int wave = tid >> 6, lane = tid & 63;
    const int quad = lane >> 4, col = lane & 15;
    const int mblk = blockIdx.x;
    const int nblk = blockIdx.y;
    const int ks   = blockIdx.z;
    const int inp  = mblk >> 6;
    const int mbase = mblk * 64;
    const int nbase = nblk * 128;
    const int wm = wave & 1, wn = wave >> 1;

    __shared__ __align__(16) char smem[49152];   // [2][ A 8192 | B 16384 ]

    const unsigned short* gA[2];
    const unsigned short* gB[4];
#pragma unroll
    for (int i = 0; i < 2; ++i){
        int s = i * 256 + wave * 64 + lane;
        int row = s >> 3, c = (s & 7) ^ (row & 7);
        gA[i] = Xbf + (size_t)(mbase + row) * HD + ks * 1024 + c * 8;
    }
#pragma unroll
    for (int j = 0; j < 4; ++j){
        int s = j * 256 + wave * 64 + lane;
        int row = s >> 3, c = (s & 7) ^ (row & 7);
        gB[j] = Wbf + (size_t)(inp * 256 + nbase + row) * HD + ks * 1024 + c * 8;
    }

#define K2_STAGE(d, k0)                                                        \
    {                                                                          \
        _Pragma("unroll")                                                      \
        for (int i = 0; i < 2; ++i)                                            \
            gload_lds16(gA[i] + (k0),                                          \
                        smem + (d) * 24576 + (i * 256 + wave * 64 + lane) * 16);\
        _Pragma("unroll")                                                      \
        for (int j = 0; j < 4; ++j)                                            \
            gload_lds16(gB[j] + (k0),                                          \
                        smem + (d) * 24576 + 8192 + (j * 256 + wave * 64 + lane) * 16);\
    }

    int aoff[2][2], boff[4][2];
#pragma unroll
    for (int mi = 0; mi < 2; ++mi){
        int ra = wm * 32 + mi * 16 + col;
#pragma unroll
        for (int kst = 0; kst < 2; ++kst){
            int cc = kst * 4 + quad;
            aoff[mi][kst] = ra * 128 + ((cc ^ (ra & 7)) << 4);
        }
    }
#pragma unroll
    for (int ni = 0; ni < 4; ++ni){
        int rb = wn * 64 + ni * 16 + col;
#pragma unroll
        for (int kst = 0; kst < 2; ++kst){
            int cc = kst * 4 + quad;
            boff[ni][kst] = rb * 128 + ((cc ^ (rb & 7)) << 4);
        }
    }

    f32x4 acc[2][4];
#pragma unroll
    for (int mi = 0; mi < 2; ++mi)
#pragma unroll
        for (int ni = 0; ni < 4; ++ni) acc[mi][ni] = (f32x4){0.f, 0.f, 0.f, 0.f};

    int cur = 0;
    K2_STAGE(0, 0);
    __syncthreads();
    for (int t = 0; t < 16; ++t){
        if (t < 15) K2_STAGE(cur ^ 1, (t + 1) * 64);
        const char* Ab = smem + cur * 24576;
        const char* Bb = Ab + 8192;
        s16x8 a[2][2], b[4][2];
#pragma unroll
        for (int mi = 0; mi < 2; ++mi)
#pragma unroll
            for (int kst = 0; kst < 2; ++kst)
                a[mi][kst] = *(const s16x8*)(Ab + aoff[mi][kst]);
#pragma unroll
        for (int ni = 0; ni < 4; ++ni)
#pragma unroll
            for (int kst = 0; kst < 2; ++kst)
                b[ni][kst] = *(const s16x8*)(Bb + boff[ni][kst]);
#pragma unroll
        for (int kst = 0; kst < 2; ++kst)
#pragma unroll
            for (int mi = 0; mi < 2; ++mi)
#pragma unroll
                for (int ni = 0; ni < 4; ++ni)
                    acc[mi][ni] = __builtin_amdgcn_mfma_f32_16x16x32_bf16(
                        a[mi][kst], b[ni][kst], acc[mi][ni], 0, 0, 0);
        __syncthreads();
        cur ^= 1;
    }
#undef K2_STAGE

    float* dst = HP + (size_t)ks * NT * D2;
#pragma unroll
    for (int mi = 0; mi < 2; ++mi){
#pragma unroll
        for (int ni = 0; ni < 4; ++ni){
#pragma unroll
            for (int reg = 0; reg < 4; ++reg){
                int m = mbase + wm * 32 + mi * 16 + quad * 4 + reg;
                int n = nbase + wn * 64 + ni * 16 + col;
                dst[(size_t)m * D2 + n] = acc[mi][ni][reg];
            }
        }
    }
}

// ---------------- K3 v13: combine HP + bias + GELU, GEMM2, l2norm.
__global__ __launch_bounds__(256)
void k3_gemm2(const float* __restrict__ HP,
              const float* __restrict__ b1q, const float* __restrict__ b1r,
              const float* __restrict__ W2q, const float* __restrict__ b2q,
              const float* __restrict__ W2r, const float* __restrict__ b2r,
              float* __restrict__ Z, unsigned short* __restrict__ Zbf){
    const int gstart = blockIdx.x * 16;
    const int inp = (gstart >= NQ) ? 1 : 0;
    const float* b1 = inp ? b1r : b1q;
    const float* W2 = inp ? W2r : W2q;
    const float* b2 = inp ? b2r : b2q;

    __shared__ __align__(16) float Hs[16][68];
    __shared__ __align__(16) float Wk[64][132];
    __shared__ float red[16][17];
    __shared__ float normS[16];

    const int tid = threadIdx.x;
    const int ty = tid >> 4;     // row 0..15
    const int tx = tid & 15;     // col group 0..15

    float acc[8];
#pragma unroll
    for (int jj = 0; jj < 8; ++jj) acc[jj] = 0.f;

    for (int kc = 0; kc < 4; ++kc){
#pragma unroll
        for (int i = 0; i < 4; ++i){
            int e = tid + i * 256;
            int rr = e >> 6, kk = e & 63;
            size_t idx = (size_t)(gstart + rr) * D2 + kc * 64 + kk;
            float hv = HP[idx] + HP[(size_t)NT * D2 + idx] + b1[kc * 64 + kk];
            Hs[rr][kk] = gelu_exact(hv);
        }
#pragma unroll
        for (int i = 0; i < 32; ++i){
            int e = tid + i * 256;
            int nn = e >> 6, kk = e & 63;
            Wk[kk][nn] = W2[(size_t)nn * D2 + kc * 64 + kk];
        }
        __syncthreads();
#pragma unroll
        for (int k4 = 0; k4 < 16; ++k4){
            float a0[4];
            float4 t0 = *(const float4*)&Hs[ty][k4 * 4];
            a0[0] = t0.x; a0[1] = t0.y; a0[2] = t0.z; a0[3] = t0.w;
#pragma unroll
            for (int kq = 0; kq < 4; ++kq){
                float4 w0 = *(const float4*)&Wk[k4 * 4 + kq][tx * 8];
                float4 w1 = *(const float4*)&Wk[k4 * 4 + kq][tx * 8 + 4];
                float wv[8] = {w0.x, w0.y, w0.z, w0.w, w1.x, w1.y, w1.z, w1.w};
#pragma unroll
                for (int jj = 0; jj < 8; ++jj)
                    acc[jj] += a0[kq] * wv[jj];
            }
        }
        __syncthreads();
    }
    float v0[8];
    float sq0 = 0.f;
#pragma unroll
    for (int jj = 0; jj < 8; ++jj){
        int c = tx * 8 + jj;
        v0[jj] = acc[jj] + b2[c];
        sq0 += v0[jj] * v0[jj];
    }
    red[ty][tx] = sq0;
    __syncthreads();
    if (tid < 16){
        float s = 0.f;
#pragma unroll
        for (int t = 0; t < 16; ++t) s += red[tid][t];
        normS[tid] = 1.0f / fmaxf(sqrtf(s), 1e-12f);
    }
    __syncthreads();
    float s0 = normS[ty];
    int row0 = gstart + ty;
    size_t o0 = (size_t)row0 * DD + tx * 8;
    float z0[8];
#pragma unroll
    for (int jj = 0; jj < 8; ++jj) z0[jj] = v0[jj] * s0;
    float4 a = {z0[0], z0[1], z0[2], z0[3]}, b = {z0[4], z0[5], z0[6], z0[7]};
    *(float4*)&Z[o0]     = a;  *(float4*)&Z[o0 + 4] = b;
    uint4 p0 = {pack2bf(z0[0], z0[1]), pack2bf(z0[2], z0[3]),
                pack2bf(z0[4], z0[5]), pack2bf(z0[6], z0[7])};
    *(uint4*)&Zbf[o0] = p0;
}

// ---------------- KT: ZbfT[d][r] = Zbf[NQ + r][d]  (r part only), tile 64x128.
__global__ __launch_bounds__(256)
void kT_transpose(const unsigned short* __restrict__ Zbf,
                  unsigned short* __restrict__ ZbfT){
    __shared__ unsigned short Ts[64][129];
    const int r0 = blockIdx.x * 64;
    const int tid = threadIdx.x;
#pragma unroll
    for (int i = 0; i < 32; ++i){
        int e = tid + i * 256;
        int rr = e >> 7, dd = e & 127;
        Ts[rr][dd] = Zbf[(size_t)(NQ + r0 + rr) * DD + dd];
    }
    __syncthreads();
#pragma unroll
    for (int i = 0; i < 32; ++i){
        int e = tid + i * 256;
        int dd = e >> 6, rr = e & 63;
        ZbfT[(size_t)dd * NQ + r0 + rr] = Ts[rr][dd];
    }
}

// ---------------- KA v17: flash attention, dbuf LDS K/V, split 8.
// Grid (64, 8): 64 m-blocks x 64 q-rows (4 waves x 16), NIT=8.
// Dynamic LDS 74752B: sK[2]@0/16K, sV[2]@32K/48K, Pt@64K (4 x [16][72]).
// Pipeline: STAGE(next) -> compute(cur) {QK,exp,PV} -> ONE barrier.
__global__ __launch_bounds__(256)
void kA_attn(const unsigned short* __restrict__ Zbf,
             const unsigned short* __restrict__ ZbfT,
             float* __restrict__ OP, float* __restrict__ LW){
    extern __shared__ __align__(16) char smem[];
    const int tid  = threadIdx.x;
    const int wave = tid >> 6, lane = tid & 63;
    const int quad = lane >> 4, col = lane & 15;
    const int m0   = blockIdx.x * 64 + wave * 16;
    const int split = blockIdx.y;
    const float scl = 0.08838834764831845f;   // 1/sqrt(128)

    unsigned short (*Pt)[16][72] = (unsigned short(*)[16][72])(smem + 65536);

    s16x8 aq[4];
#pragma unroll
    for (int kb = 0; kb < 4; ++kb)
        aq[kb] = *(const s16x8*)&Zbf[(size_t)(m0 + col) * DD + kb * 32 + quad * 8];

    const unsigned short* gK[4];
    const unsigned short* gV[4];
    int dK[4], dV[4];
#pragma unroll
    for (int i = 0; i < 4; ++i){
        int s = i * 256 + tid;
        int row = s >> 4, c = (s & 15) ^ (row & 15);
        gK[i] = Zbf + (size_t)(NQ + row) * DD + c * 8;
        dK[i] = s * 16;
        int s2 = i * 256 + tid;
        int rv = s2 >> 3, cv = (s2 & 7) ^ (rv & 7);
        gV[i] = ZbfT + (size_t)rv * NQ + cv * 8;
        dV[i] = s2 * 16;
    }

#define KA_STAGE(d, t)                                                         \
    {                                                                          \
        const int rr0 = split * KPS + (t) * 64;                                \
        char* kb_ = smem + (d) * 16384;                                        \
        char* vb_ = smem + 32768 + (d) * 16384;                                \
        _Pragma("unroll")                                                      \
        for (int i = 0; i < 4; ++i)                                            \
            gload_lds16(gK[i] + (size_t)rr0 * DD, kb_ + dK[i]);                \
        _Pragma("unroll")                                                      \
        for (int i = 0; i < 4; ++i)                                            \
            gload_lds16(gV[i] + rr0, vb_ + dV[i]);                             \
    }

    int kOff[4][4];
#pragma unroll
    for (int nt = 0; nt < 4; ++nt){
        int rb = nt * 16 + col;
#pragma unroll
        for (int kb = 0; kb < 4; ++kb)
            kOff[nt][kb] = rb * 256 + (((kb * 4 + quad) ^ (rb & 15)) << 4);
    }
    int vOff[8][2];
#pragma unroll
    for (int dt = 0; dt < 8; ++dt){
        int rv = dt * 16 + col;
#pragma unroll
        for (int kb2 = 0; kb2 < 2; ++kb2)
            vOff[dt][kb2] = rv * 128 + (((kb2 * 4 + quad) ^ (rv & 7)) << 4);
    }

    f32x4 o[8];
#pragma unroll
    for (int dt = 0; dt < 8; ++dt) o[dt] = (f32x4){0.f, 0.f, 0.f, 0.f};
    float lp[4] = {0.f, 0.f, 0.f, 0.f}, wp[4] = {0.f, 0.f, 0.f, 0.f};

    KA_STAGE(0, 0);
    __syncthreads();
    int cur = 0;
    for (int it = 0; it < NIT; ++it){
        if (it + 1 < NIT) KA_STAGE(cur ^ 1, it + 1);
        const char* Kb = smem + cur * 16384;
        const char* Vb = smem + 32768 + cur * 16384;

        // QK^T + exp (K from LDS).
#pragma unroll
        for (int nt = 0; nt < 4; ++nt){
            s16x8 b[4];
#pragma unroll
            for (int kb = 0; kb < 4; ++kb)
                b[kb] = *(const s16x8*)(Kb + kOff[nt][kb]);
            f32x4 s = (f32x4){0.f, 0.f, 0.f, 0.f};
#pragma unroll
            for (int kb = 0; kb < 4; ++kb)
                s = __builtin_amdgcn_mfma_f32_16x16x32_bf16(aq[kb], b[kb], s, 0, 0, 0);
#pragma unroll
            for (int reg = 0; reg < 4; ++reg){
                float sv = s[reg] * scl;
                float e  = __expf(sv);
                lp[reg] += e;
                wp[reg] += e * sv;
                Pt[wave][quad * 4 + reg][nt * 16 + col] = f2bf(e);
            }
        }
        // PV (V from LDS; Pt per-wave, lgkmcnt orders).
        s16x8 ap[2];
#pragma unroll
        for (int kb2 = 0; kb2 < 2; ++kb2)
            ap[kb2] = *(const s16x8*)&Pt[wave][col][kb2 * 32 + quad * 8];
#pragma unroll
        for (int dt = 0; dt < 8; ++dt){
#pragma unroll
            for (int kb2 = 0; kb2 < 2; ++kb2){
                s16x8 b = *(const s16x8*)(Vb + vOff[dt][kb2]);
                o[dt] = __builtin_amdgcn_mfma_f32_16x16x32_bf16(ap[kb2], b, o[dt], 0, 0, 0);
            }
        }
        __syncthreads();
        cur ^= 1;
    }
#undef KA_STAGE

#pragma unroll
    for (int reg = 0; reg < 4; ++reg){
        float l = lp[reg], w = wp[reg];
        l += __shfl_xor(l, 8);  w += __shfl_xor(w, 8);
        l += __shfl_xor(l, 4);  w += __shfl_xor(w, 4);
        l += __shfl_xor(l, 2);  w += __shfl_xor(w, 2);
        l += __shfl_xor(l, 1);  w += __shfl_xor(w, 1);
        if (col == 0){
            int row = m0 + quad * 4 + reg;
            LW[((size_t)split * NQ + row) * 2]     = l;
            LW[((size_t)split * NQ + row) * 2 + 1] = w;
        }
    }
#pragma unroll
    for (int dt = 0; dt < 8; ++dt){
#pragma unroll
        for (int reg = 0; reg < 4; ++reg){
            int row = m0 + quad * 4 + reg;
            OP[((size_t)split * NQ + row) * DD + dt * 16 + col] = o[dt][reg];
        }
    }
}

// ---------------- K8 v17: kC fused + decoder MLP (W1d LDS-staged), 8 splits.
__global__ __launch_bounds__(256)
void k8_decoder(const float* __restrict__ Z, const float* __restrict__ OP,
                const float* __restrict__ LW,
                const float* __restrict__ gd, const float* __restrict__ bd,
                const float* __restrict__ W1d, const float* __restrict__ b1d,
                const float* __restrict__ W2d, const float* __restrict__ b2d,
                const float* __restrict__ beta, const float* __restrict__ W_len,
                const float* __restrict__ b_len,
                float* __restrict__ out){
    const int r0 = blockIdx.x * 4;
    const int tid = threadIdx.x;
    const int wave = tid >> 6, lane = tid & 63;
    const int row = r0 + wave;

    __shared__ __align__(16) float Xs[4][256];
    __shared__ __align__(16) float Wd[128][33];
    __shared__ float RBs[4][128];
    __shared__ float pr[4][2];
    __shared__ float cosS[4], uS[4];

    // ---- Phase A: combine OP splits -> rb, cos, entropy (per wave/row).
    {
        const int c0 = lane * 2;
        float v0 = 0.f, v1 = 0.f;
#pragma unroll
        for (int s = 0; s < NSPLIT; ++s){
            float2 t = *(const float2*)&OP[((size_t)s * NQ + row) * DD + c0];
            v0 += t.x; v1 += t.y;
        }
        float ss = v0 * v0 + v1 * v1;
#pragma unroll
        for (int off = 32; off > 0; off >>= 1) ss += __shfl_xor(ss, off);
        float scale = 1.0f / fmaxf(sqrtf(ss), 1e-12f);
        float rb0 = v0 * scale, rb1 = v1 * scale;
        RBs[wave][c0]     = rb0;
        RBs[wave][c0 + 1] = rb1;
        float2 zq = *(const float2*)&Z[(size_t)row * DD + c0];
        float cz = zq.x * rb0 + zq.y * rb1;
#pragma unroll
        for (int off = 32; off > 0; off >>= 1) cz += __shfl_xor(cz, off);
        float l_p = 0.f, w_p = 0.f;
        if (lane < NSPLIT){
            float2 lw = *(const float2*)&LW[((size_t)lane * NQ + row) * 2];
            l_p = lw.x; w_p = lw.y;
        }
#pragma unroll
        for (int off = NSPLIT / 2; off > 0; off >>= 1){
            l_p += __shfl_xor(l_p, off);
            w_p += __shfl_xor(w_p, off);
        }
        if (lane == 0){
            cosS[wave] = cz;
            float ent = logf(l_p) - w_p / l_p;
            uS[wave] = ent * (1.0f / 8.317766166719343f);  // / ln(4096)
        }
    }
    __syncthreads();

    // ---- Phase B: LN for row, one wave per row, shfl-only reduction.
    {
        const int c0 = lane * 4;
        float4 v;
        if (c0 < DD) v = *(const float4*)&Z[(size_t)row * DD + c0];
        else         v = *(const float4*)&RBs[wave][c0 - DD];
        float s  = v.x + v.y + v.z + v.w;
        float sq = v.x * v.x + v.y * v.y + v.z * v.z + v.w * v.w;
#pragma unroll
        for (int off = 32; off > 0; off >>= 1){
            s  += __shfl_xor(s, off);
            sq += __shfl_xor(sq, off);
        }
        float mean = s * (1.0f / D2);
        float var  = sq * (1.0f / D2) - mean * mean;
        float rstd = rsqrtf(fmaxf(var, 0.0f) + 1e-5f);
        float4 g = *(const float4*)&gd[c0];
        float4 b = *(const float4*)&bd[c0];
        float4 xn;
        xn.x = (v.x - mean) * rstd * g.x + b.x;
        xn.y = (v.y - mean) * rstd * g.y + b.y;
        xn.z = (v.z - mean) * rstd * g.z + b.z;
        xn.w = (v.w - mean) * rstd * g.w + b.w;
        *(float4*)&Xs[wave][c0] = xn;
    }
    __syncthreads();

    // ---- GEMM1 + GELU + W2 dot, W1d via LDS chunks.
    const int j  = tid & 127;
    const int rp = tid >> 7;     // waves 0,1 -> rows 0,1 ; waves 2,3 -> rows 2,3
    const float* xa = &Xs[rp * 2][0];
    const float* xb = &Xs[rp * 2 + 1][0];
    float h0 = 0.f, h1 = 0.f;
    for (int cch = 0; cch < 8; ++cch){
#pragma unroll
        for (int i = 0; i < 16; ++i){
            int e = tid + i * 256;
            int j2 = e >> 5, kk = e & 31;
            Wd[j2][kk] = W1d[(size_t)j2 * D2 + cch * 32 + kk];
        }
        __syncthreads();
#pragma unroll
        for (int k4 = 0; k4 < 8; ++k4){
            float4 w  = *(const float4*)&Wd[j][k4 * 4];
            float4 a4 = *(const float4*)&xa[cch * 32 + k4 * 4];
            float4 b4 = *(const float4*)&xb[cch * 32 + k4 * 4];
            h0 += w.x * a4.x + w.y * a4.y + w.z * a4.z + w.w * a4.w;
            h1 += w.x * b4.x + w.y * b4.y + w.z * b4.z + w.w * b4.w;
        }
        __syncthreads();
    }
    float bj = b1d[j];
    h0 = gelu_exact(h0 + bj);
    h1 = gelu_exact(h1 + bj);
    float w2 = W2d[j];
    float p0 = h0 * w2, p1 = h1 * w2;
#pragma unroll
    for (int off = 32; off > 0; off >>= 1){
        p0 += __shfl_xor(p0, off);
        p1 += __shfl_xor(p1, off);
    }
    if (lane == 0){ pr[wave][0] = p0; pr[wave][1] = p1; }
    __syncthreads();

    // ---- Final logit + scalar heads: threads 0..3, one row each.
    if (tid < 4){
        const int rw    = tid;
        const int rpair = rw >> 1, rlo = rw & 1;
        float lg = b2d[0] + pr[rpair * 2][rlo] + pr[rpair * 2 + 1][rlo];
        const int gr = r0 + rw;
        float u  = uS[rw];
        float cv = cosS[rw];
        float dln = cv * W_len[0] + u * W_len[1] + b_len[0];
        float dt = beta[0] * u + beta[1] * tanhf(dln);
        dt = fminf(0.5f, fmaxf(-0.5f, dt));
        out[gr]      = lg;
        out[NQ + gr] = dt;
    }
}

extern "C" void kernel_launch(void* const* d_in, const int* in_sizes, int n_in,
                              void* d_out, int out_size, void* d_ws, size_t ws_size,
                              hipStream_t stream){
    const float* q      = (const float*)d_in[0];
    const float* R      = (const float*)d_in[1];
    const float* ln_q_g = (const float*)d_in[2];
    const float* ln_q_b = (const float*)d_in[3];
    const float* W1q    = (const float*)d_in[4];
    const float* b1q    = (const float*)d_in[5];
    const float* W2q    = (const float*)d_in[6];
    const float* b2q    = (const float*)d_in[7];
    const float* ln_r_g = (const float*)d_in[8];
    const float* ln_r_b = (const float*)d_in[9];
    const float* W1r    = (const float*)d_in[10];
    const float* b1r    = (const float*)d_in[11];
    const float* W2r    = (const float*)d_in[12];
    const float* b2r    = (const float*)d_in[13];
    const float* ln_d_g = (const float*)d_in[14];
    const float* ln_d_b = (const float*)d_in[15];
    const float* W1d    = (const float*)d_in[16];
    const float* b1d    = (const float*)d_in[17];
    const float* W2d    = (const float*)d_in[18];
    const float* b2d    = (const float*)d_in[19];
    const float* beta   = (const float*)d_in[20];
    const float* W_len  = (const float*)d_in[21];
    const float* b_len  = (const float*)d_in[22];

    float* WS = (float*)d_ws;
    unsigned short* Xbf  = (unsigned short*)(WS);             // 8192*2048 bf16 = 8388608 fl
    float* OP    = WS;                                        // [8][4096][128] aliases Xbf (dead after k2)
    float* HP    = WS + 8388608;                              // 2*8192*256
    float* LW    = WS + 8388608;                              // [8][4096][2] aliases HP (dead after k3)
    unsigned short* Wbf  = (unsigned short*)(WS + 12582912);  // 512*2048 bf16
    float* Z     = WS + 13107200;                             // 8192*128
    unsigned short* Zbf  = (unsigned short*)(WS + 14155776);  // 8192*128 bf16
    unsigned short* ZbfT = (unsigned short*)(WS + 14680064);  // 128*4096 bf16
    float* out   = (float*)d_out;

    hipLaunchKernelGGL(kLN_cast, dim3(NT + 512), dim3(256), 0, stream,
                       q, R, ln_q_g, ln_q_b, ln_r_g, ln_r_b, W1q, W1r, Xbf, Wbf);
    hipLaunchKernelGGL(k2_mfma, dim3(128, 2, 2), dim3(256), 0, stream, Xbf, Wbf, HP);
    hipLaunchKernelGGL(k3_gemm2, dim3(512), dim3(256), 0, stream,
                       HP, b1q, b1r, W2q, b2q, W2r, b2r, Z, Zbf);
    hipLaunchKernelGGL(kT_transpose, dim3(64), dim3(256), 0, stream, Zbf, ZbfT);
    hipLaunchKernelGGL(kA_attn, dim3(64, NSPLIT), dim3(256), 74752, stream,
                       Zbf, ZbfT, OP, LW);
    hipLaunchKernelGGL(k8_decoder, dim3(1024), dim3(256), 0, stream,
                       Z, OP, LW, ln_d_g, ln_d_b, W1d, b1d, W2d, b2d,
                       beta, W_len, b_len, out);
}